// Round 1
// baseline (319.234 us; speedup 1.0000x reference)
//
#include <hip/hip_runtime.h>

// ---------------------------------------------------------------------------
// Transformer block forward on gfx950.  B=2 T=2048 C=1024 H=16 HS=64 FF=4096.
// All matmuls: f16 inputs, fp32 MFMA accumulation (16x16x32).
// Workspace layout (needs 80 MB):
//   [ 0, 6M)  Wqkv^T  f16 [3072][1024]
//   [ 6M, 8M) Wproj^T f16 [1024][1024]
//   [ 8M,16M) W1^T    f16 [4096][1024]
//   [16M,24M) W2^T    f16 [1024][4096]
//   [24M,40M) x1      f32 [4096][1024]
//   [40M,64M) QKV     f16 [4096][3072]   (later reused as low half of ffh)
//   [64M,72M) h1 f16 [4096][1024], then vT f16 [32][64][2048] (reuse)
//   [72M,80M) att f16 [4096][1024], then h2 f16 (reuse)
//   ffh f16 [4096][4096] = [40M,72M)  (QKV+vT slots, both dead by then)
// ---------------------------------------------------------------------------

typedef _Float16 f16;
typedef _Float16 f16x8 __attribute__((ext_vector_type(8)));
typedef _Float16 f16x4v __attribute__((ext_vector_type(4)));
typedef float f32x4 __attribute__((ext_vector_type(4)));

static constexpr int Tn = 2048;
static constexpr int Cn = 1024;
static constexpr int HSn = 64;

// ---------------------------------------------------------------------------
// LayerNorm (fp32 in) -> f16 out.  One block per row, 256 threads.
// ---------------------------------------------------------------------------
__global__ __launch_bounds__(256) void ln_kernel(const float* __restrict__ x,
                                                 const float* __restrict__ w,
                                                 const float* __restrict__ b,
                                                 f16* __restrict__ out) {
    int row = blockIdx.x;
    const float* xr = x + (size_t)row * Cn;
    int tid = threadIdx.x, l = tid & 63, wv = tid >> 6;
    float4 v = *(const float4*)(xr + tid * 4);
    float s = v.x + v.y + v.z + v.w;
    float sq = v.x * v.x + v.y * v.y + v.z * v.z + v.w * v.w;
#pragma unroll
    for (int off = 32; off > 0; off >>= 1) {
        s += __shfl_down(s, off);
        sq += __shfl_down(sq, off);
    }
    __shared__ float red[8];
    if (l == 0) { red[wv] = s; red[wv + 4] = sq; }
    __syncthreads();
    float ts = red[0] + red[1] + red[2] + red[3];
    float tq = red[4] + red[5] + red[6] + red[7];
    float mean = ts * (1.0f / Cn);
    float var = tq * (1.0f / Cn) - mean * mean;
    float rstd = rsqrtf(var + 1e-5f);
    float4 wv4 = *(const float4*)(w + tid * 4);
    float4 bv4 = *(const float4*)(b + tid * 4);
    f16x4v o;
    o[0] = (f16)((v.x - mean) * rstd * wv4.x + bv4.x);
    o[1] = (f16)((v.y - mean) * rstd * wv4.y + bv4.y);
    o[2] = (f16)((v.z - mean) * rstd * wv4.z + bv4.z);
    o[3] = (f16)((v.w - mean) * rstd * wv4.w + bv4.w);
    *(f16x4v*)(out + (size_t)row * Cn + tid * 4) = o;
}

// ---------------------------------------------------------------------------
// Transpose + cast fp32 -> f16:  out[c][r] = in[r][c].  32x32 tiles.
// ---------------------------------------------------------------------------
__global__ __launch_bounds__(256) void tr_cast_f32(const float* __restrict__ in, int irs,
                                                   f16* __restrict__ out, int ors) {
    __shared__ float tile[32][33];
    int r0 = blockIdx.x * 32, c0 = blockIdx.y * 32;
    int t = threadIdx.x;
    int rr = t >> 3, c4 = (t & 7) * 4;
    float4 v = *(const float4*)(in + (size_t)(r0 + rr) * irs + c0 + c4);
    tile[rr][c4] = v.x; tile[rr][c4 + 1] = v.y; tile[rr][c4 + 2] = v.z; tile[rr][c4 + 3] = v.w;
    __syncthreads();
    int cc = t >> 3, r4 = (t & 7) * 4;
    f16x4v o;
    o[0] = (f16)tile[r4][cc];
    o[1] = (f16)tile[r4 + 1][cc];
    o[2] = (f16)tile[r4 + 2][cc];
    o[3] = (f16)tile[r4 + 3][cc];
    *(f16x4v*)(out + (size_t)(c0 + cc) * ors + r0 + r4) = o;
}

// Same, but gathers Wq/Wk/Wv [H][C][HS] into Wqkv^T rows n = qkv*1024 + h*64 + s.
__global__ __launch_bounds__(256) void tr_cast_qkv(const float* __restrict__ Wq,
                                                   const float* __restrict__ Wk,
                                                   const float* __restrict__ Wv,
                                                   f16* __restrict__ out) {
    int z = blockIdx.z;
    int qkv = z >> 4, h = z & 15;
    const float* in = (qkv == 0 ? Wq : qkv == 1 ? Wk : Wv) + (size_t)h * Cn * HSn; // [1024][64]
    f16* o = out + (size_t)(qkv * Cn + h * HSn) * Cn;
    __shared__ float tile[32][33];
    int r0 = blockIdx.x * 32, c0 = blockIdx.y * 32;
    int t = threadIdx.x;
    int rr = t >> 3, c4 = (t & 7) * 4;
    float4 v = *(const float4*)(in + (size_t)(r0 + rr) * HSn + c0 + c4);
    tile[rr][c4] = v.x; tile[rr][c4 + 1] = v.y; tile[rr][c4 + 2] = v.z; tile[rr][c4 + 3] = v.w;
    __syncthreads();
    int cc = t >> 3, r4 = (t & 7) * 4;
    f16x4v ov;
    ov[0] = (f16)tile[r4][cc];
    ov[1] = (f16)tile[r4 + 1][cc];
    ov[2] = (f16)tile[r4 + 2][cc];
    ov[3] = (f16)tile[r4 + 3][cc];
    *(f16x4v*)(o + (size_t)(c0 + cc) * Cn + r0 + r4) = ov;
}

// ---------------------------------------------------------------------------
// f16 transpose: vT[bh][s][t] = QKV[(b*T+t)][2048 + h*64 + s].  64x64 tiles.
// ---------------------------------------------------------------------------
__global__ __launch_bounds__(256) void tr_vT(const f16* __restrict__ QKV, f16* __restrict__ vT) {
    int bh = blockIdx.z;
    int b = bh >> 4, h = bh & 15;
    const f16* in = QKV + (size_t)b * Tn * 3072 + 2048 + h * HSn; // [T][64] stride 3072
    f16* out = vT + (size_t)bh * HSn * Tn;                        // [64][T]
    int r0 = blockIdx.x * 64;
    __shared__ __align__(16) f16 tile[64][72];
    int t = threadIdx.x;
#pragma unroll
    for (int i = 0; i < 2; i++) {
        int f = i * 256 + t;
        int rr = f >> 3, c8 = (f & 7) * 8;
        *(uint4*)(&tile[rr][c8]) = *(const uint4*)(in + (size_t)(r0 + rr) * 3072 + c8);
    }
    __syncthreads();
#pragma unroll
    for (int i = 0; i < 2; i++) {
        int f = i * 256 + t;
        int cc = f >> 3, r8 = (f & 7) * 8;
        union { f16 h[8]; uint4 v; } u;
#pragma unroll
        for (int j = 0; j < 8; j++) u.h[j] = tile[r8 + j][cc];
        *(uint4*)(out + (size_t)cc * Tn + r0 + r8) = u.v;
    }
}

// ---------------------------------------------------------------------------
// GEMM: C[M][N] = A[M][K] @ Bt[N][K]^T, f16 in, fp32 acc.
// 128x128 tile, BK=32, 4 waves (each 64x64 = 4x4 MFMA frags).
// EPI: 0 = store f16, 1 = relu -> f16, 2 = +resid(f32) -> f32.
// M,N % 128 == 0, K % 32 == 0 (all shapes here satisfy this).
// ---------------------------------------------------------------------------
template <int EPI>
__global__ __launch_bounds__(256) void gemm_bt(const f16* __restrict__ A, const f16* __restrict__ Bt,
                                               void* __restrict__ Cout, const float* __restrict__ resid,
                                               int M, int N, int K) {
    constexpr int LDT = 40; // padded LDS row stride (80 B, 16B-aligned, breaks bank pattern)
    __shared__ __align__(16) f16 As[128 * LDT];
    __shared__ __align__(16) f16 Bs[128 * LDT];
    int bm = blockIdx.x, bn = blockIdx.y;
    int tid = threadIdx.x, l = tid & 63, w = tid >> 6;
    int wr = w >> 1, wc = w & 1;
    f32x4 acc[4][4];
#pragma unroll
    for (int m = 0; m < 4; m++)
#pragma unroll
        for (int n = 0; n < 4; n++) acc[m][n] = f32x4{0.f, 0.f, 0.f, 0.f};

    int srow = tid >> 2, skc = (tid & 3) * 8;
    const f16* ag = A + (size_t)(bm * 128 + srow) * K + skc;
    const f16* bg = Bt + (size_t)(bn * 128 + srow) * K + skc;

    uint4 ra0 = *(const uint4*)(ag);
    uint4 ra1 = *(const uint4*)(ag + (size_t)64 * K);
    uint4 rb0 = *(const uint4*)(bg);
    uint4 rb1 = *(const uint4*)(bg + (size_t)64 * K);

    int KT = K >> 5;
    int rbase = (wr * 64 + (l & 15)) * LDT + (l >> 4) * 8;
    int cbase = (wc * 64 + (l & 15)) * LDT + (l >> 4) * 8;

    for (int kt = 0; kt < KT; ++kt) {
        *(uint4*)(&As[srow * LDT + skc]) = ra0;
        *(uint4*)(&As[(srow + 64) * LDT + skc]) = ra1;
        *(uint4*)(&Bs[srow * LDT + skc]) = rb0;
        *(uint4*)(&Bs[(srow + 64) * LDT + skc]) = rb1;
        __syncthreads();
        if (kt + 1 < KT) { // prefetch next K-tile into regs, overlaps MFMA below
            int k0 = (kt + 1) * 32;
            ra0 = *(const uint4*)(ag + k0);
            ra1 = *(const uint4*)(ag + (size_t)64 * K + k0);
            rb0 = *(const uint4*)(bg + k0);
            rb1 = *(const uint4*)(bg + (size_t)64 * K + k0);
        }
        f16x8 af[4], bf[4];
#pragma unroll
        for (int m = 0; m < 4; m++) af[m] = *(const f16x8*)(&As[rbase + m * 16 * LDT]);
#pragma unroll
        for (int n = 0; n < 4; n++) bf[n] = *(const f16x8*)(&Bs[cbase + n * 16 * LDT]);
#pragma unroll
        for (int m = 0; m < 4; m++)
#pragma unroll
            for (int n = 0; n < 4; n++)
                acc[m][n] = __builtin_amdgcn_mfma_f32_16x16x32_f16(af[m], bf[n], acc[m][n], 0, 0, 0);
        __syncthreads();
    }

    int row0 = bm * 128 + wr * 64 + (l >> 4) * 4;
    int col0 = bn * 128 + wc * 64 + (l & 15);
#pragma unroll
    for (int m = 0; m < 4; m++) {
#pragma unroll
        for (int n = 0; n < 4; n++) {
#pragma unroll
            for (int r = 0; r < 4; r++) {
                size_t idx = (size_t)(row0 + m * 16 + r) * N + (col0 + n * 16);
                float v = acc[m][n][r];
                if constexpr (EPI == 0) ((f16*)Cout)[idx] = (f16)v;
                else if constexpr (EPI == 1) ((f16*)Cout)[idx] = (f16)fmaxf(v, 0.f);
                else ((float*)Cout)[idx] = v + resid[idx];
            }
        }
    }
}

// ---------------------------------------------------------------------------
// Flash attention, causal.  Block = (b,h,qtile of 64 rows), 4 waves x 16 rows.
// KV tiles of 64.  K and V^T staged in LDS with XOR swizzle (row&7)<<4.
// P round-trips through per-wave LDS (S-layout -> A-layout).
// ---------------------------------------------------------------------------
__global__ __launch_bounds__(256) void attn_kernel(const f16* __restrict__ QKV,
                                                   const f16* __restrict__ vT,
                                                   const float* __restrict__ p,
                                                   f16* __restrict__ att) {
    int qt = blockIdx.x & 31, bh = blockIdx.x >> 5;
    int b = bh >> 4, h = bh & 15;
    int tid = threadIdx.x, w = tid >> 6, l = tid & 63;
    float scale = rsqrtf(p[h]);

    __shared__ __align__(16) f16 Ks[64 * 64];
    __shared__ __align__(16) f16 Vs[64 * 64];
    __shared__ __align__(16) f16 Ps[4][16 * 72];
    f16* Pw = &Ps[w][0];

    int qrow = qt * 64 + w * 16 + (l & 15);
    const f16* qptr = QKV + (size_t)(b * Tn + qrow) * 3072 + h * HSn + (l >> 4) * 8;
    f16x8 qf0 = *(const f16x8*)(qptr);
    f16x8 qf1 = *(const f16x8*)(qptr + 32);

    f32x4 o[4];
#pragma unroll
    for (int nf = 0; nf < 4; nf++) o[nf] = f32x4{0.f, 0.f, 0.f, 0.f};
    float m_r[4] = {-1e30f, -1e30f, -1e30f, -1e30f};
    float l_r[4] = {0.f, 0.f, 0.f, 0.f};

    int w_qend = qt * 64 + w * 16 + 16;
    int q0 = qt * 64 + w * 16 + (l >> 4) * 4; // this lane's register-row base
    int nkv = qt * 64 + 64;

    for (int kv0 = 0; kv0 < nkv; kv0 += 64) {
        // stage K tile [64][64] and V^T tile [64][64] with XOR swizzle
#pragma unroll
        for (int i = 0; i < 2; i++) {
            int f = i * 256 + tid;
            int row = f >> 3, c8 = f & 7;
            uint4 kd = *(const uint4*)(QKV + (size_t)(b * Tn + kv0 + row) * 3072 + 1024 + h * HSn + c8 * 8);
            uint4 vd = *(const uint4*)(vT + (size_t)(bh * HSn + row) * Tn + kv0 + c8 * 8);
            int dst = row * 128 + ((c8 * 16) ^ ((row & 7) << 4));
            *(uint4*)((char*)Ks + dst) = kd;
            *(uint4*)((char*)Vs + dst) = vd;
        }
        __syncthreads();

        if (kv0 < w_qend) { // wave-uniform: skip fully-masked tiles
            // S = Q K^T
            f32x4 s[4];
#pragma unroll
            for (int n = 0; n < 4; n++) s[n] = f32x4{0.f, 0.f, 0.f, 0.f};
#pragma unroll
            for (int n = 0; n < 4; n++) {
#pragma unroll
                for (int ks = 0; ks < 2; ks++) {
                    int boff = (n * 16 + (l & 15)) * 128 + (((ks * 32 + (l >> 4) * 8) * 2) ^ ((l & 7) << 4));
                    f16x8 kf = *(const f16x8*)((const char*)Ks + boff);
                    s[n] = __builtin_amdgcn_mfma_f32_16x16x32_f16(ks == 0 ? qf0 : qf1, kf, s[n], 0, 0, 0);
                }
            }
            // scale + causal mask + row max
            float rmax[4] = {-1e30f, -1e30f, -1e30f, -1e30f};
#pragma unroll
            for (int n = 0; n < 4; n++) {
                int kvg = kv0 + n * 16 + (l & 15);
#pragma unroll
                for (int r = 0; r < 4; r++) {
                    float v = s[n][r] * scale;
                    v = (kvg <= q0 + r) ? v : -1e30f;
                    s[n][r] = v;
                    rmax[r] = fmaxf(rmax[r], v);
                }
            }
#pragma unroll
            for (int r = 0; r < 4; r++) {
                rmax[r] = fmaxf(rmax[r], __shfl_xor(rmax[r], 1));
                rmax[r] = fmaxf(rmax[r], __shfl_xor(rmax[r], 2));
                rmax[r] = fmaxf(rmax[r], __shfl_xor(rmax[r], 4));
                rmax[r] = fmaxf(rmax[r], __shfl_xor(rmax[r], 8));
            }
            float alpha[4], rsum[4];
#pragma unroll
            for (int r = 0; r < 4; r++) {
                float mn = fmaxf(m_r[r], rmax[r]);
                alpha[r] = __expf(m_r[r] - mn);
                m_r[r] = mn;
                rsum[r] = 0.f;
            }
#pragma unroll
            for (int nf = 0; nf < 4; nf++)
#pragma unroll
                for (int r = 0; r < 4; r++) o[nf][r] *= alpha[r];
            // P = exp(S - m), write to per-wave LDS in S-layout
#pragma unroll
            for (int n = 0; n < 4; n++) {
#pragma unroll
                for (int r = 0; r < 4; r++) {
                    float pv = __expf(s[n][r] - m_r[r]);
                    rsum[r] += pv;
                    Pw[((l >> 4) * 4 + r) * 72 + n * 16 + (l & 15)] = (f16)pv;
                }
            }
#pragma unroll
            for (int r = 0; r < 4; r++) {
                rsum[r] += __shfl_xor(rsum[r], 1);
                rsum[r] += __shfl_xor(rsum[r], 2);
                rsum[r] += __shfl_xor(rsum[r], 4);
                rsum[r] += __shfl_xor(rsum[r], 8);
                l_r[r] = l_r[r] * alpha[r] + rsum[r];
            }
            // read P back in A-layout (wave-private buffer, in-order DS pipe)
            f16x8 pa0 = *(const f16x8*)(&Pw[(l & 15) * 72 + (l >> 4) * 8]);
            f16x8 pa1 = *(const f16x8*)(&Pw[(l & 15) * 72 + 32 + (l >> 4) * 8]);
            // O += P V
#pragma unroll
            for (int nf = 0; nf < 4; nf++) {
#pragma unroll
                for (int ks = 0; ks < 2; ks++) {
                    int boff = (nf * 16 + (l & 15)) * 128 + (((ks * 32 + (l >> 4) * 8) * 2) ^ ((l & 7) << 4));
                    f16x8 vf = *(const f16x8*)((const char*)Vs + boff);
                    o[nf] = __builtin_amdgcn_mfma_f32_16x16x32_f16(ks == 0 ? pa0 : pa1, vf, o[nf], 0, 0, 0);
                }
            }
        }
        __syncthreads();
    }
    // epilogue: O / l, store to att [B*T][C] at col h*64+...
#pragma unroll
    for (int nf = 0; nf < 4; nf++) {
#pragma unroll
        for (int r = 0; r < 4; r++) {
            float v = o[nf][r] / l_r[r];
            att[(size_t)(b * Tn + q0 + r) * Cn + h * HSn + nf * 16 + (l & 15)] = (f16)v;
        }
    }
}

// ---------------------------------------------------------------------------
extern "C" void kernel_launch(void* const* d_in, const int* in_sizes, int n_in,
                              void* d_out, int out_size, void* d_ws, size_t ws_size,
                              hipStream_t stream) {
    const float* x = (const float*)d_in[0];
    const float* Wq = (const float*)d_in[1];
    const float* Wk = (const float*)d_in[2];
    const float* Wv = (const float*)d_in[3];
    const float* p = (const float*)d_in[4];
    const float* Wproj = (const float*)d_in[5];
    const float* W1 = (const float*)d_in[6];
    const float* W2 = (const float*)d_in[7];
    const float* ln1w = (const float*)d_in[8];
    const float* ln1b = (const float*)d_in[9];
    const float* ln2w = (const float*)d_in[10];
    const float* ln2b = (const float*)d_in[11];

    char* ws = (char*)d_ws;
    const size_t MB = 1ull << 20;
    f16* Wqkv_t = (f16*)(ws + 0 * MB);   // [3072][1024]
    f16* Wproj_t = (f16*)(ws + 6 * MB);  // [1024][1024]
    f16* W1_t = (f16*)(ws + 8 * MB);     // [4096][1024]
    f16* W2_t = (f16*)(ws + 16 * MB);    // [1024][4096]
    float* x1 = (float*)(ws + 24 * MB);  // [4096][1024] f32
    f16* QKV = (f16*)(ws + 40 * MB);     // [4096][3072]
    f16* h1 = (f16*)(ws + 64 * MB);      // [4096][1024]
    f16* vTb = (f16*)(ws + 64 * MB);     // [32][64][2048] (reuses h1 slot)
    f16* attb = (f16*)(ws + 72 * MB);    // [4096][1024]
    f16* h2 = attb;                      // reuse (att dead after proj gemm)
    f16* ffh = QKV;                      // [4096][4096] spans 40M..72M (QKV+vT dead)
    float* out = (float*)d_out;

    // weight repack (transposed f16)
    tr_cast_qkv<<<dim3(32, 2, 48), 256, 0, stream>>>(Wq, Wk, Wv, Wqkv_t);
    tr_cast_f32<<<dim3(32, 32), 256, 0, stream>>>(Wproj, 1024, Wproj_t, 1024);
    tr_cast_f32<<<dim3(32, 128), 256, 0, stream>>>(W1, 4096, W1_t, 1024);
    tr_cast_f32<<<dim3(128, 32), 256, 0, stream>>>(W2, 1024, W2_t, 4096);

    // block forward
    ln_kernel<<<4096, 256, 0, stream>>>(x, ln1w, ln1b, h1);
    gemm_bt<0><<<dim3(32, 24), 256, 0, stream>>>(h1, Wqkv_t, QKV, nullptr, 4096, 3072, 1024);
    tr_vT<<<dim3(32, 1, 32), 256, 0, stream>>>(QKV, vTb);
    attn_kernel<<<1024, 256, 0, stream>>>(QKV, vTb, p, attb);
    gemm_bt<2><<<dim3(32, 8), 256, 0, stream>>>(attb, Wproj_t, x1, x, 4096, 1024, 1024);
    ln_kernel<<<4096, 256, 0, stream>>>(x1, ln2w, ln2b, h2);
    gemm_bt<1><<<dim3(32, 32), 256, 0, stream>>>(h2, W1_t, ffh, nullptr, 4096, 4096, 1024);
    gemm_bt<2><<<dim3(32, 8), 256, 0, stream>>>(ffh, W2_t, out, x1, 4096, 1024, 4096);
}

// Round 2
// 284.236 us; speedup vs baseline: 1.1231x; 1.1231x over previous
//
#include <hip/hip_runtime.h>

// ---------------------------------------------------------------------------
// Transformer block forward on gfx950.  B=2 T=2048 C=1024 H=16 HS=64 FF=4096.
// All matmuls: f16 inputs, fp32 MFMA accumulation (16x16x32).
// R2: global_load_lds staging + LDS double-buffer (1 barrier/iter) in GEMM and
//     attention; swapped QK^T (lane-local softmax); paired causal q-tiles.
// Workspace layout (80 MB):
//   [ 0, 6M)  Wqkv^T  f16 [3072][1024]
//   [ 6M, 8M) Wproj^T f16 [1024][1024]
//   [ 8M,16M) W1^T    f16 [4096][1024]
//   [16M,24M) W2^T    f16 [1024][4096]
//   [24M,40M) x1      f32 [4096][1024]
//   [40M,64M) QKV     f16 [4096][3072]
//   [64M,72M) h1 f16 [4096][1024], then vT f16 [32][64][2048] (reuse)
//   [72M,80M) att f16 [4096][1024], then h2 f16 (reuse)
//   ffh f16 [4096][4096] = [40M,72M)  (QKV+vT dead by then)
// ---------------------------------------------------------------------------

typedef _Float16 f16;
typedef _Float16 f16x8 __attribute__((ext_vector_type(8)));
typedef _Float16 f16x4v __attribute__((ext_vector_type(4)));
typedef float f32x4 __attribute__((ext_vector_type(4)));

static constexpr int Tn = 2048;
static constexpr int Cn = 1024;
static constexpr int HSn = 64;

// async global->LDS, 16B per lane; dest = wave-uniform base + lane*16
__device__ __forceinline__ void glds16(const f16* g, f16* l) {
    __builtin_amdgcn_global_load_lds((const __attribute__((address_space(1))) void*)g,
                                     (__attribute__((address_space(3))) void*)l,
                                     16, 0, 0);
}

// ---------------------------------------------------------------------------
// LayerNorm (fp32 in) -> f16 out.  One block per row, 256 threads.
// ---------------------------------------------------------------------------
__global__ __launch_bounds__(256) void ln_kernel(const float* __restrict__ x,
                                                 const float* __restrict__ w,
                                                 const float* __restrict__ b,
                                                 f16* __restrict__ out) {
    int row = blockIdx.x;
    const float* xr = x + (size_t)row * Cn;
    int tid = threadIdx.x, l = tid & 63, wv = tid >> 6;
    float4 v = *(const float4*)(xr + tid * 4);
    float s = v.x + v.y + v.z + v.w;
    float sq = v.x * v.x + v.y * v.y + v.z * v.z + v.w * v.w;
#pragma unroll
    for (int off = 32; off > 0; off >>= 1) {
        s += __shfl_down(s, off);
        sq += __shfl_down(sq, off);
    }
    __shared__ float red[8];
    if (l == 0) { red[wv] = s; red[wv + 4] = sq; }
    __syncthreads();
    float ts = red[0] + red[1] + red[2] + red[3];
    float tq = red[4] + red[5] + red[6] + red[7];
    float mean = ts * (1.0f / Cn);
    float var = tq * (1.0f / Cn) - mean * mean;
    float rstd = rsqrtf(var + 1e-5f);
    float4 wv4 = *(const float4*)(w + tid * 4);
    float4 bv4 = *(const float4*)(b + tid * 4);
    f16x4v o;
    o[0] = (f16)((v.x - mean) * rstd * wv4.x + bv4.x);
    o[1] = (f16)((v.y - mean) * rstd * wv4.y + bv4.y);
    o[2] = (f16)((v.z - mean) * rstd * wv4.z + bv4.z);
    o[3] = (f16)((v.w - mean) * rstd * wv4.w + bv4.w);
    *(f16x4v*)(out + (size_t)row * Cn + tid * 4) = o;
}

// ---------------------------------------------------------------------------
// Transpose + cast fp32 -> f16:  out[c][r] = in[r][c].  32x32 tiles.
// ---------------------------------------------------------------------------
__global__ __launch_bounds__(256) void tr_cast_f32(const float* __restrict__ in, int irs,
                                                   f16* __restrict__ out, int ors) {
    __shared__ float tile[32][33];
    int r0 = blockIdx.x * 32, c0 = blockIdx.y * 32;
    int t = threadIdx.x;
    int rr = t >> 3, c4 = (t & 7) * 4;
    float4 v = *(const float4*)(in + (size_t)(r0 + rr) * irs + c0 + c4);
    tile[rr][c4] = v.x; tile[rr][c4 + 1] = v.y; tile[rr][c4 + 2] = v.z; tile[rr][c4 + 3] = v.w;
    __syncthreads();
    int cc = t >> 3, r4 = (t & 7) * 4;
    f16x4v o;
    o[0] = (f16)tile[r4][cc];
    o[1] = (f16)tile[r4 + 1][cc];
    o[2] = (f16)tile[r4 + 2][cc];
    o[3] = (f16)tile[r4 + 3][cc];
    *(f16x4v*)(out + (size_t)(c0 + cc) * ors + r0 + r4) = o;
}

// Same, but gathers Wq/Wk/Wv [H][C][HS] into Wqkv^T rows n = qkv*1024 + h*64 + s.
__global__ __launch_bounds__(256) void tr_cast_qkv(const float* __restrict__ Wq,
                                                   const float* __restrict__ Wk,
                                                   const float* __restrict__ Wv,
                                                   f16* __restrict__ out) {
    int z = blockIdx.z;
    int qkv = z >> 4, h = z & 15;
    const float* in = (qkv == 0 ? Wq : qkv == 1 ? Wk : Wv) + (size_t)h * Cn * HSn; // [1024][64]
    f16* o = out + (size_t)(qkv * Cn + h * HSn) * Cn;
    __shared__ float tile[32][33];
    int r0 = blockIdx.x * 32, c0 = blockIdx.y * 32;
    int t = threadIdx.x;
    int rr = t >> 3, c4 = (t & 7) * 4;
    float4 v = *(const float4*)(in + (size_t)(r0 + rr) * HSn + c0 + c4);
    tile[rr][c4] = v.x; tile[rr][c4 + 1] = v.y; tile[rr][c4 + 2] = v.z; tile[rr][c4 + 3] = v.w;
    __syncthreads();
    int cc = t >> 3, r4 = (t & 7) * 4;
    f16x4v ov;
    ov[0] = (f16)tile[r4][cc];
    ov[1] = (f16)tile[r4 + 1][cc];
    ov[2] = (f16)tile[r4 + 2][cc];
    ov[3] = (f16)tile[r4 + 3][cc];
    *(f16x4v*)(o + (size_t)(c0 + cc) * Cn + r0 + r4) = ov;
}

// ---------------------------------------------------------------------------
// f16 transpose: vT[bh][s][t] = QKV[(b*T+t)][2048 + h*64 + s].  64x64 tiles.
// ---------------------------------------------------------------------------
__global__ __launch_bounds__(256) void tr_vT(const f16* __restrict__ QKV, f16* __restrict__ vT) {
    int bh = blockIdx.z;
    int b = bh >> 4, h = bh & 15;
    const f16* in = QKV + (size_t)b * Tn * 3072 + 2048 + h * HSn; // [T][64] stride 3072
    f16* out = vT + (size_t)bh * HSn * Tn;                        // [64][T]
    int r0 = blockIdx.x * 64;
    __shared__ __align__(16) f16 tile[64][72];
    int t = threadIdx.x;
#pragma unroll
    for (int i = 0; i < 2; i++) {
        int f = i * 256 + t;
        int rr = f >> 3, c8 = (f & 7) * 8;
        *(uint4*)(&tile[rr][c8]) = *(const uint4*)(in + (size_t)(r0 + rr) * 3072 + c8);
    }
    __syncthreads();
#pragma unroll
    for (int i = 0; i < 2; i++) {
        int f = i * 256 + t;
        int cc = f >> 3, r8 = (f & 7) * 8;
        union { f16 h[8]; uint4 v; } u;
#pragma unroll
        for (int j = 0; j < 8; j++) u.h[j] = tile[r8 + j][cc];
        *(uint4*)(out + (size_t)cc * Tn + r0 + r8) = u.v;
    }
}

// ---------------------------------------------------------------------------
// GEMM: C[M][N] = A[M][K] @ Bt[N][K]^T, f16 in, fp32 acc.
// 128x128 tile, BK=32, 4 waves (each 64x64 = 4x4 MFMA frags).
// global_load_lds staging, double-buffered LDS, one barrier per K-step.
// EPI: 0 = store f16, 1 = relu -> f16, 2 = +resid(f32) -> f32.
// ---------------------------------------------------------------------------
template <int EPI>
__global__ __launch_bounds__(256) void gemm_bt(const f16* __restrict__ A, const f16* __restrict__ Bt,
                                               void* __restrict__ Cout, const float* __restrict__ resid,
                                               int M, int N, int K) {
    __shared__ __align__(16) f16 As[2][4096]; // [128][32] per buffer, linear
    __shared__ __align__(16) f16 Bs[2][4096];
    int bm = blockIdx.x, bn = blockIdx.y;
    int tid = threadIdx.x, l = tid & 63, w = tid >> 6;
    int wr = w >> 1, wc = w & 1;
    f32x4 acc[4][4];
#pragma unroll
    for (int m = 0; m < 4; m++)
#pragma unroll
        for (int n = 0; n < 4; n++) acc[m][n] = f32x4{0.f, 0.f, 0.f, 0.f};

    const f16* ag = A + (size_t)(bm * 128 + (tid >> 2)) * K + (tid & 3) * 8;
    const f16* bg = Bt + (size_t)(bn * 128 + (tid >> 2)) * K + (tid & 3) * 8;
    const size_t half = (size_t)64 * K;
    int KT = K >> 5;
    int rbase = (wr * 64 + (l & 15)) * 32 + (l >> 4) * 8;
    int cbase = (wc * 64 + (l & 15)) * 32 + (l >> 4) * 8;

    auto stage = [&](int kt, int bf) {
        int k0 = kt * 32;
        glds16(ag + k0, &As[bf][w * 512]);
        glds16(ag + half + k0, &As[bf][2048 + w * 512]);
        glds16(bg + k0, &Bs[bf][w * 512]);
        glds16(bg + half + k0, &Bs[bf][2048 + w * 512]);
    };

    stage(0, 0);
    __syncthreads(); // tile 0 ready
    for (int kt = 0; kt < KT; ++kt) {
        int cb = kt & 1;
        if (kt + 1 < KT) stage(kt + 1, cb ^ 1); // in flight across the compute below
        f16x8 af[4], bfr[4];
#pragma unroll
        for (int m = 0; m < 4; m++) af[m] = *(const f16x8*)(&As[cb][rbase + m * 512]);
#pragma unroll
        for (int n = 0; n < 4; n++) bfr[n] = *(const f16x8*)(&Bs[cb][cbase + n * 512]);
#pragma unroll
        for (int m = 0; m < 4; m++)
#pragma unroll
            for (int n = 0; n < 4; n++)
                acc[m][n] = __builtin_amdgcn_mfma_f32_16x16x32_f16(af[m], bfr[n], acc[m][n], 0, 0, 0);
        __syncthreads(); // drains next-tile loads + guards buffer reuse
    }

    int row0 = bm * 128 + wr * 64 + (l >> 4) * 4;
    int col0 = bn * 128 + wc * 64 + (l & 15);
#pragma unroll
    for (int m = 0; m < 4; m++) {
#pragma unroll
        for (int n = 0; n < 4; n++) {
#pragma unroll
            for (int r = 0; r < 4; r++) {
                size_t idx = (size_t)(row0 + m * 16 + r) * N + (col0 + n * 16);
                float v = acc[m][n][r];
                if constexpr (EPI == 0) ((f16*)Cout)[idx] = (f16)v;
                else if constexpr (EPI == 1) ((f16*)Cout)[idx] = (f16)fmaxf(v, 0.f);
                else ((float*)Cout)[idx] = v + resid[idx];
            }
        }
    }
}

// ---------------------------------------------------------------------------
// Flash attention, causal.  Block = (bh, qtile-pair), 4 waves x 16 q-rows,
// two passes: qt and 31-qt (uniform 33 KV tiles per block).
// Swapped QK^T: s[n] = mfma(K, Q) -> lane holds S^T[kv][q=lane&15]; softmax
// stats are lane-local (2 shfl per reduce).  K/V staged via global_load_lds
// with the XOR swizzle applied to the per-lane GLOBAL source address (LDS
// linear dest), double-buffered, 1 barrier/tile.
// ---------------------------------------------------------------------------
__global__ __launch_bounds__(256) void attn_kernel(const f16* __restrict__ QKV,
                                                   const f16* __restrict__ vT,
                                                   const float* __restrict__ p,
                                                   f16* __restrict__ att) {
    int pq = blockIdx.x & 15, bh = blockIdx.x >> 4;
    int b = bh >> 4, h = bh & 15;
    int tid = threadIdx.x, w = tid >> 6, l = tid & 63;
    float scale = rsqrtf(p[h]);

    __shared__ __align__(16) f16 Ks[2][4096]; // [64][64] per buffer, swizzled content
    __shared__ __align__(16) f16 Vs[2][4096];
    __shared__ __align__(16) f16 Ps[4][16 * 80];
    f16* Pw = &Ps[w][0];

    // glds staging: lane covers linear LDS bytes; invert swizzle on global col
    int srow0 = tid >> 3;                  // rows 0..31 (instr 0)
    int c0 = (tid & 7) ^ (srow0 & 7);      // inverse-swizzled 16B chunk
    int srow1 = 32 + srow0;                // rows 32..63 (instr 1)
    int c1 = (tid & 7) ^ (srow1 & 7);
    const f16* Kg = QKV + (size_t)b * Tn * 3072 + 1024 + h * HSn; // [T][64] stride 3072
    const f16* Vg = vT + (size_t)bh * HSn * Tn;                   // [64][Tn]

    auto stageKV = [&](int kv0, int bf) {
        glds16(Kg + (size_t)(kv0 + srow0) * 3072 + c0 * 8, &Ks[bf][w * 512]);
        glds16(Kg + (size_t)(kv0 + srow1) * 3072 + c1 * 8, &Ks[bf][2048 + w * 512]);
        glds16(Vg + (size_t)srow0 * Tn + kv0 + c0 * 8, &Vs[bf][w * 512]);
        glds16(Vg + (size_t)srow1 * Tn + kv0 + c1 * 8, &Vs[bf][2048 + w * 512]);
    };

    for (int pass = 0; pass < 2; ++pass) {
        int qt = pass ? (31 - pq) : pq;
        int qg = qt * 64 + w * 16 + (l & 15);     // this lane's softmax q-row
        int qo = qt * 64 + w * 16 + (l >> 4) * 4; // this lane's O q-row base
        const f16* qptr = QKV + (size_t)(b * Tn + qg) * 3072 + h * HSn + (l >> 4) * 8;
        f16x8 qf0 = *(const f16x8*)(qptr);
        f16x8 qf1 = *(const f16x8*)(qptr + 32);

        f32x4 o[4];
#pragma unroll
        for (int nf = 0; nf < 4; nf++) o[nf] = f32x4{0.f, 0.f, 0.f, 0.f};
        float m_r = -1e30f, l_r = 0.f;

        int nt = qt + 1; // KV tiles for this q-tile
        stageKV(0, 0);
        __syncthreads();
        for (int t = 0; t < nt; ++t) {
            int cb = t & 1, kv0 = t * 64;
            if (t + 1 < nt) stageKV(kv0 + 64, cb ^ 1);
            const char* Kb = (const char*)&Ks[cb][0];
            const char* Vb = (const char*)&Vs[cb][0];
            // S^T = K Q^T : lane holds s[n][r] = S[kv0+n*16+(l>>4)*4+r][qg]
            f32x4 s[4];
#pragma unroll
            for (int n = 0; n < 4; n++) s[n] = f32x4{0.f, 0.f, 0.f, 0.f};
#pragma unroll
            for (int n = 0; n < 4; n++) {
#pragma unroll
                for (int ks = 0; ks < 2; ks++) {
                    int boff = (n * 16 + (l & 15)) * 128 + (((ks * 32 + (l >> 4) * 8) * 2) ^ ((l & 7) << 4));
                    f16x8 kf = *(const f16x8*)(Kb + boff);
                    s[n] = __builtin_amdgcn_mfma_f32_16x16x32_f16(kf, ks == 0 ? qf0 : qf1, s[n], 0, 0, 0);
                }
            }
            // scale + causal mask + in-register row max (row == lane's q)
            int rel = qg - kv0;
            float tmax = -1e30f;
#pragma unroll
            for (int n = 0; n < 4; n++) {
#pragma unroll
                for (int r = 0; r < 4; r++) {
                    int kvr = n * 16 + (l >> 4) * 4 + r;
                    float v = s[n][r] * scale;
                    v = (kvr <= rel) ? v : -1e30f;
                    s[n][r] = v;
                    tmax = fmaxf(tmax, v);
                }
            }
            tmax = fmaxf(tmax, __shfl_xor(tmax, 16));
            tmax = fmaxf(tmax, __shfl_xor(tmax, 32));
            float mnew = fmaxf(m_r, tmax);
            float alpha = __expf(m_r - mnew);
            m_r = mnew;
            // P = exp(S - m), packed b64 writes into per-wave LDS [q][kv] (stride 80)
            float rsum = 0.f;
#pragma unroll
            for (int n = 0; n < 4; n++) {
                f16x4v pk;
#pragma unroll
                for (int r = 0; r < 4; r++) {
                    float e = __expf(s[n][r] - mnew);
                    rsum += e;
                    pk[r] = (f16)e;
                }
                *(f16x4v*)(&Pw[(l & 15) * 80 + n * 16 + (l >> 4) * 4]) = pk;
            }
            rsum += __shfl_xor(rsum, 16);
            rsum += __shfl_xor(rsum, 32);
            l_r = l_r * alpha + rsum;
            // broadcast alpha to this lane's O rows, rescale O
            float ar[4];
#pragma unroll
            for (int r = 0; r < 4; r++) ar[r] = __shfl(alpha, (l >> 4) * 4 + r);
#pragma unroll
            for (int nf = 0; nf < 4; nf++)
#pragma unroll
                for (int r = 0; r < 4; r++) o[nf][r] *= ar[r];
            // P back as A-fragments (wave-private, in-order DS pipe)
            f16x8 pa0 = *(const f16x8*)(&Pw[(l & 15) * 80 + (l >> 4) * 8]);
            f16x8 pa1 = *(const f16x8*)(&Pw[(l & 15) * 80 + 32 + (l >> 4) * 8]);
            // O += P V
#pragma unroll
            for (int nf = 0; nf < 4; nf++) {
#pragma unroll
                for (int ks = 0; ks < 2; ks++) {
                    int boff = (nf * 16 + (l & 15)) * 128 + (((ks * 32 + (l >> 4) * 8) * 2) ^ ((l & 7) << 4));
                    f16x8 vf = *(const f16x8*)(Vb + boff);
                    o[nf] = __builtin_amdgcn_mfma_f32_16x16x32_f16(ks == 0 ? pa0 : pa1, vf, o[nf], 0, 0, 0);
                }
            }
            __syncthreads(); // drains next-tile glds + guards buffer reuse
        }
        // epilogue: O / l (l broadcast from stat lanes), store
        float lro[4];
#pragma unroll
        for (int r = 0; r < 4; r++) lro[r] = __shfl(l_r, (l >> 4) * 4 + r);
#pragma unroll
        for (int nf = 0; nf < 4; nf++) {
#pragma unroll
            for (int r = 0; r < 4; r++) {
                float v = o[nf][r] / lro[r];
                att[(size_t)(b * Tn + qo + r) * Cn + h * HSn + nf * 16 + (l & 15)] = (f16)v;
            }
        }
    }
}

// ---------------------------------------------------------------------------
extern "C" void kernel_launch(void* const* d_in, const int* in_sizes, int n_in,
                              void* d_out, int out_size, void* d_ws, size_t ws_size,
                              hipStream_t stream) {
    const float* x = (const float*)d_in[0];
    const float* Wq = (const float*)d_in[1];
    const float* Wk = (const float*)d_in[2];
    const float* Wv = (const float*)d_in[3];
    const float* p = (const float*)d_in[4];
    const float* Wproj = (const float*)d_in[5];
    const float* W1 = (const float*)d_in[6];
    const float* W2 = (const float*)d_in[7];
    const float* ln1w = (const float*)d_in[8];
    const float* ln1b = (const float*)d_in[9];
    const float* ln2w = (const float*)d_in[10];
    const float* ln2b = (const float*)d_in[11];

    char* ws = (char*)d_ws;
    const size_t MB = 1ull << 20;
    f16* Wqkv_t = (f16*)(ws + 0 * MB);   // [3072][1024]
    f16* Wproj_t = (f16*)(ws + 6 * MB);  // [1024][1024]
    f16* W1_t = (f16*)(ws + 8 * MB);     // [4096][1024]
    f16* W2_t = (f16*)(ws + 16 * MB);    // [1024][4096]
    float* x1 = (float*)(ws + 24 * MB);  // [4096][1024] f32
    f16* QKV = (f16*)(ws + 40 * MB);     // [4096][3072]
    f16* h1 = (f16*)(ws + 64 * MB);      // [4096][1024]
    f16* vTb = (f16*)(ws + 64 * MB);     // [32][64][2048] (reuses h1 slot)
    f16* attb = (f16*)(ws + 72 * MB);    // [4096][1024]
    f16* h2 = attb;                      // reuse (att dead after proj gemm)
    f16* ffh = QKV;                      // [4096][4096] spans 40M..72M
    float* out = (float*)d_out;

    // weight repack (transposed f16)
    tr_cast_qkv<<<dim3(32, 2, 48), 256, 0, stream>>>(Wq, Wk, Wv, Wqkv_t);
    tr_cast_f32<<<dim3(32, 32), 256, 0, stream>>>(Wproj, 1024, Wproj_t, 1024);
    tr_cast_f32<<<dim3(32, 128), 256, 0, stream>>>(W1, 4096, W1_t, 1024);
    tr_cast_f32<<<dim3(128, 32), 256, 0, stream>>>(W2, 1024, W2_t, 4096);

    // block forward
    ln_kernel<<<4096, 256, 0, stream>>>(x, ln1w, ln1b, h1);
    gemm_bt<0><<<dim3(32, 24), 256, 0, stream>>>(h1, Wqkv_t, QKV, nullptr, 4096, 3072, 1024);
    tr_vT<<<dim3(32, 1, 32), 256, 0, stream>>>(QKV, vTb);
    attn_kernel<<<512, 256, 0, stream>>>(QKV, vTb, p, attb);
    gemm_bt<2><<<dim3(32, 8), 256, 0, stream>>>(attb, Wproj_t, x1, x, 4096, 1024, 1024);
    ln_kernel<<<4096, 256, 0, stream>>>(x1, ln2w, ln2b, h2);
    gemm_bt<1><<<dim3(32, 32), 256, 0, stream>>>(h2, W1_t, ffh, nullptr, 4096, 4096, 1024);
    gemm_bt<2><<<dim3(32, 8), 256, 0, stream>>>(ffh, W2_t, out, x1, 4096, 1024, 4096);
}

// Round 3
// 262.034 us; speedup vs baseline: 1.2183x; 1.0847x over previous
//
#include <hip/hip_runtime.h>

// ---------------------------------------------------------------------------
// Transformer block forward on gfx950.  B=2 T=2048 C=1024 H=16 HS=64 FF=4096.
// All matmuls: f16 inputs, fp32 MFMA accumulation (16x16x32).
// R3: in-block split-K (8 waves, 2 K-groups) for the N=1024 GEMMs (proj, FF2)
//     to fix 1-wave/SIMD occupancy; XCD-aware block swizzle (T1) on GEMMs and
//     attention; s_setprio around attention MFMA clusters (T5).
// Workspace layout (80 MB):
//   [ 0, 6M)  Wqkv^T  f16 [3072][1024]
//   [ 6M, 8M) Wproj^T f16 [1024][1024]
//   [ 8M,16M) W1^T    f16 [4096][1024]
//   [16M,24M) W2^T    f16 [1024][4096]
//   [24M,40M) x1      f32 [4096][1024]
//   [40M,64M) QKV     f16 [4096][3072]
//   [64M,72M) h1 f16 [4096][1024], then vT f16 [32][64][2048] (reuse)
//   [72M,80M) att f16 [4096][1024], then h2 f16 (reuse)
//   ffh f16 [4096][4096] = [40M,72M)  (QKV+vT dead by then)
// ---------------------------------------------------------------------------

typedef _Float16 f16;
typedef _Float16 f16x8 __attribute__((ext_vector_type(8)));
typedef _Float16 f16x4v __attribute__((ext_vector_type(4)));
typedef float f32x4 __attribute__((ext_vector_type(4)));

static constexpr int Tn = 2048;
static constexpr int Cn = 1024;
static constexpr int HSn = 64;

// async global->LDS, 16B per lane; dest = wave-uniform base + lane*16
__device__ __forceinline__ void glds16(const f16* g, f16* l) {
    __builtin_amdgcn_global_load_lds((const __attribute__((address_space(1))) void*)g,
                                     (__attribute__((address_space(3))) void*)l,
                                     16, 0, 0);
}

// bijective XCD swizzle (valid when nwg % 8 == 0): contiguous tile chunk/XCD
__device__ __forceinline__ int xcd_swz(int wg, int nwg) {
    int cpx = nwg >> 3;
    return (wg & 7) * cpx + (wg >> 3);
}

// ---------------------------------------------------------------------------
// LayerNorm (fp32 in) -> f16 out.  One block per row, 256 threads.
// ---------------------------------------------------------------------------
__global__ __launch_bounds__(256) void ln_kernel(const float* __restrict__ x,
                                                 const float* __restrict__ w,
                                                 const float* __restrict__ b,
                                                 f16* __restrict__ out) {
    int row = blockIdx.x;
    const float* xr = x + (size_t)row * Cn;
    int tid = threadIdx.x, l = tid & 63, wv = tid >> 6;
    float4 v = *(const float4*)(xr + tid * 4);
    float s = v.x + v.y + v.z + v.w;
    float sq = v.x * v.x + v.y * v.y + v.z * v.z + v.w * v.w;
#pragma unroll
    for (int off = 32; off > 0; off >>= 1) {
        s += __shfl_down(s, off);
        sq += __shfl_down(sq, off);
    }
    __shared__ float red[8];
    if (l == 0) { red[wv] = s; red[wv + 4] = sq; }
    __syncthreads();
    float ts = red[0] + red[1] + red[2] + red[3];
    float tq = red[4] + red[5] + red[6] + red[7];
    float mean = ts * (1.0f / Cn);
    float var = tq * (1.0f / Cn) - mean * mean;
    float rstd = rsqrtf(var + 1e-5f);
    float4 wv4 = *(const float4*)(w + tid * 4);
    float4 bv4 = *(const float4*)(b + tid * 4);
    f16x4v o;
    o[0] = (f16)((v.x - mean) * rstd * wv4.x + bv4.x);
    o[1] = (f16)((v.y - mean) * rstd * wv4.y + bv4.y);
    o[2] = (f16)((v.z - mean) * rstd * wv4.z + bv4.z);
    o[3] = (f16)((v.w - mean) * rstd * wv4.w + bv4.w);
    *(f16x4v*)(out + (size_t)row * Cn + tid * 4) = o;
}

// ---------------------------------------------------------------------------
// Transpose + cast fp32 -> f16:  out[c][r] = in[r][c].  32x32 tiles.
// ---------------------------------------------------------------------------
__global__ __launch_bounds__(256) void tr_cast_f32(const float* __restrict__ in, int irs,
                                                   f16* __restrict__ out, int ors) {
    __shared__ float tile[32][33];
    int r0 = blockIdx.x * 32, c0 = blockIdx.y * 32;
    int t = threadIdx.x;
    int rr = t >> 3, c4 = (t & 7) * 4;
    float4 v = *(const float4*)(in + (size_t)(r0 + rr) * irs + c0 + c4);
    tile[rr][c4] = v.x; tile[rr][c4 + 1] = v.y; tile[rr][c4 + 2] = v.z; tile[rr][c4 + 3] = v.w;
    __syncthreads();
    int cc = t >> 3, r4 = (t & 7) * 4;
    f16x4v o;
    o[0] = (f16)tile[r4][cc];
    o[1] = (f16)tile[r4 + 1][cc];
    o[2] = (f16)tile[r4 + 2][cc];
    o[3] = (f16)tile[r4 + 3][cc];
    *(f16x4v*)(out + (size_t)(c0 + cc) * ors + r0 + r4) = o;
}

// Same, but gathers Wq/Wk/Wv [H][C][HS] into Wqkv^T rows n = qkv*1024 + h*64 + s.
__global__ __launch_bounds__(256) void tr_cast_qkv(const float* __restrict__ Wq,
                                                   const float* __restrict__ Wk,
                                                   const float* __restrict__ Wv,
                                                   f16* __restrict__ out) {
    int z = blockIdx.z;
    int qkv = z >> 4, h = z & 15;
    const float* in = (qkv == 0 ? Wq : qkv == 1 ? Wk : Wv) + (size_t)h * Cn * HSn; // [1024][64]
    f16* o = out + (size_t)(qkv * Cn + h * HSn) * Cn;
    __shared__ float tile[32][33];
    int r0 = blockIdx.x * 32, c0 = blockIdx.y * 32;
    int t = threadIdx.x;
    int rr = t >> 3, c4 = (t & 7) * 4;
    float4 v = *(const float4*)(in + (size_t)(r0 + rr) * HSn + c0 + c4);
    tile[rr][c4] = v.x; tile[rr][c4 + 1] = v.y; tile[rr][c4 + 2] = v.z; tile[rr][c4 + 3] = v.w;
    __syncthreads();
    int cc = t >> 3, r4 = (t & 7) * 4;
    f16x4v ov;
    ov[0] = (f16)tile[r4][cc];
    ov[1] = (f16)tile[r4 + 1][cc];
    ov[2] = (f16)tile[r4 + 2][cc];
    ov[3] = (f16)tile[r4 + 3][cc];
    *(f16x4v*)(o + (size_t)(c0 + cc) * Cn + r0 + r4) = ov;
}

// ---------------------------------------------------------------------------
// f16 transpose: vT[bh][s][t] = QKV[(b*T+t)][2048 + h*64 + s].  64x64 tiles.
// ---------------------------------------------------------------------------
__global__ __launch_bounds__(256) void tr_vT(const f16* __restrict__ QKV, f16* __restrict__ vT) {
    int bh = blockIdx.z;
    int b = bh >> 4, h = bh & 15;
    const f16* in = QKV + (size_t)b * Tn * 3072 + 2048 + h * HSn; // [T][64] stride 3072
    f16* out = vT + (size_t)bh * HSn * Tn;                        // [64][T]
    int r0 = blockIdx.x * 64;
    __shared__ __align__(16) f16 tile[64][72];
    int t = threadIdx.x;
#pragma unroll
    for (int i = 0; i < 2; i++) {
        int f = i * 256 + t;
        int rr = f >> 3, c8 = (f & 7) * 8;
        *(uint4*)(&tile[rr][c8]) = *(const uint4*)(in + (size_t)(r0 + rr) * 3072 + c8);
    }
    __syncthreads();
#pragma unroll
    for (int i = 0; i < 2; i++) {
        int f = i * 256 + t;
        int cc = f >> 3, r8 = (f & 7) * 8;
        union { f16 h[8]; uint4 v; } u;
#pragma unroll
        for (int j = 0; j < 8; j++) u.h[j] = tile[r8 + j][cc];
        *(uint4*)(out + (size_t)cc * Tn + r0 + r8) = u.v;
    }
}

// ---------------------------------------------------------------------------
// GEMM: C[M][N] = A[M][K] @ Bt[N][K]^T, f16 in, fp32 acc.
// 128x128 tile, BK=32, 4 waves.  glds staging, LDS dbuf, 1 barrier/K-step.
// EPI: 0 = store f16, 1 = relu -> f16, 2 = +resid(f32) -> f32.
// ---------------------------------------------------------------------------
template <int EPI>
__global__ __launch_bounds__(256) void gemm_bt(const f16* __restrict__ A, const f16* __restrict__ Bt,
                                               void* __restrict__ Cout, const float* __restrict__ resid,
                                               int M, int N, int K) {
    __shared__ __align__(16) f16 As[2][4096]; // [128][32] per buffer, linear
    __shared__ __align__(16) f16 Bs[2][4096];
    int nwgx = gridDim.x;
    int sw = xcd_swz(blockIdx.y * nwgx + blockIdx.x, nwgx * gridDim.y);
    int bm = sw % nwgx, bn = sw / nwgx;
    int tid = threadIdx.x, l = tid & 63, w = tid >> 6;
    int wr = w >> 1, wc = w & 1;
    f32x4 acc[4][4];
#pragma unroll
    for (int m = 0; m < 4; m++)
#pragma unroll
        for (int n = 0; n < 4; n++) acc[m][n] = f32x4{0.f, 0.f, 0.f, 0.f};

    const f16* ag = A + (size_t)(bm * 128 + (tid >> 2)) * K + (tid & 3) * 8;
    const f16* bg = Bt + (size_t)(bn * 128 + (tid >> 2)) * K + (tid & 3) * 8;
    const size_t half = (size_t)64 * K;
    int KT = K >> 5;
    int rbase = (wr * 64 + (l & 15)) * 32 + (l >> 4) * 8;
    int cbase = (wc * 64 + (l & 15)) * 32 + (l >> 4) * 8;

    auto stage = [&](int kt, int bf) {
        int k0 = kt * 32;
        glds16(ag + k0, &As[bf][w * 512]);
        glds16(ag + half + k0, &As[bf][2048 + w * 512]);
        glds16(bg + k0, &Bs[bf][w * 512]);
        glds16(bg + half + k0, &Bs[bf][2048 + w * 512]);
    };

    stage(0, 0);
    __syncthreads();
    for (int kt = 0; kt < KT; ++kt) {
        int cb = kt & 1;
        if (kt + 1 < KT) stage(kt + 1, cb ^ 1);
        f16x8 af[4], bfr[4];
#pragma unroll
        for (int m = 0; m < 4; m++) af[m] = *(const f16x8*)(&As[cb][rbase + m * 512]);
#pragma unroll
        for (int n = 0; n < 4; n++) bfr[n] = *(const f16x8*)(&Bs[cb][cbase + n * 512]);
#pragma unroll
        for (int m = 0; m < 4; m++)
#pragma unroll
            for (int n = 0; n < 4; n++)
                acc[m][n] = __builtin_amdgcn_mfma_f32_16x16x32_f16(af[m], bfr[n], acc[m][n], 0, 0, 0);
        __syncthreads();
    }

    int row0 = bm * 128 + wr * 64 + (l >> 4) * 4;
    int col0 = bn * 128 + wc * 64 + (l & 15);
#pragma unroll
    for (int m = 0; m < 4; m++) {
#pragma unroll
        for (int n = 0; n < 4; n++) {
#pragma unroll
            for (int r = 0; r < 4; r++) {
                size_t idx = (size_t)(row0 + m * 16 + r) * N + (col0 + n * 16);
                float v = acc[m][n][r];
                if constexpr (EPI == 0) ((f16*)Cout)[idx] = (f16)v;
                else if constexpr (EPI == 1) ((f16*)Cout)[idx] = (f16)fmaxf(v, 0.f);
                else ((float*)Cout)[idx] = v + resid[idx];
            }
        }
    }
}

// ---------------------------------------------------------------------------
// GEMM with in-block split-K: 512 threads = 2 groups x 4 waves.  Group g
// computes the 128x128 tile over K-range [g*K/2, (g+1)*K/2) with its own LDS
// double-buffer; group 1's accumulators are reduced into group 0 via LDS at
// the end.  Fixes 1-wave/SIMD occupancy for small-grid (N=1024) GEMMs.
// ---------------------------------------------------------------------------
template <int EPI>
__global__ __launch_bounds__(512) void gemm_ks(const f16* __restrict__ A, const f16* __restrict__ Bt,
                                               void* __restrict__ Cout, const float* __restrict__ resid,
                                               int M, int N, int K) {
    __shared__ __align__(16) char smem[65536];
    f16* As = (f16*)smem;            // [grp][buf][4096] = 32KB
    f16* Bs = (f16*)(smem + 32768);  // [grp][buf][4096] = 32KB
    int nwgx = gridDim.x;
    int sw = xcd_swz(blockIdx.y * nwgx + blockIdx.x, nwgx * gridDim.y);
    int bm = sw % nwgx, bn = sw / nwgx;
    int tid = threadIdx.x, l = tid & 63, w = tid >> 6;
    int grp = w >> 2, wl = w & 3;
    int wr = wl >> 1, wc = wl & 1;
    int Kh = K >> 1;
    int KT = Kh >> 5;

    f32x4 acc[4][4];
#pragma unroll
    for (int m = 0; m < 4; m++)
#pragma unroll
        for (int n = 0; n < 4; n++) acc[m][n] = f32x4{0.f, 0.f, 0.f, 0.f};

    // staging: group's 256 threads cover a 128x32 tile; instr j covers rows
    // [j*64, j*64+64); per-thread row = j*64 + wl*16 + (l>>2), chunk = l&3.
    const f16* agp = A + (size_t)(bm * 128 + wl * 16 + (l >> 2)) * K + grp * Kh + (l & 3) * 8;
    const f16* bgp = Bt + (size_t)(bn * 128 + wl * 16 + (l >> 2)) * K + grp * Kh + (l & 3) * 8;
    const size_t half = (size_t)64 * K;
    f16* Ab = As + grp * 8192;
    f16* Bb = Bs + grp * 8192;

    auto stage = [&](int kt, int bf) {
        size_t k0 = (size_t)kt * 32;
        glds16(agp + k0, Ab + bf * 4096 + wl * 512);
        glds16(agp + half + k0, Ab + bf * 4096 + 2048 + wl * 512);
        glds16(bgp + k0, Bb + bf * 4096 + wl * 512);
        glds16(bgp + half + k0, Bb + bf * 4096 + 2048 + wl * 512);
    };

    int rbase = (wr * 64 + (l & 15)) * 32 + (l >> 4) * 8;
    int cbase = (wc * 64 + (l & 15)) * 32 + (l >> 4) * 8;

    stage(0, 0);
    __syncthreads();
    for (int kt = 0; kt < KT; ++kt) {
        int cb = kt & 1;
        if (kt + 1 < KT) stage(kt + 1, cb ^ 1);
        f16x8 af[4], bfr[4];
#pragma unroll
        for (int m = 0; m < 4; m++) af[m] = *(const f16x8*)(Ab + cb * 4096 + rbase + m * 512);
#pragma unroll
        for (int n = 0; n < 4; n++) bfr[n] = *(const f16x8*)(Bb + cb * 4096 + cbase + n * 512);
#pragma unroll
        for (int m = 0; m < 4; m++)
#pragma unroll
            for (int n = 0; n < 4; n++)
                acc[m][n] = __builtin_amdgcn_mfma_f32_16x16x32_f16(af[m], bfr[n], acc[m][n], 0, 0, 0);
        __syncthreads();
    }

    // cross-group reduction: group1 -> LDS -> group0 (4 rounds, stride 20
    // floats per lane spreads b128 accesses across all 32 banks).
    float* red = (float*)smem;
#pragma unroll
    for (int m = 0; m < 4; m++) {
        if (grp == 1) {
#pragma unroll
            for (int n = 0; n < 4; n++)
                *(f32x4*)(red + wl * 1280 + l * 20 + n * 4) = acc[m][n];
        }
        __syncthreads();
        if (grp == 0) {
#pragma unroll
            for (int n = 0; n < 4; n++)
                acc[m][n] += *(const f32x4*)(red + wl * 1280 + l * 20 + n * 4);
        }
        __syncthreads();
    }

    if (grp == 0) {
        int row0 = bm * 128 + wr * 64 + (l >> 4) * 4;
        int col0 = bn * 128 + wc * 64 + (l & 15);
#pragma unroll
        for (int m = 0; m < 4; m++) {
#pragma unroll
            for (int n = 0; n < 4; n++) {
#pragma unroll
                for (int r = 0; r < 4; r++) {
                    size_t idx = (size_t)(row0 + m * 16 + r) * N + (col0 + n * 16);
                    float v = acc[m][n][r];
                    if constexpr (EPI == 0) ((f16*)Cout)[idx] = (f16)v;
                    else if constexpr (EPI == 1) ((f16*)Cout)[idx] = (f16)fmaxf(v, 0.f);
                    else ((float*)Cout)[idx] = v + resid[idx];
                }
            }
        }
    }
}

// ---------------------------------------------------------------------------
// Flash attention, causal.  Block = (bh, qtile-pair), swapped QK^T, glds
// staging with source-side swizzle, dbuf, setprio around MFMA clusters.
// ---------------------------------------------------------------------------
__global__ __launch_bounds__(256) void attn_kernel(const f16* __restrict__ QKV,
                                                   const f16* __restrict__ vT,
                                                   const float* __restrict__ p,
                                                   f16* __restrict__ att) {
    int sw = xcd_swz(blockIdx.x, gridDim.x);
    int pq = sw & 15, bh = sw >> 4;
    int b = bh >> 4, h = bh & 15;
    int tid = threadIdx.x, w = tid >> 6, l = tid & 63;
    float scale = rsqrtf(p[h]);

    __shared__ __align__(16) f16 Ks[2][4096];
    __shared__ __align__(16) f16 Vs[2][4096];
    __shared__ __align__(16) f16 Ps[4][16 * 80];
    f16* Pw = &Ps[w][0];

    int srow0 = tid >> 3;
    int c0 = (tid & 7) ^ (srow0 & 7);
    int srow1 = 32 + srow0;
    int c1 = (tid & 7) ^ (srow1 & 7);
    const f16* Kg = QKV + (size_t)b * Tn * 3072 + 1024 + h * HSn;
    const f16* Vg = vT + (size_t)bh * HSn * Tn;

    auto stageKV = [&](int kv0, int bf) {
        glds16(Kg + (size_t)(kv0 + srow0) * 3072 + c0 * 8, &Ks[bf][w * 512]);
        glds16(Kg + (size_t)(kv0 + srow1) * 3072 + c1 * 8, &Ks[bf][2048 + w * 512]);
        glds16(Vg + (size_t)srow0 * Tn + kv0 + c0 * 8, &Vs[bf][w * 512]);
        glds16(Vg + (size_t)srow1 * Tn + kv0 + c1 * 8, &Vs[bf][2048 + w * 512]);
    };

    for (int pass = 0; pass < 2; ++pass) {
        int qt = pass ? (31 - pq) : pq;
        int qg = qt * 64 + w * 16 + (l & 15);
        int qo = qt * 64 + w * 16 + (l >> 4) * 4;
        const f16* qptr = QKV + (size_t)(b * Tn + qg) * 3072 + h * HSn + (l >> 4) * 8;
        f16x8 qf0 = *(const f16x8*)(qptr);
        f16x8 qf1 = *(const f16x8*)(qptr + 32);

        f32x4 o[4];
#pragma unroll
        for (int nf = 0; nf < 4; nf++) o[nf] = f32x4{0.f, 0.f, 0.f, 0.f};
        float m_r = -1e30f, l_r = 0.f;

        int nt = qt + 1;
        stageKV(0, 0);
        __syncthreads();
        for (int t = 0; t < nt; ++t) {
            int cb = t & 1, kv0 = t * 64;
            if (t + 1 < nt) stageKV(kv0 + 64, cb ^ 1);
            const char* Kb = (const char*)&Ks[cb][0];
            const char* Vb = (const char*)&Vs[cb][0];
            f32x4 s[4];
#pragma unroll
            for (int n = 0; n < 4; n++) s[n] = f32x4{0.f, 0.f, 0.f, 0.f};
            __builtin_amdgcn_s_setprio(1);
#pragma unroll
            for (int n = 0; n < 4; n++) {
#pragma unroll
                for (int ks = 0; ks < 2; ks++) {
                    int boff = (n * 16 + (l & 15)) * 128 + (((ks * 32 + (l >> 4) * 8) * 2) ^ ((l & 7) << 4));
                    f16x8 kf = *(const f16x8*)(Kb + boff);
                    s[n] = __builtin_amdgcn_mfma_f32_16x16x32_f16(kf, ks == 0 ? qf0 : qf1, s[n], 0, 0, 0);
                }
            }
            __builtin_amdgcn_s_setprio(0);
            int rel = qg - kv0;
            float tmax = -1e30f;
#pragma unroll
            for (int n = 0; n < 4; n++) {
#pragma unroll
                for (int r = 0; r < 4; r++) {
                    int kvr = n * 16 + (l >> 4) * 4 + r;
                    float v = s[n][r] * scale;
                    v = (kvr <= rel) ? v : -1e30f;
                    s[n][r] = v;
                    tmax = fmaxf(tmax, v);
                }
            }
            tmax = fmaxf(tmax, __shfl_xor(tmax, 16));
            tmax = fmaxf(tmax, __shfl_xor(tmax, 32));
            float mnew = fmaxf(m_r, tmax);
            float alpha = __expf(m_r - mnew);
            m_r = mnew;
            float rsum = 0.f;
#pragma unroll
            for (int n = 0; n < 4; n++) {
                f16x4v pk;
#pragma unroll
                for (int r = 0; r < 4; r++) {
                    float e = __expf(s[n][r] - mnew);
                    rsum += e;
                    pk[r] = (f16)e;
                }
                *(f16x4v*)(&Pw[(l & 15) * 80 + n * 16 + (l >> 4) * 4]) = pk;
            }
            rsum += __shfl_xor(rsum, 16);
            rsum += __shfl_xor(rsum, 32);
            l_r = l_r * alpha + rsum;
            float ar[4];
#pragma unroll
            for (int r = 0; r < 4; r++) ar[r] = __shfl(alpha, (l >> 4) * 4 + r);
#pragma unroll
            for (int nf = 0; nf < 4; nf++)
#pragma unroll
                for (int r = 0; r < 4; r++) o[nf][r] *= ar[r];
            f16x8 pa0 = *(const f16x8*)(&Pw[(l & 15) * 80 + (l >> 4) * 8]);
            f16x8 pa1 = *(const f16x8*)(&Pw[(l & 15) * 80 + 32 + (l >> 4) * 8]);
            __builtin_amdgcn_s_setprio(1);
#pragma unroll
            for (int nf = 0; nf < 4; nf++) {
#pragma unroll
                for (int ks = 0; ks < 2; ks++) {
                    int boff = (nf * 16 + (l & 15)) * 128 + (((ks * 32 + (l >> 4) * 8) * 2) ^ ((l & 7) << 4));
                    f16x8 vf = *(const f16x8*)(Vb + boff);
                    o[nf] = __builtin_amdgcn_mfma_f32_16x16x32_f16(ks == 0 ? pa0 : pa1, vf, o[nf], 0, 0, 0);
                }
            }
            __builtin_amdgcn_s_setprio(0);
            __syncthreads();
        }
        float lro[4];
#pragma unroll
        for (int r = 0; r < 4; r++) lro[r] = __shfl(l_r, (l >> 4) * 4 + r);
#pragma unroll
        for (int nf = 0; nf < 4; nf++) {
#pragma unroll
            for (int r = 0; r < 4; r++) {
                float v = o[nf][r] / lro[r];
                att[(size_t)(b * Tn + qo + r) * Cn + h * HSn + nf * 16 + (l & 15)] = (f16)v;
            }
        }
    }
}

// ---------------------------------------------------------------------------
extern "C" void kernel_launch(void* const* d_in, const int* in_sizes, int n_in,
                              void* d_out, int out_size, void* d_ws, size_t ws_size,
                              hipStream_t stream) {
    const float* x = (const float*)d_in[0];
    const float* Wq = (const float*)d_in[1];
    const float* Wk = (const float*)d_in[2];
    const float* Wv = (const float*)d_in[3];
    const float* p = (const float*)d_in[4];
    const float* Wproj = (const float*)d_in[5];
    const float* W1 = (const float*)d_in[6];
    const float* W2 = (const float*)d_in[7];
    const float* ln1w = (const float*)d_in[8];
    const float* ln1b = (const float*)d_in[9];
    const float* ln2w = (const float*)d_in[10];
    const float* ln2b = (const float*)d_in[11];

    char* ws = (char*)d_ws;
    const size_t MB = 1ull << 20;
    f16* Wqkv_t = (f16*)(ws + 0 * MB);   // [3072][1024]
    f16* Wproj_t = (f16*)(ws + 6 * MB);  // [1024][1024]
    f16* W1_t = (f16*)(ws + 8 * MB);     // [4096][1024]
    f16* W2_t = (f16*)(ws + 16 * MB);    // [1024][4096]
    float* x1 = (float*)(ws + 24 * MB);  // [4096][1024] f32
    f16* QKV = (f16*)(ws + 40 * MB);     // [4096][3072]
    f16* h1 = (f16*)(ws + 64 * MB);      // [4096][1024]
    f16* vTb = (f16*)(ws + 64 * MB);     // [32][64][2048] (reuses h1 slot)
    f16* attb = (f16*)(ws + 72 * MB);    // [4096][1024]
    f16* h2 = attb;                      // reuse (att dead after proj gemm)
    f16* ffh = QKV;                      // [4096][4096] spans 40M..72M
    float* out = (float*)d_out;

    // weight repack (transposed f16)
    tr_cast_qkv<<<dim3(32, 2, 48), 256, 0, stream>>>(Wq, Wk, Wv, Wqkv_t);
    tr_cast_f32<<<dim3(32, 32), 256, 0, stream>>>(Wproj, 1024, Wproj_t, 1024);
    tr_cast_f32<<<dim3(32, 128), 256, 0, stream>>>(W1, 4096, W1_t, 1024);
    tr_cast_f32<<<dim3(128, 32), 256, 0, stream>>>(W2, 1024, W2_t, 4096);

    // block forward
    ln_kernel<<<4096, 256, 0, stream>>>(x, ln1w, ln1b, h1);
    gemm_bt<0><<<dim3(32, 24), 256, 0, stream>>>(h1, Wqkv_t, QKV, nullptr, 4096, 3072, 1024);
    tr_vT<<<dim3(32, 1, 32), 256, 0, stream>>>(QKV, vTb);
    attn_kernel<<<512, 256, 0, stream>>>(QKV, vTb, p, attb);
    gemm_ks<2><<<dim3(32, 8), 512, 0, stream>>>(attb, Wproj_t, x1, x, 4096, 1024, 1024);
    ln_kernel<<<4096, 256, 0, stream>>>(x1, ln2w, ln2b, h2);
    gemm_bt<1><<<dim3(32, 32), 256, 0, stream>>>(h2, W1_t, ffh, nullptr, 4096, 4096, 1024);
    gemm_ks<2><<<dim3(32, 8), 512, 0, stream>>>(ffh, W2_t, out, x1, 4096, 1024, 4096);
}

// Round 4
// 261.100 us; speedup vs baseline: 1.2227x; 1.0036x over previous
//
#include <hip/hip_runtime.h>

// ---------------------------------------------------------------------------
// Transformer block forward on gfx950.  B=2 T=2048 C=1024 H=16 HS=64 FF=4096.
// All matmuls: f16 inputs, fp32 MFMA accumulation (16x16x32).
// R4: counted-vmcnt pipeline (T4): 3 LDS buffers, prefetch depth 2,
//     s_waitcnt vmcnt(4) + raw s_barrier per K-step (vmcnt(0) only on the
//     last iter) in gemm_bt, gemm_ks, and attn.  Replaces the 2-phase
//     __syncthreads drain (the m97-structure ~20% stall).
// Workspace layout (80 MB): unchanged from R3.
// ---------------------------------------------------------------------------

typedef _Float16 f16;
typedef _Float16 f16x8 __attribute__((ext_vector_type(8)));
typedef _Float16 f16x4v __attribute__((ext_vector_type(4)));
typedef float f32x4 __attribute__((ext_vector_type(4)));

static constexpr int Tn = 2048;
static constexpr int Cn = 1024;
static constexpr int HSn = 64;

// async global->LDS, 16B per lane; dest = wave-uniform base + lane*16
__device__ __forceinline__ void glds16(const f16* g, f16* l) {
    __builtin_amdgcn_global_load_lds((const __attribute__((address_space(1))) void*)g,
                                     (__attribute__((address_space(3))) void*)l,
                                     16, 0, 0);
}

// bijective XCD swizzle (valid when nwg % 8 == 0): contiguous tile chunk/XCD
__device__ __forceinline__ int xcd_swz(int wg, int nwg) {
    int cpx = nwg >> 3;
    return (wg & 7) * cpx + (wg >> 3);
}

// wait until at most N vector-memory ops outstanding (oldest retire first)
#define VMCNT(N) asm volatile("s_waitcnt vmcnt(" #N ")" ::: "memory")

// ---------------------------------------------------------------------------
// LayerNorm (fp32 in) -> f16 out.  One block per row, 256 threads.
// ---------------------------------------------------------------------------
__global__ __launch_bounds__(256) void ln_kernel(const float* __restrict__ x,
                                                 const float* __restrict__ w,
                                                 const float* __restrict__ b,
                                                 f16* __restrict__ out) {
    int row = blockIdx.x;
    const float* xr = x + (size_t)row * Cn;
    int tid = threadIdx.x, l = tid & 63, wv = tid >> 6;
    float4 v = *(const float4*)(xr + tid * 4);
    float s = v.x + v.y + v.z + v.w;
    float sq = v.x * v.x + v.y * v.y + v.z * v.z + v.w * v.w;
#pragma unroll
    for (int off = 32; off > 0; off >>= 1) {
        s += __shfl_down(s, off);
        sq += __shfl_down(sq, off);
    }
    __shared__ float red[8];
    if (l == 0) { red[wv] = s; red[wv + 4] = sq; }
    __syncthreads();
    float ts = red[0] + red[1] + red[2] + red[3];
    float tq = red[4] + red[5] + red[6] + red[7];
    float mean = ts * (1.0f / Cn);
    float var = tq * (1.0f / Cn) - mean * mean;
    float rstd = rsqrtf(var + 1e-5f);
    float4 wv4 = *(const float4*)(w + tid * 4);
    float4 bv4 = *(const float4*)(b + tid * 4);
    f16x4v o;
    o[0] = (f16)((v.x - mean) * rstd * wv4.x + bv4.x);
    o[1] = (f16)((v.y - mean) * rstd * wv4.y + bv4.y);
    o[2] = (f16)((v.z - mean) * rstd * wv4.z + bv4.z);
    o[3] = (f16)((v.w - mean) * rstd * wv4.w + bv4.w);
    *(f16x4v*)(out + (size_t)row * Cn + tid * 4) = o;
}

// ---------------------------------------------------------------------------
// Transpose + cast fp32 -> f16:  out[c][r] = in[r][c].  32x32 tiles.
// ---------------------------------------------------------------------------
__global__ __launch_bounds__(256) void tr_cast_f32(const float* __restrict__ in, int irs,
                                                   f16* __restrict__ out, int ors) {
    __shared__ float tile[32][33];
    int r0 = blockIdx.x * 32, c0 = blockIdx.y * 32;
    int t = threadIdx.x;
    int rr = t >> 3, c4 = (t & 7) * 4;
    float4 v = *(const float4*)(in + (size_t)(r0 + rr) * irs + c0 + c4);
    tile[rr][c4] = v.x; tile[rr][c4 + 1] = v.y; tile[rr][c4 + 2] = v.z; tile[rr][c4 + 3] = v.w;
    __syncthreads();
    int cc = t >> 3, r4 = (t & 7) * 4;
    f16x4v o;
    o[0] = (f16)tile[r4][cc];
    o[1] = (f16)tile[r4 + 1][cc];
    o[2] = (f16)tile[r4 + 2][cc];
    o[3] = (f16)tile[r4 + 3][cc];
    *(f16x4v*)(out + (size_t)(c0 + cc) * ors + r0 + r4) = o;
}

// Same, but gathers Wq/Wk/Wv [H][C][HS] into Wqkv^T rows n = qkv*1024 + h*64 + s.
__global__ __launch_bounds__(256) void tr_cast_qkv(const float* __restrict__ Wq,
                                                   const float* __restrict__ Wk,
                                                   const float* __restrict__ Wv,
                                                   f16* __restrict__ out) {
    int z = blockIdx.z;
    int qkv = z >> 4, h = z & 15;
    const float* in = (qkv == 0 ? Wq : qkv == 1 ? Wk : Wv) + (size_t)h * Cn * HSn; // [1024][64]
    f16* o = out + (size_t)(qkv * Cn + h * HSn) * Cn;
    __shared__ float tile[32][33];
    int r0 = blockIdx.x * 32, c0 = blockIdx.y * 32;
    int t = threadIdx.x;
    int rr = t >> 3, c4 = (t & 7) * 4;
    float4 v = *(const float4*)(in + (size_t)(r0 + rr) * HSn + c0 + c4);
    tile[rr][c4] = v.x; tile[rr][c4 + 1] = v.y; tile[rr][c4 + 2] = v.z; tile[rr][c4 + 3] = v.w;
    __syncthreads();
    int cc = t >> 3, r4 = (t & 7) * 4;
    f16x4v ov;
    ov[0] = (f16)tile[r4][cc];
    ov[1] = (f16)tile[r4 + 1][cc];
    ov[2] = (f16)tile[r4 + 2][cc];
    ov[3] = (f16)tile[r4 + 3][cc];
    *(f16x4v*)(o + (size_t)(c0 + cc) * Cn + r0 + r4) = ov;
}

// ---------------------------------------------------------------------------
// f16 transpose: vT[bh][s][t] = QKV[(b*T+t)][2048 + h*64 + s].  64x64 tiles.
// ---------------------------------------------------------------------------
__global__ __launch_bounds__(256) void tr_vT(const f16* __restrict__ QKV, f16* __restrict__ vT) {
    int bh = blockIdx.z;
    int b = bh >> 4, h = bh & 15;
    const f16* in = QKV + (size_t)b * Tn * 3072 + 2048 + h * HSn; // [T][64] stride 3072
    f16* out = vT + (size_t)bh * HSn * Tn;                        // [64][T]
    int r0 = blockIdx.x * 64;
    __shared__ __align__(16) f16 tile[64][72];
    int t = threadIdx.x;
#pragma unroll
    for (int i = 0; i < 2; i++) {
        int f = i * 256 + t;
        int rr = f >> 3, c8 = (f & 7) * 8;
        *(uint4*)(&tile[rr][c8]) = *(const uint4*)(in + (size_t)(r0 + rr) * 3072 + c8);
    }
    __syncthreads();
#pragma unroll
    for (int i = 0; i < 2; i++) {
        int f = i * 256 + t;
        int cc = f >> 3, r8 = (f & 7) * 8;
        union { f16 h[8]; uint4 v; } u;
#pragma unroll
        for (int j = 0; j < 8; j++) u.h[j] = tile[r8 + j][cc];
        *(uint4*)(out + (size_t)cc * Tn + r0 + r8) = u.v;
    }
}

// ---------------------------------------------------------------------------
// GEMM: C[M][N] = A[M][K] @ Bt[N][K]^T, f16 in, fp32 acc.
// 128x128 tile, BK=32, 4 waves.  glds staging, 3-buffer rotation, counted
// vmcnt (steady-state vmcnt(4), never 0), one raw barrier per K-step.
// EPI: 0 = store f16, 1 = relu -> f16, 2 = +resid(f32) -> f32.
// ---------------------------------------------------------------------------
template <int EPI>
__global__ __launch_bounds__(256) void gemm_bt(const f16* __restrict__ A, const f16* __restrict__ Bt,
                                               void* __restrict__ Cout, const float* __restrict__ resid,
                                               int M, int N, int K) {
    __shared__ __align__(16) f16 As[3][4096]; // [128][32] per buffer, linear
    __shared__ __align__(16) f16 Bs[3][4096];
    int nwgx = gridDim.x;
    int sw = xcd_swz(blockIdx.y * nwgx + blockIdx.x, nwgx * gridDim.y);
    int bm = sw % nwgx, bn = sw / nwgx;
    int tid = threadIdx.x, l = tid & 63, w = tid >> 6;
    int wr = w >> 1, wc = w & 1;
    f32x4 acc[4][4];
#pragma unroll
    for (int m = 0; m < 4; m++)
#pragma unroll
        for (int n = 0; n < 4; n++) acc[m][n] = f32x4{0.f, 0.f, 0.f, 0.f};

    const f16* ag = A + (size_t)(bm * 128 + (tid >> 2)) * K + (tid & 3) * 8;
    const f16* bg = Bt + (size_t)(bn * 128 + (tid >> 2)) * K + (tid & 3) * 8;
    const size_t half = (size_t)64 * K;
    int KT = K >> 5;
    int rbase = (wr * 64 + (l & 15)) * 32 + (l >> 4) * 8;
    int cbase = (wc * 64 + (l & 15)) * 32 + (l >> 4) * 8;

    auto stage = [&](int kt, int bf) {
        int k0 = kt * 32;
        glds16(ag + k0, &As[bf][w * 512]);
        glds16(ag + half + k0, &As[bf][2048 + w * 512]);
        glds16(bg + k0, &Bs[bf][w * 512]);
        glds16(bg + half + k0, &Bs[bf][2048 + w * 512]);
    };

    stage(0, 0);
    if (KT > 1) stage(1, 1);
    int cb = 0, nb = 2; // compute buffer, next buffer to fill
    for (int kt = 0; kt < KT; ++kt) {
        if (kt + 1 < KT) VMCNT(4);  // tile kt landed; kt+1 (+kt+2) in flight
        else VMCNT(0);
        __builtin_amdgcn_s_barrier();
        if (kt + 2 < KT) { stage(kt + 2, nb); nb = (nb == 2) ? 0 : nb + 1; }
        f16x8 af[4], bfr[4];
#pragma unroll
        for (int m = 0; m < 4; m++) af[m] = *(const f16x8*)(&As[cb][rbase + m * 512]);
#pragma unroll
        for (int n = 0; n < 4; n++) bfr[n] = *(const f16x8*)(&Bs[cb][cbase + n * 512]);
#pragma unroll
        for (int m = 0; m < 4; m++)
#pragma unroll
            for (int n = 0; n < 4; n++)
                acc[m][n] = __builtin_amdgcn_mfma_f32_16x16x32_f16(af[m], bfr[n], acc[m][n], 0, 0, 0);
        cb = (cb == 2) ? 0 : cb + 1;
    }

    int row0 = bm * 128 + wr * 64 + (l >> 4) * 4;
    int col0 = bn * 128 + wc * 64 + (l & 15);
#pragma unroll
    for (int m = 0; m < 4; m++) {
#pragma unroll
        for (int n = 0; n < 4; n++) {
#pragma unroll
            for (int r = 0; r < 4; r++) {
                size_t idx = (size_t)(row0 + m * 16 + r) * N + (col0 + n * 16);
                float v = acc[m][n][r];
                if constexpr (EPI == 0) ((f16*)Cout)[idx] = (f16)v;
                else if constexpr (EPI == 1) ((f16*)Cout)[idx] = (f16)fmaxf(v, 0.f);
                else ((float*)Cout)[idx] = v + resid[idx];
            }
        }
    }
}

// ---------------------------------------------------------------------------
// GEMM with in-block split-K: 512 threads = 2 groups x 4 waves, each group
// covering half of K with its own 3-buffer counted-vmcnt pipeline (groups
// have identical KT, so the per-iter raw barriers stay collective).  Group 1
// accumulators reduced into group 0 via LDS at the end.
// ---------------------------------------------------------------------------
template <int EPI>
__global__ __launch_bounds__(512) void gemm_ks(const f16* __restrict__ A, const f16* __restrict__ Bt,
                                               void* __restrict__ Cout, const float* __restrict__ resid,
                                               int M, int N, int K) {
    __shared__ __align__(16) char smem[98304];
    f16* As = (f16*)smem;            // [grp][3][4096] = 48KB
    f16* Bs = (f16*)(smem + 49152);  // [grp][3][4096] = 48KB
    int nwgx = gridDim.x;
    int sw = xcd_swz(blockIdx.y * nwgx + blockIdx.x, nwgx * gridDim.y);
    int bm = sw % nwgx, bn = sw / nwgx;
    int tid = threadIdx.x, l = tid & 63, w = tid >> 6;
    int grp = w >> 2, wl = w & 3;
    int wr = wl >> 1, wc = wl & 1;
    int Kh = K >> 1;
    int KT = Kh >> 5;

    f32x4 acc[4][4];
#pragma unroll
    for (int m = 0; m < 4; m++)
#pragma unroll
        for (int n = 0; n < 4; n++) acc[m][n] = f32x4{0.f, 0.f, 0.f, 0.f};

    const f16* agp = A + (size_t)(bm * 128 + wl * 16 + (l >> 2)) * K + grp * Kh + (l & 3) * 8;
    const f16* bgp = Bt + (size_t)(bn * 128 + wl * 16 + (l >> 2)) * K + grp * Kh + (l & 3) * 8;
    const size_t half = (size_t)64 * K;
    f16* Ab = As + grp * 12288;
    f16* Bb = Bs + grp * 12288;

    auto stage = [&](int kt, int bf) {
        size_t k0 = (size_t)kt * 32;
        glds16(agp + k0, Ab + bf * 4096 + wl * 512);
        glds16(agp + half + k0, Ab + bf * 4096 + 2048 + wl * 512);
        glds16(bgp + k0, Bb + bf * 4096 + wl * 512);
        glds16(bgp + half + k0, Bb + bf * 4096 + 2048 + wl * 512);
    };

    int rbase = (wr * 64 + (l & 15)) * 32 + (l >> 4) * 8;
    int cbase = (wc * 64 + (l & 15)) * 32 + (l >> 4) * 8;

    stage(0, 0);
    if (KT > 1) stage(1, 1);
    int cb = 0, nb = 2;
    for (int kt = 0; kt < KT; ++kt) {
        if (kt + 1 < KT) VMCNT(4);
        else VMCNT(0);
        __builtin_amdgcn_s_barrier();
        if (kt + 2 < KT) { stage(kt + 2, nb); nb = (nb == 2) ? 0 : nb + 1; }
        f16x8 af[4], bfr[4];
#pragma unroll
        for (int m = 0; m < 4; m++) af[m] = *(const f16x8*)(Ab + cb * 4096 + rbase + m * 512);
#pragma unroll
        for (int n = 0; n < 4; n++) bfr[n] = *(const f16x8*)(Bb + cb * 4096 + cbase + n * 512);
#pragma unroll
        for (int m = 0; m < 4; m++)
#pragma unroll
            for (int n = 0; n < 4; n++)
                acc[m][n] = __builtin_amdgcn_mfma_f32_16x16x32_f16(af[m], bfr[n], acc[m][n], 0, 0, 0);
        cb = (cb == 2) ? 0 : cb + 1;
    }
    __syncthreads(); // all compute done before reduction scratch reuses smem

    // cross-group reduction: group1 -> LDS -> group0 (stride-20 spreads banks)
    float* red = (float*)smem;
#pragma unroll
    for (int m = 0; m < 4; m++) {
        if (grp == 1) {
#pragma unroll
            for (int n = 0; n < 4; n++)
                *(f32x4*)(red + wl * 1280 + l * 20 + n * 4) = acc[m][n];
        }
        __syncthreads();
        if (grp == 0) {
#pragma unroll
            for (int n = 0; n < 4; n++)
                acc[m][n] += *(const f32x4*)(red + wl * 1280 + l * 20 + n * 4);
        }
        __syncthreads();
    }

    if (grp == 0) {
        int row0 = bm * 128 + wr * 64 + (l >> 4) * 4;
        int col0 = bn * 128 + wc * 64 + (l & 15);
#pragma unroll
        for (int m = 0; m < 4; m++) {
#pragma unroll
            for (int n = 0; n < 4; n++) {
#pragma unroll
                for (int r = 0; r < 4; r++) {
                    size_t idx = (size_t)(row0 + m * 16 + r) * N + (col0 + n * 16);
                    float v = acc[m][n][r];
                    if constexpr (EPI == 0) ((f16*)Cout)[idx] = (f16)v;
                    else if constexpr (EPI == 1) ((f16*)Cout)[idx] = (f16)fmaxf(v, 0.f);
                    else ((float*)Cout)[idx] = v + resid[idx];
                }
            }
        }
    }
}

// ---------------------------------------------------------------------------
// Flash attention, causal.  Block = (bh, qtile-pair), swapped QK^T, glds
// staging with source-side swizzle, 3-buffer counted-vmcnt pipeline,
// setprio around MFMA clusters.
// ---------------------------------------------------------------------------
__global__ __launch_bounds__(256) void attn_kernel(const f16* __restrict__ QKV,
                                                   const f16* __restrict__ vT,
                                                   const float* __restrict__ p,
                                                   f16* __restrict__ att) {
    int sw = xcd_swz(blockIdx.x, gridDim.x);
    int pq = sw & 15, bh = sw >> 4;
    int b = bh >> 4, h = bh & 15;
    int tid = threadIdx.x, w = tid >> 6, l = tid & 63;
    float scale = rsqrtf(p[h]);

    __shared__ __align__(16) f16 Ks[3][4096];
    __shared__ __align__(16) f16 Vs[3][4096];
    __shared__ __align__(16) f16 Ps[4][16 * 80];
    f16* Pw = &Ps[w][0];

    int srow0 = tid >> 3;
    int c0 = (tid & 7) ^ (srow0 & 7);
    int srow1 = 32 + srow0;
    int c1 = (tid & 7) ^ (srow1 & 7);
    const f16* Kg = QKV + (size_t)b * Tn * 3072 + 1024 + h * HSn;
    const f16* Vg = vT + (size_t)bh * HSn * Tn;

    auto stageKV = [&](int kv0, int bf) {
        glds16(Kg + (size_t)(kv0 + srow0) * 3072 + c0 * 8, &Ks[bf][w * 512]);
        glds16(Kg + (size_t)(kv0 + srow1) * 3072 + c1 * 8, &Ks[bf][2048 + w * 512]);
        glds16(Vg + (size_t)srow0 * Tn + kv0 + c0 * 8, &Vs[bf][w * 512]);
        glds16(Vg + (size_t)srow1 * Tn + kv0 + c1 * 8, &Vs[bf][2048 + w * 512]);
    };

    for (int pass = 0; pass < 2; ++pass) {
        int qt = pass ? (31 - pq) : pq;
        int qg = qt * 64 + w * 16 + (l & 15);
        int qo = qt * 64 + w * 16 + (l >> 4) * 4;
        const f16* qptr = QKV + (size_t)(b * Tn + qg) * 3072 + h * HSn + (l >> 4) * 8;
        f16x8 qf0 = *(const f16x8*)(qptr);
        f16x8 qf1 = *(const f16x8*)(qptr + 32);

        f32x4 o[4];
#pragma unroll
        for (int nf = 0; nf < 4; nf++) o[nf] = f32x4{0.f, 0.f, 0.f, 0.f};
        float m_r = -1e30f, l_r = 0.f;

        int nt = qt + 1;
        stageKV(0, 0);
        if (nt > 1) stageKV(64, 1);
        int cb = 0, nb = 2;
        for (int t = 0; t < nt; ++t) {
            if (t + 1 < nt) VMCNT(4);
            else VMCNT(0);
            __builtin_amdgcn_s_barrier();
            if (t + 2 < nt) { stageKV((t + 2) * 64, nb); nb = (nb == 2) ? 0 : nb + 1; }
            int kv0 = t * 64;
            const char* Kb = (const char*)&Ks[cb][0];
            const char* Vb = (const char*)&Vs[cb][0];
            f32x4 s[4];
#pragma unroll
            for (int n = 0; n < 4; n++) s[n] = f32x4{0.f, 0.f, 0.f, 0.f};
            __builtin_amdgcn_s_setprio(1);
#pragma unroll
            for (int n = 0; n < 4; n++) {
#pragma unroll
                for (int ks = 0; ks < 2; ks++) {
                    int boff = (n * 16 + (l & 15)) * 128 + (((ks * 32 + (l >> 4) * 8) * 2) ^ ((l & 7) << 4));
                    f16x8 kf = *(const f16x8*)(Kb + boff);
                    s[n] = __builtin_amdgcn_mfma_f32_16x16x32_f16(kf, ks == 0 ? qf0 : qf1, s[n], 0, 0, 0);
                }
            }
            __builtin_amdgcn_s_setprio(0);
            int rel = qg - kv0;
            float tmax = -1e30f;
#pragma unroll
            for (int n = 0; n < 4; n++) {
#pragma unroll
                for (int r = 0; r < 4; r++) {
                    int kvr = n * 16 + (l >> 4) * 4 + r;
                    float v = s[n][r] * scale;
                    v = (kvr <= rel) ? v : -1e30f;
                    s[n][r] = v;
                    tmax = fmaxf(tmax, v);
                }
            }
            tmax = fmaxf(tmax, __shfl_xor(tmax, 16));
            tmax = fmaxf(tmax, __shfl_xor(tmax, 32));
            float mnew = fmaxf(m_r, tmax);
            float alpha = __expf(m_r - mnew);
            m_r = mnew;
            float rsum = 0.f;
#pragma unroll
            for (int n = 0; n < 4; n++) {
                f16x4v pk;
#pragma unroll
                for (int r = 0; r < 4; r++) {
                    float e = __expf(s[n][r] - mnew);
                    rsum += e;
                    pk[r] = (f16)e;
                }
                *(f16x4v*)(&Pw[(l & 15) * 80 + n * 16 + (l >> 4) * 4]) = pk;
            }
            rsum += __shfl_xor(rsum, 16);
            rsum += __shfl_xor(rsum, 32);
            l_r = l_r * alpha + rsum;
            float ar[4];
#pragma unroll
            for (int r = 0; r < 4; r++) ar[r] = __shfl(alpha, (l >> 4) * 4 + r);
#pragma unroll
            for (int nf = 0; nf < 4; nf++)
#pragma unroll
                for (int r = 0; r < 4; r++) o[nf][r] *= ar[r];
            f16x8 pa0 = *(const f16x8*)(&Pw[(l & 15) * 80 + (l >> 4) * 8]);
            f16x8 pa1 = *(const f16x8*)(&Pw[(l & 15) * 80 + 32 + (l >> 4) * 8]);
            __builtin_amdgcn_s_setprio(1);
#pragma unroll
            for (int nf = 0; nf < 4; nf++) {
#pragma unroll
                for (int ks = 0; ks < 2; ks++) {
                    int boff = (nf * 16 + (l & 15)) * 128 + (((ks * 32 + (l >> 4) * 8) * 2) ^ ((l & 7) << 4));
                    f16x8 vf = *(const f16x8*)(Vb + boff);
                    o[nf] = __builtin_amdgcn_mfma_f32_16x16x32_f16(ks == 0 ? pa0 : pa1, vf, o[nf], 0, 0, 0);
                }
            }
            __builtin_amdgcn_s_setprio(0);
            cb = (cb == 2) ? 0 : cb + 1;
        }
        __syncthreads(); // all waves done with K/V buffers before next pass restages
        float lro[4];
#pragma unroll
        for (int r = 0; r < 4; r++) lro[r] = __shfl(l_r, (l >> 4) * 4 + r);
#pragma unroll
        for (int nf = 0; nf < 4; nf++) {
#pragma unroll
            for (int r = 0; r < 4; r++) {
                float v = o[nf][r] / lro[r];
                att[(size_t)(b * Tn + qo + r) * Cn + h * HSn + nf * 16 + (l & 15)] = (f16)v;
            }
        }
    }
}

// ---------------------------------------------------------------------------
extern "C" void kernel_launch(void* const* d_in, const int* in_sizes, int n_in,
                              void* d_out, int out_size, void* d_ws, size_t ws_size,
                              hipStream_t stream) {
    const float* x = (const float*)d_in[0];
    const float* Wq = (const float*)d_in[1];
    const float* Wk = (const float*)d_in[2];
    const float* Wv = (const float*)d_in[3];
    const float* p = (const float*)d_in[4];
    const float* Wproj = (const float*)d_in[5];
    const float* W1 = (const float*)d_in[6];
    const float* W2 = (const float*)d_in[7];
    const float* ln1w = (const float*)d_in[8];
    const float* ln1b = (const float*)d_in[9];
    const float* ln2w = (const float*)d_in[10];
    const float* ln2b = (const float*)d_in[11];

    char* ws = (char*)d_ws;
    const size_t MB = 1ull << 20;
    f16* Wqkv_t = (f16*)(ws + 0 * MB);   // [3072][1024]
    f16* Wproj_t = (f16*)(ws + 6 * MB);  // [1024][1024]
    f16* W1_t = (f16*)(ws + 8 * MB);     // [4096][1024]
    f16* W2_t = (f16*)(ws + 16 * MB);    // [1024][4096]
    float* x1 = (float*)(ws + 24 * MB);  // [4096][1024] f32
    f16* QKV = (f16*)(ws + 40 * MB);     // [4096][3072]
    f16* h1 = (f16*)(ws + 64 * MB);      // [4096][1024]
    f16* vTb = (f16*)(ws + 64 * MB);     // [32][64][2048] (reuses h1 slot)
    f16* attb = (f16*)(ws + 72 * MB);    // [4096][1024]
    f16* h2 = attb;                      // reuse (att dead after proj gemm)
    f16* ffh = QKV;                      // [4096][4096] spans 40M..72M
    float* out = (float*)d_out;

    // weight repack (transposed f16)
    tr_cast_qkv<<<dim3(32, 2, 48), 256, 0, stream>>>(Wq, Wk, Wv, Wqkv_t);
    tr_cast_f32<<<dim3(32, 32), 256, 0, stream>>>(Wproj, 1024, Wproj_t, 1024);
    tr_cast_f32<<<dim3(32, 128), 256, 0, stream>>>(W1, 4096, W1_t, 1024);
    tr_cast_f32<<<dim3(128, 32), 256, 0, stream>>>(W2, 1024, W2_t, 4096);

    // block forward
    ln_kernel<<<4096, 256, 0, stream>>>(x, ln1w, ln1b, h1);
    gemm_bt<0><<<dim3(32, 24), 256, 0, stream>>>(h1, Wqkv_t, QKV, nullptr, 4096, 3072, 1024);
    tr_vT<<<dim3(32, 1, 32), 256, 0, stream>>>(QKV, vTb);
    attn_kernel<<<512, 256, 0, stream>>>(QKV, vTb, p, attb);
    gemm_ks<2><<<dim3(32, 8), 512, 0, stream>>>(attb, Wproj_t, x1, x, 4096, 1024, 1024);
    ln_kernel<<<4096, 256, 0, stream>>>(x1, ln2w, ln2b, h2);
    gemm_bt<1><<<dim3(32, 32), 256, 0, stream>>>(h2, W1_t, ffh, nullptr, 4096, 4096, 1024);
    gemm_ks<2><<<dim3(32, 8), 512, 0, stream>>>(ffh, W2_t, out, x1, 4096, 1024, 4096);
}

// Round 5
// 253.284 us; speedup vs baseline: 1.2604x; 1.0309x over previous
//
#include <hip/hip_runtime.h>

// ---------------------------------------------------------------------------
// Transformer block forward on gfx950.  B=2 T=2048 C=1024 H=16 HS=64 FF=4096.
// All matmuls: f16 inputs, fp32 MFMA accumulation (16x16x32).
// R5: attn VALU diet (exp2-domain softmax w/ Q-prescale, diagonal-only mask,
//     T13 defer-rescale, 2-buf 42KB LDS); L2-aware XCD mapping (XCD owns a
//     bm-chunk so its A-panel L2-fits) on all GEMMs + attn; GEMMs reverted to
//     proven 2-phase 2-buffer structure (R4's 3-buf vmcnt was null + cost LDS).
// Workspace layout (80 MB): unchanged.
// ---------------------------------------------------------------------------

typedef _Float16 f16;
typedef _Float16 f16x8 __attribute__((ext_vector_type(8)));
typedef _Float16 f16x4v __attribute__((ext_vector_type(4)));
typedef float f32x4 __attribute__((ext_vector_type(4)));

static constexpr int Tn = 2048;
static constexpr int Cn = 1024;
static constexpr int HSn = 64;

// async global->LDS, 16B per lane; dest = wave-uniform base + lane*16
__device__ __forceinline__ void glds16(const f16* g, f16* l) {
    __builtin_amdgcn_global_load_lds((const __attribute__((address_space(1))) void*)g,
                                     (__attribute__((address_space(3))) void*)l,
                                     16, 0, 0);
}

// ---------------------------------------------------------------------------
// LayerNorm (fp32 in) -> f16 out.  One block per row, 256 threads.
// ---------------------------------------------------------------------------
__global__ __launch_bounds__(256) void ln_kernel(const float* __restrict__ x,
                                                 const float* __restrict__ w,
                                                 const float* __restrict__ b,
                                                 f16* __restrict__ out) {
    int row = blockIdx.x;
    const float* xr = x + (size_t)row * Cn;
    int tid = threadIdx.x, l = tid & 63, wv = tid >> 6;
    float4 v = *(const float4*)(xr + tid * 4);
    float s = v.x + v.y + v.z + v.w;
    float sq = v.x * v.x + v.y * v.y + v.z * v.z + v.w * v.w;
#pragma unroll
    for (int off = 32; off > 0; off >>= 1) {
        s += __shfl_down(s, off);
        sq += __shfl_down(sq, off);
    }
    __shared__ float red[8];
    if (l == 0) { red[wv] = s; red[wv + 4] = sq; }
    __syncthreads();
    float ts = red[0] + red[1] + red[2] + red[3];
    float tq = red[4] + red[5] + red[6] + red[7];
    float mean = ts * (1.0f / Cn);
    float var = tq * (1.0f / Cn) - mean * mean;
    float rstd = rsqrtf(var + 1e-5f);
    float4 wv4 = *(const float4*)(w + tid * 4);
    float4 bv4 = *(const float4*)(b + tid * 4);
    f16x4v o;
    o[0] = (f16)((v.x - mean) * rstd * wv4.x + bv4.x);
    o[1] = (f16)((v.y - mean) * rstd * wv4.y + bv4.y);
    o[2] = (f16)((v.z - mean) * rstd * wv4.z + bv4.z);
    o[3] = (f16)((v.w - mean) * rstd * wv4.w + bv4.w);
    *(f16x4v*)(out + (size_t)row * Cn + tid * 4) = o;
}

// ---------------------------------------------------------------------------
// Transpose + cast fp32 -> f16:  out[c][r] = in[r][c].  32x32 tiles.
// ---------------------------------------------------------------------------
__global__ __launch_bounds__(256) void tr_cast_f32(const float* __restrict__ in, int irs,
                                                   f16* __restrict__ out, int ors) {
    __shared__ float tile[32][33];
    int r0 = blockIdx.x * 32, c0 = blockIdx.y * 32;
    int t = threadIdx.x;
    int rr = t >> 3, c4 = (t & 7) * 4;
    float4 v = *(const float4*)(in + (size_t)(r0 + rr) * irs + c0 + c4);
    tile[rr][c4] = v.x; tile[rr][c4 + 1] = v.y; tile[rr][c4 + 2] = v.z; tile[rr][c4 + 3] = v.w;
    __syncthreads();
    int cc = t >> 3, r4 = (t & 7) * 4;
    f16x4v o;
    o[0] = (f16)tile[r4][cc];
    o[1] = (f16)tile[r4 + 1][cc];
    o[2] = (f16)tile[r4 + 2][cc];
    o[3] = (f16)tile[r4 + 3][cc];
    *(f16x4v*)(out + (size_t)(c0 + cc) * ors + r0 + r4) = o;
}

// Same, but gathers Wq/Wk/Wv [H][C][HS] into Wqkv^T rows n = qkv*1024 + h*64 + s.
__global__ __launch_bounds__(256) void tr_cast_qkv(const float* __restrict__ Wq,
                                                   const float* __restrict__ Wk,
                                                   const float* __restrict__ Wv,
                                                   f16* __restrict__ out) {
    int z = blockIdx.z;
    int qkv = z >> 4, h = z & 15;
    const float* in = (qkv == 0 ? Wq : qkv == 1 ? Wk : Wv) + (size_t)h * Cn * HSn; // [1024][64]
    f16* o = out + (size_t)(qkv * Cn + h * HSn) * Cn;
    __shared__ float tile[32][33];
    int r0 = blockIdx.x * 32, c0 = blockIdx.y * 32;
    int t = threadIdx.x;
    int rr = t >> 3, c4 = (t & 7) * 4;
    float4 v = *(const float4*)(in + (size_t)(r0 + rr) * HSn + c0 + c4);
    tile[rr][c4] = v.x; tile[rr][c4 + 1] = v.y; tile[rr][c4 + 2] = v.z; tile[rr][c4 + 3] = v.w;
    __syncthreads();
    int cc = t >> 3, r4 = (t & 7) * 4;
    f16x4v ov;
    ov[0] = (f16)tile[r4][cc];
    ov[1] = (f16)tile[r4 + 1][cc];
    ov[2] = (f16)tile[r4 + 2][cc];
    ov[3] = (f16)tile[r4 + 3][cc];
    *(f16x4v*)(o + (size_t)(c0 + cc) * Cn + r0 + r4) = ov;
}

// ---------------------------------------------------------------------------
// f16 transpose: vT[bh][s][t] = QKV[(b*T+t)][2048 + h*64 + s].  64x64 tiles.
// ---------------------------------------------------------------------------
__global__ __launch_bounds__(256) void tr_vT(const f16* __restrict__ QKV, f16* __restrict__ vT) {
    int bh = blockIdx.z;
    int b = bh >> 4, h = bh & 15;
    const f16* in = QKV + (size_t)b * Tn * 3072 + 2048 + h * HSn; // [T][64] stride 3072
    f16* out = vT + (size_t)bh * HSn * Tn;                        // [64][T]
    int r0 = blockIdx.x * 64;
    __shared__ __align__(16) f16 tile[64][72];
    int t = threadIdx.x;
#pragma unroll
    for (int i = 0; i < 2; i++) {
        int f = i * 256 + t;
        int rr = f >> 3, c8 = (f & 7) * 8;
        *(uint4*)(&tile[rr][c8]) = *(const uint4*)(in + (size_t)(r0 + rr) * 3072 + c8);
    }
    __syncthreads();
#pragma unroll
    for (int i = 0; i < 2; i++) {
        int f = i * 256 + t;
        int cc = f >> 3, r8 = (f & 7) * 8;
        union { f16 h[8]; uint4 v; } u;
#pragma unroll
        for (int j = 0; j < 8; j++) u.h[j] = tile[r8 + j][cc];
        *(uint4*)(out + (size_t)cc * Tn + r0 + r8) = u.v;
    }
}

// L2-aware decode: XCD x owns bm-chunk [4x, 4x+4) so its A-panel (<=4MB)
// stays L2-resident; bn varies within the chunk.  Requires gridDim.x == 32.
__device__ __forceinline__ void l2_map(int& bm, int& bn) {
    int wg = blockIdx.y * 32 + blockIdx.x;
    int x = wg & 7, idx = wg >> 3;
    bm = x * 4 + (idx & 3);
    bn = idx >> 2;
}

// ---------------------------------------------------------------------------
// GEMM: C[M][N] = A[M][K] @ Bt[N][K]^T, f16 in, fp32 acc.
// 128x128 tile, BK=32, 4 waves.  glds staging, 2-buffer, 1 barrier/K-step.
// EPI: 0 = store f16, 1 = relu -> f16, 2 = +resid(f32) -> f32.
// ---------------------------------------------------------------------------
template <int EPI>
__global__ __launch_bounds__(256) void gemm_bt(const f16* __restrict__ A, const f16* __restrict__ Bt,
                                               void* __restrict__ Cout, const float* __restrict__ resid,
                                               int M, int N, int K) {
    __shared__ __align__(16) f16 As[2][4096]; // [128][32] per buffer, linear
    __shared__ __align__(16) f16 Bs[2][4096];
    int bm, bn;
    l2_map(bm, bn);
    int tid = threadIdx.x, l = tid & 63, w = tid >> 6;
    int wr = w >> 1, wc = w & 1;
    f32x4 acc[4][4];
#pragma unroll
    for (int m = 0; m < 4; m++)
#pragma unroll
        for (int n = 0; n < 4; n++) acc[m][n] = f32x4{0.f, 0.f, 0.f, 0.f};

    const f16* ag = A + (size_t)(bm * 128 + (tid >> 2)) * K + (tid & 3) * 8;
    const f16* bg = Bt + (size_t)(bn * 128 + (tid >> 2)) * K + (tid & 3) * 8;
    const size_t half = (size_t)64 * K;
    int KT = K >> 5;
    int rbase = (wr * 64 + (l & 15)) * 32 + (l >> 4) * 8;
    int cbase = (wc * 64 + (l & 15)) * 32 + (l >> 4) * 8;

    auto stage = [&](int kt, int bf) {
        int k0 = kt * 32;
        glds16(ag + k0, &As[bf][w * 512]);
        glds16(ag + half + k0, &As[bf][2048 + w * 512]);
        glds16(bg + k0, &Bs[bf][w * 512]);
        glds16(bg + half + k0, &Bs[bf][2048 + w * 512]);
    };

    stage(0, 0);
    __syncthreads();
    for (int kt = 0; kt < KT; ++kt) {
        int cb = kt & 1;
        if (kt + 1 < KT) stage(kt + 1, cb ^ 1); // in flight across compute
        f16x8 af[4], bfr[4];
#pragma unroll
        for (int m = 0; m < 4; m++) af[m] = *(const f16x8*)(&As[cb][rbase + m * 512]);
#pragma unroll
        for (int n = 0; n < 4; n++) bfr[n] = *(const f16x8*)(&Bs[cb][cbase + n * 512]);
#pragma unroll
        for (int m = 0; m < 4; m++)
#pragma unroll
            for (int n = 0; n < 4; n++)
                acc[m][n] = __builtin_amdgcn_mfma_f32_16x16x32_f16(af[m], bfr[n], acc[m][n], 0, 0, 0);
        __syncthreads(); // drains next-tile glds + guards buffer reuse
    }

    int row0 = bm * 128 + wr * 64 + (l >> 4) * 4;
    int col0 = bn * 128 + wc * 64 + (l & 15);
#pragma unroll
    for (int m = 0; m < 4; m++) {
#pragma unroll
        for (int n = 0; n < 4; n++) {
#pragma unroll
            for (int r = 0; r < 4; r++) {
                size_t idx = (size_t)(row0 + m * 16 + r) * N + (col0 + n * 16);
                float v = acc[m][n][r];
                if constexpr (EPI == 0) ((f16*)Cout)[idx] = (f16)v;
                else if constexpr (EPI == 1) ((f16*)Cout)[idx] = (f16)fmaxf(v, 0.f);
                else ((float*)Cout)[idx] = v + resid[idx];
            }
        }
    }
}

// ---------------------------------------------------------------------------
// GEMM with in-block split-K: 512 threads = 2 groups x 4 waves; group g does
// K-range [g*K/2, (g+1)*K/2) with its own 2-buffer pipeline; group 1 reduced
// into group 0 via LDS.  64KB LDS -> 2 blocks/CU.
// ---------------------------------------------------------------------------
template <int EPI>
__global__ __launch_bounds__(512) void gemm_ks(const f16* __restrict__ A, const f16* __restrict__ Bt,
                                               void* __restrict__ Cout, const float* __restrict__ resid,
                                               int M, int N, int K) {
    __shared__ __align__(16) char smem[65536];
    f16* As = (f16*)smem;            // [grp][2][4096] = 32KB
    f16* Bs = (f16*)(smem + 32768);  // [grp][2][4096] = 32KB
    int bm, bn;
    l2_map(bm, bn);
    int tid = threadIdx.x, l = tid & 63, w = tid >> 6;
    int grp = w >> 2, wl = w & 3;
    int wr = wl >> 1, wc = wl & 1;
    int Kh = K >> 1;
    int KT = Kh >> 5;

    f32x4 acc[4][4];
#pragma unroll
    for (int m = 0; m < 4; m++)
#pragma unroll
        for (int n = 0; n < 4; n++) acc[m][n] = f32x4{0.f, 0.f, 0.f, 0.f};

    const f16* agp = A + (size_t)(bm * 128 + wl * 16 + (l >> 2)) * K + grp * Kh + (l & 3) * 8;
    const f16* bgp = Bt + (size_t)(bn * 128 + wl * 16 + (l >> 2)) * K + grp * Kh + (l & 3) * 8;
    const size_t half = (size_t)64 * K;
    f16* Ab = As + grp * 8192;
    f16* Bb = Bs + grp * 8192;

    auto stage = [&](int kt, int bf) {
        size_t k0 = (size_t)kt * 32;
        glds16(agp + k0, Ab + bf * 4096 + wl * 512);
        glds16(agp + half + k0, Ab + bf * 4096 + 2048 + wl * 512);
        glds16(bgp + k0, Bb + bf * 4096 + wl * 512);
        glds16(bgp + half + k0, Bb + bf * 4096 + 2048 + wl * 512);
    };

    int rbase = (wr * 64 + (l & 15)) * 32 + (l >> 4) * 8;
    int cbase = (wc * 64 + (l & 15)) * 32 + (l >> 4) * 8;

    stage(0, 0);
    __syncthreads();
    for (int kt = 0; kt < KT; ++kt) {
        int cb = kt & 1;
        if (kt + 1 < KT) stage(kt + 1, cb ^ 1);
        f16x8 af[4], bfr[4];
#pragma unroll
        for (int m = 0; m < 4; m++) af[m] = *(const f16x8*)(Ab + cb * 4096 + rbase + m * 512);
#pragma unroll
        for (int n = 0; n < 4; n++) bfr[n] = *(const f16x8*)(Bb + cb * 4096 + cbase + n * 512);
#pragma unroll
        for (int m = 0; m < 4; m++)
#pragma unroll
            for (int n = 0; n < 4; n++)
                acc[m][n] = __builtin_amdgcn_mfma_f32_16x16x32_f16(af[m], bfr[n], acc[m][n], 0, 0, 0);
        __syncthreads();
    }

    // cross-group reduction: group1 -> LDS -> group0 (stride-20 spreads banks)
    float* red = (float*)smem;
#pragma unroll
    for (int m = 0; m < 4; m++) {
        if (grp == 1) {
#pragma unroll
            for (int n = 0; n < 4; n++)
                *(f32x4*)(red + wl * 1280 + l * 20 + n * 4) = acc[m][n];
        }
        __syncthreads();
        if (grp == 0) {
#pragma unroll
            for (int n = 0; n < 4; n++)
                acc[m][n] += *(const f32x4*)(red + wl * 1280 + l * 20 + n * 4);
        }
        __syncthreads();
    }

    if (grp == 0) {
        int row0 = bm * 128 + wr * 64 + (l >> 4) * 4;
        int col0 = bn * 128 + wc * 64 + (l & 15);
#pragma unroll
        for (int m = 0; m < 4; m++) {
#pragma unroll
            for (int n = 0; n < 4; n++) {
#pragma unroll
                for (int r = 0; r < 4; r++) {
                    size_t idx = (size_t)(row0 + m * 16 + r) * N + (col0 + n * 16);
                    float v = acc[m][n][r];
                    if constexpr (EPI == 0) ((f16*)Cout)[idx] = (f16)v;
                    else if constexpr (EPI == 1) ((f16*)Cout)[idx] = (f16)fmaxf(v, 0.f);
                    else ((float*)Cout)[idx] = v + resid[idx];
                }
            }
        }
    }
}

// ---------------------------------------------------------------------------
// Flash attention, causal.  Block = (bh, qtile-pair), 4 waves x 16 q-rows.
// Swapped QK^T (lane-local softmax stats).  exp2-domain softmax: Q pre-scaled
// by scale*log2e, mask only on the diagonal tile, defer-rescale (THR=8).
// 2-buffer K/V (42KB LDS -> 3 blocks/CU capacity).  XCD owns 4 heads.
// ---------------------------------------------------------------------------
__global__ __launch_bounds__(256) void attn_kernel(const f16* __restrict__ QKV,
                                                   const f16* __restrict__ vT,
                                                   const float* __restrict__ p,
                                                   f16* __restrict__ att) {
    // decode: XCD x gets bh in [4x,4x+4) (K/V 2MB -> L2-fits), all 16 pairs
    int wg = blockIdx.x;
    int x = wg & 7, idx = wg >> 3;
    int bh = x * 4 + (idx & 3);
    int pq = idx >> 2; // 0..15
    int b = bh >> 4, h = bh & 15;
    int tid = threadIdx.x, w = tid >> 6, l = tid & 63;
    float sc2 = rsqrtf(p[h]) * 1.44269504f; // scale * log2(e)

    __shared__ __align__(16) f16 Ks[2][4096];
    __shared__ __align__(16) f16 Vs[2][4096];
    __shared__ __align__(16) f16 Ps[4][16 * 80];
    f16* Pw = &Ps[w][0];

    int srow0 = tid >> 3;
    int c0 = (tid & 7) ^ (srow0 & 7);
    int srow1 = 32 + srow0;
    int c1 = (tid & 7) ^ (srow1 & 7);
    const f16* Kg = QKV + (size_t)b * Tn * 3072 + 1024 + h * HSn;
    const f16* Vg = vT + (size_t)bh * HSn * Tn;

    auto stageKV = [&](int kv0, int bf) {
        glds16(Kg + (size_t)(kv0 + srow0) * 3072 + c0 * 8, &Ks[bf][w * 512]);
        glds16(Kg + (size_t)(kv0 + srow1) * 3072 + c1 * 8, &Ks[bf][2048 + w * 512]);
        glds16(Vg + (size_t)srow0 * Tn + kv0 + c0 * 8, &Vs[bf][w * 512]);
        glds16(Vg + (size_t)srow1 * Tn + kv0 + c1 * 8, &Vs[bf][2048 + w * 512]);
    };

    for (int pass = 0; pass < 2; ++pass) {
        int qt = pass ? (31 - pq) : pq;
        int qg = qt * 64 + w * 16 + (l & 15);
        int qo = qt * 64 + w * 16 + (l >> 4) * 4;
        const f16* qptr = QKV + (size_t)(b * Tn + qg) * 3072 + h * HSn + (l >> 4) * 8;
        f16x8 qf0 = *(const f16x8*)(qptr);
        f16x8 qf1 = *(const f16x8*)(qptr + 32);
        f16 sch = (f16)sc2; // fold scale*log2e into Q (S lands in exp2 domain)
#pragma unroll
        for (int j = 0; j < 8; j++) { qf0[j] *= sch; qf1[j] *= sch; }

        f32x4 o[4];
#pragma unroll
        for (int nf = 0; nf < 4; nf++) o[nf] = f32x4{0.f, 0.f, 0.f, 0.f};
        float m_r = -1e30f, l_r = 0.f;

        int nt = qt + 1;
        stageKV(0, 0);
        __syncthreads();
        for (int t = 0; t < nt; ++t) {
            int cb = t & 1, kv0 = t * 64;
            if (t + 1 < nt) stageKV(kv0 + 64, cb ^ 1);
            const char* Kb = (const char*)&Ks[cb][0];
            const char* Vb = (const char*)&Vs[cb][0];
            f32x4 s[4];
#pragma unroll
            for (int n = 0; n < 4; n++) s[n] = f32x4{0.f, 0.f, 0.f, 0.f};
            __builtin_amdgcn_s_setprio(1);
#pragma unroll
            for (int n = 0; n < 4; n++) {
#pragma unroll
                for (int ks = 0; ks < 2; ks++) {
                    int boff = (n * 16 + (l & 15)) * 128 + (((ks * 32 + (l >> 4) * 8) * 2) ^ ((l & 7) << 4));
                    f16x8 kf = *(const f16x8*)(Kb + boff);
                    s[n] = __builtin_amdgcn_mfma_f32_16x16x32_f16(kf, ks == 0 ? qf0 : qf1, s[n], 0, 0, 0);
                }
            }
            __builtin_amdgcn_s_setprio(0);
            // causal mask only needed on the diagonal tile (t == qt):
            // for t < qt, kv0+63 <= qt*64-1 < qbase so all kv <= all q.
            if (t == qt) {
                int rel = qg - kv0;
#pragma unroll
                for (int n = 0; n < 4; n++)
#pragma unroll
                    for (int r = 0; r < 4; r++) {
                        int kvr = n * 16 + (l >> 4) * 4 + r;
                        if (kvr > rel) s[n][r] = -1e30f;
                    }
            }
            float tmax = -1e30f;
#pragma unroll
            for (int n = 0; n < 4; n++)
#pragma unroll
                for (int r = 0; r < 4; r++) tmax = fmaxf(tmax, s[n][r]);
            tmax = fmaxf(tmax, __shfl_xor(tmax, 16));
            tmax = fmaxf(tmax, __shfl_xor(tmax, 32));
            // T13 defer-rescale: skip O-rescale while max growth <= 8 (exp2
            // domain: P bounded by 2^8=256, fits f16; l/O are f32).
            float lmul = 1.f;
            if (__any(tmax > m_r + 8.f)) {
                float mnew = fmaxf(m_r, tmax);
                lmul = exp2f(m_r - mnew);
                m_r = mnew;
                float ar[4];
#pragma unroll
                for (int r = 0; r < 4; r++) ar[r] = __shfl(lmul, (l >> 4) * 4 + r);
#pragma unroll
                for (int nf = 0; nf < 4; nf++)
#pragma unroll
                    for (int r = 0; r < 4; r++) o[nf][r] *= ar[r];
            }
            float rsum = 0.f;
#pragma unroll
            for (int n = 0; n < 4; n++) {
                f16x4v pk;
#pragma unroll
                for (int r = 0; r < 4; r++) {
                    float e = exp2f(s[n][r] - m_r);
                    rsum += e;
                    pk[r] = (f16)e;
                }
                *(f16x4v*)(&Pw[(l & 15) * 80 + n * 16 + (l >> 4) * 4]) = pk;
            }
            rsum += __shfl_xor(rsum, 16);
            rsum += __shfl_xor(rsum, 32);
            l_r = l_r * lmul + rsum;
            f16x8 pa0 = *(const f16x8*)(&Pw[(l & 15) * 80 + (l >> 4) * 8]);
            f16x8 pa1 = *(const f16x8*)(&Pw[(l & 15) * 80 + 32 + (l >> 4) * 8]);
            __builtin_amdgcn_s_setprio(1);
#pragma unroll
            for (int nf = 0; nf < 4; nf++) {
#pragma unroll
                for (int ks = 0; ks < 2; ks++) {
                    int boff = (nf * 16 + (l & 15)) * 128 + (((ks * 32 + (l >> 4) * 8) * 2) ^ ((l & 7) << 4));
                    f16x8 vf = *(const f16x8*)(Vb + boff);
                    o[nf] = __builtin_amdgcn_mfma_f32_16x16x32_f16(ks == 0 ? pa0 : pa1, vf, o[nf], 0, 0, 0);
                }
            }
            __builtin_amdgcn_s_setprio(0);
            __syncthreads(); // drains next-tile glds + guards buffer reuse
        }
        float lro[4];
#pragma unroll
        for (int r = 0; r < 4; r++) lro[r] = __shfl(l_r, (l >> 4) * 4 + r);
#pragma unroll
        for (int nf = 0; nf < 4; nf++) {
#pragma unroll
            for (int r = 0; r < 4; r++) {
                float v = o[nf][r] / lro[r];
                att[(size_t)(b * Tn + qo + r) * Cn + h * HSn + nf * 16 + (l & 15)] = (f16)v;
            }
        }
    }
}

// ---------------------------------------------------------------------------
extern "C" void kernel_launch(void* const* d_in, const int* in_sizes, int n_in,
                              void* d_out, int out_size, void* d_ws, size_t ws_size,
                              hipStream_t stream) {
    const float* x = (const float*)d_in[0];
    const float* Wq = (const float*)d_in[1];
    const float* Wk = (const float*)d_in[2];
    const float* Wv = (const float*)d_in[3];
    const float* p = (const float*)d_in[4];
    const float* Wproj = (const float*)d_in[5];
    const float* W1 = (const float*)d_in[6];
    const float* W2 = (const float*)d_in[7];
    const float* ln1w = (const float*)d_in[8];
    const float* ln1b = (const float*)d_in[9];
    const float* ln2w = (const float*)d_in[10];
    const float* ln2b = (const float*)d_in[11];

    char* ws = (char*)d_ws;
    const size_t MB = 1ull << 20;
    f16* Wqkv_t = (f16*)(ws + 0 * MB);   // [3072][1024]
    f16* Wproj_t = (f16*)(ws + 6 * MB);  // [1024][1024]
    f16* W1_t = (f16*)(ws + 8 * MB);     // [4096][1024]
    f16* W2_t = (f16*)(ws + 16 * MB);    // [1024][4096]
    float* x1 = (float*)(ws + 24 * MB);  // [4096][1024] f32
    f16* QKV = (f16*)(ws + 40 * MB);     // [4096][3072]
    f16* h1 = (f16*)(ws + 64 * MB);      // [4096][1024]
    f16* vTb = (f16*)(ws + 64 * MB);     // [32][64][2048] (reuses h1 slot)
    f16* attb = (f16*)(ws + 72 * MB);    // [4096][1024]
    f16* h2 = attb;                      // reuse (att dead after proj gemm)
    f16* ffh = QKV;                      // [4096][4096] spans 40M..72M
    float* out = (float*)d_out;

    // weight repack (transposed f16)
    tr_cast_qkv<<<dim3(32, 2, 48), 256, 0, stream>>>(Wq, Wk, Wv, Wqkv_t);
    tr_cast_f32<<<dim3(32, 32), 256, 0, stream>>>(Wproj, 1024, Wproj_t, 1024);
    tr_cast_f32<<<dim3(32, 128), 256, 0, stream>>>(W1, 4096, W1_t, 1024);
    tr_cast_f32<<<dim3(128, 32), 256, 0, stream>>>(W2, 1024, W2_t, 4096);

    // block forward
    ln_kernel<<<4096, 256, 0, stream>>>(x, ln1w, ln1b, h1);
    gemm_bt<0><<<dim3(32, 24), 256, 0, stream>>>(h1, Wqkv_t, QKV, nullptr, 4096, 3072, 1024);
    tr_vT<<<dim3(32, 1, 32), 256, 0, stream>>>(QKV, vTb);
    attn_kernel<<<512, 256, 0, stream>>>(QKV, vTb, p, attb);
    gemm_ks<2><<<dim3(32, 8), 512, 0, stream>>>(attb, Wproj_t, x1, x, 4096, 1024, 1024);
    ln_kernel<<<4096, 256, 0, stream>>>(x1, ln2w, ln2b, h2);
    gemm_bt<1><<<dim3(32, 32), 256, 0, stream>>>(h2, W1_t, ffh, nullptr, 4096, 4096, 1024);
    gemm_ks<2><<<dim3(32, 8), 512, 0, stream>>>(ffh, W2_t, out, x1, 4096, 1024, 4096);
}

// Round 6
// 243.090 us; speedup vs baseline: 1.3132x; 1.0419x over previous
//
#include <hip/hip_runtime.h>

// ---------------------------------------------------------------------------
// Transformer block forward on gfx950.  B=2 T=2048 C=1024 H=16 HS=64 FF=4096.
// All matmuls: f16 inputs, fp32 MFMA accumulation (16x16x32).
// R6: gemm8 = 256x256-tile 8-wave deep-pipelined GEMM (BK=32, 4 LDS buffers,
//     stage depth 3, one vmcnt(8)+s_barrier per K-tile -- never a full drain
//     in the loop; 2 phases x 16 MFMA; XOR bank swizzle both sides; setprio).
//     Used for QKV and FF1 (grids 192/256).  proj/FF2 stay on gemm_ks 128^2
//     (256-block grid beats 64-block 256^2).  Attn unchanged from R5.
// Workspace layout (80 MB): unchanged.
// ---------------------------------------------------------------------------

typedef _Float16 f16;
typedef _Float16 f16x8 __attribute__((ext_vector_type(8)));
typedef _Float16 f16x4v __attribute__((ext_vector_type(4)));
typedef float f32x4 __attribute__((ext_vector_type(4)));

static constexpr int Tn = 2048;
static constexpr int Cn = 1024;
static constexpr int HSn = 64;

// async global->LDS, 16B per lane; dest = wave-uniform base + lane*16
__device__ __forceinline__ void glds16(const f16* g, f16* l) {
    __builtin_amdgcn_global_load_lds((const __attribute__((address_space(1))) void*)g,
                                     (__attribute__((address_space(3))) void*)l,
                                     16, 0, 0);
}

#define VMCNT(N) asm volatile("s_waitcnt vmcnt(" #N ")" ::: "memory")
// raw barrier with code-motion fences (no implicit vmcnt/lgkm drain)
__device__ __forceinline__ void barrier_raw() {
    asm volatile("" ::: "memory");
    __builtin_amdgcn_s_barrier();
    asm volatile("" ::: "memory");
}

// ---------------------------------------------------------------------------
// LayerNorm (fp32 in) -> f16 out.  One block per row, 256 threads.
// ---------------------------------------------------------------------------
__global__ __launch_bounds__(256) void ln_kernel(const float* __restrict__ x,
                                                 const float* __restrict__ w,
                                                 const float* __restrict__ b,
                                                 f16* __restrict__ out) {
    int row = blockIdx.x;
    const float* xr = x + (size_t)row * Cn;
    int tid = threadIdx.x, l = tid & 63, wv = tid >> 6;
    float4 v = *(const float4*)(xr + tid * 4);
    float s = v.x + v.y + v.z + v.w;
    float sq = v.x * v.x + v.y * v.y + v.z * v.z + v.w * v.w;
#pragma unroll
    for (int off = 32; off > 0; off >>= 1) {
        s += __shfl_down(s, off);
        sq += __shfl_down(sq, off);
    }
    __shared__ float red[8];
    if (l == 0) { red[wv] = s; red[wv + 4] = sq; }
    __syncthreads();
    float ts = red[0] + red[1] + red[2] + red[3];
    float tq = red[4] + red[5] + red[6] + red[7];
    float mean = ts * (1.0f / Cn);
    float var = tq * (1.0f / Cn) - mean * mean;
    float rstd = rsqrtf(var + 1e-5f);
    float4 wv4 = *(const float4*)(w + tid * 4);
    float4 bv4 = *(const float4*)(b + tid * 4);
    f16x4v o;
    o[0] = (f16)((v.x - mean) * rstd * wv4.x + bv4.x);
    o[1] = (f16)((v.y - mean) * rstd * wv4.y + bv4.y);
    o[2] = (f16)((v.z - mean) * rstd * wv4.z + bv4.z);
    o[3] = (f16)((v.w - mean) * rstd * wv4.w + bv4.w);
    *(f16x4v*)(out + (size_t)row * Cn + tid * 4) = o;
}

// ---------------------------------------------------------------------------
// Transpose + cast fp32 -> f16:  out[c][r] = in[r][c].  32x32 tiles.
// ---------------------------------------------------------------------------
__global__ __launch_bounds__(256) void tr_cast_f32(const float* __restrict__ in, int irs,
                                                   f16* __restrict__ out, int ors) {
    __shared__ float tile[32][33];
    int r0 = blockIdx.x * 32, c0 = blockIdx.y * 32;
    int t = threadIdx.x;
    int rr = t >> 3, c4 = (t & 7) * 4;
    float4 v = *(const float4*)(in + (size_t)(r0 + rr) * irs + c0 + c4);
    tile[rr][c4] = v.x; tile[rr][c4 + 1] = v.y; tile[rr][c4 + 2] = v.z; tile[rr][c4 + 3] = v.w;
    __syncthreads();
    int cc = t >> 3, r4 = (t & 7) * 4;
    f16x4v o;
    o[0] = (f16)tile[r4][cc];
    o[1] = (f16)tile[r4 + 1][cc];
    o[2] = (f16)tile[r4 + 2][cc];
    o[3] = (f16)tile[r4 + 3][cc];
    *(f16x4v*)(out + (size_t)(c0 + cc) * ors + r0 + r4) = o;
}

// Same, but gathers Wq/Wk/Wv [H][C][HS] into Wqkv^T rows n = qkv*1024 + h*64 + s.
__global__ __launch_bounds__(256) void tr_cast_qkv(const float* __restrict__ Wq,
                                                   const float* __restrict__ Wk,
                                                   const float* __restrict__ Wv,
                                                   f16* __restrict__ out) {
    int z = blockIdx.z;
    int qkv = z >> 4, h = z & 15;
    const float* in = (qkv == 0 ? Wq : qkv == 1 ? Wk : Wv) + (size_t)h * Cn * HSn; // [1024][64]
    f16* o = out + (size_t)(qkv * Cn + h * HSn) * Cn;
    __shared__ float tile[32][33];
    int r0 = blockIdx.x * 32, c0 = blockIdx.y * 32;
    int t = threadIdx.x;
    int rr = t >> 3, c4 = (t & 7) * 4;
    float4 v = *(const float4*)(in + (size_t)(r0 + rr) * HSn + c0 + c4);
    tile[rr][c4] = v.x; tile[rr][c4 + 1] = v.y; tile[rr][c4 + 2] = v.z; tile[rr][c4 + 3] = v.w;
    __syncthreads();
    int cc = t >> 3, r4 = (t & 7) * 4;
    f16x4v ov;
    ov[0] = (f16)tile[r4][cc];
    ov[1] = (f16)tile[r4 + 1][cc];
    ov[2] = (f16)tile[r4 + 2][cc];
    ov[3] = (f16)tile[r4 + 3][cc];
    *(f16x4v*)(o + (size_t)(c0 + cc) * Cn + r0 + r4) = ov;
}

// ---------------------------------------------------------------------------
// f16 transpose: vT[bh][s][t] = QKV[(b*T+t)][2048 + h*64 + s].  64x64 tiles.
// ---------------------------------------------------------------------------
__global__ __launch_bounds__(256) void tr_vT(const f16* __restrict__ QKV, f16* __restrict__ vT) {
    int bh = blockIdx.z;
    int b = bh >> 4, h = bh & 15;
    const f16* in = QKV + (size_t)b * Tn * 3072 + 2048 + h * HSn; // [T][64] stride 3072
    f16* out = vT + (size_t)bh * HSn * Tn;                        // [64][T]
    int r0 = blockIdx.x * 64;
    __shared__ __align__(16) f16 tile[64][72];
    int t = threadIdx.x;
#pragma unroll
    for (int i = 0; i < 2; i++) {
        int f = i * 256 + t;
        int rr = f >> 3, c8 = (f & 7) * 8;
        *(uint4*)(&tile[rr][c8]) = *(const uint4*)(in + (size_t)(r0 + rr) * 3072 + c8);
    }
    __syncthreads();
#pragma unroll
    for (int i = 0; i < 2; i++) {
        int f = i * 256 + t;
        int cc = f >> 3, r8 = (f & 7) * 8;
        union { f16 h[8]; uint4 v; } u;
#pragma unroll
        for (int j = 0; j < 8; j++) u.h[j] = tile[r8 + j][cc];
        *(uint4*)(out + (size_t)cc * Tn + r0 + r8) = u.v;
    }
}

// ---------------------------------------------------------------------------
// gemm8: C[M][N] = A[M][K] @ Bt[N][K]^T, 256x256 tile, 8 waves (2M x 4N),
// BK=32, 4 LDS buffers, stage depth 3.  Per K-tile: vmcnt(8) + s_barrier
// (tile t's 4 loads are the oldest; t+1,t+2 = 8 newer stay in flight), then
// phase0 {8 ds_read, issue stage(t+3), 16 MFMA}, s_barrier, phase1 {4
// ds_read, 16 MFMA}.  LDS chunk swizzle c ^= (row>>1)&3 on both sides ->
// 2-way (free) bank access on ds_read_b128.  EPI: 0 = f16, 1 = relu f16.
// Requires M%256==0, N%256==0, K%32==0, K/32 >= 3, M/256 == 16.
// ---------------------------------------------------------------------------
template <int EPI>
__global__ __launch_bounds__(512, 2) void gemm8(const f16* __restrict__ A, const f16* __restrict__ Bt,
                                                f16* __restrict__ Cout, int M, int N, int K) {
    __shared__ __align__(16) f16 Abuf[4][8192]; // [buf][half(128 rows)][128][32] swizzled
    __shared__ __align__(16) f16 Bbuf[4][8192];
    int wg = blockIdx.x;
    int xcd = wg & 7, idx = wg >> 3;
    int bm = xcd * 2 + (idx & 1), bn = idx >> 1; // XCD owns 2 bm (1MB A-panel, L2-fits)
    int tid = threadIdx.x, l = tid & 63, w = tid >> 6;
    int wr = w >> 2, wc = w & 3; // wave grid 2(M) x 4(N); per-wave out 128x64

    f32x4 acc[8][4];
#pragma unroll
    for (int m = 0; m < 8; m++)
#pragma unroll
        for (int n = 0; n < 4; n++) acc[m][n] = f32x4{0.f, 0.f, 0.f, 0.f};

    // fragment-read lane offset (f16 units), swizzle folded in:
    // row'=(l&15)(+16m), chunk=(l>>4)^((row'>>1)&3) with (row'>>1)&3 == ((l&15)>>1)&3
    int l15 = l & 15;
    int lane_off = l15 * 32 + (((l >> 4) ^ ((l15 >> 1) & 3)) << 3);
    const f16* Afr = &Abuf[0][wr * 4096 + lane_off];
    const f16* Bfr = &Bbuf[0][(wc >> 1) * 4096 + (wc & 1) * 2048 + lane_off];

    // staging: thread covers (row = w*16 + l/4 [+128], chunk' = (l&3)^((l>>3)&3))
    int srow = w * 16 + (l >> 2);
    int schunk = (l & 3) ^ ((l >> 3) & 3);
    const f16* agp = A + (size_t)(bm * 256 + srow) * K + schunk * 8;
    const f16* bgp = Bt + (size_t)(bn * 256 + srow) * K + schunk * 8;
    const size_t rK = (size_t)128 * K;
    f16* dstA = &Abuf[0][w * 512]; // +bf*8192 (+4096 for half 1); lane adds *16B
    f16* dstB = &Bbuf[0][w * 512];

    auto stage = [&](int kt, int bf) {
        int k0 = kt * 32;
        glds16(agp + k0, dstA + bf * 8192);
        glds16(agp + rK + k0, dstA + bf * 8192 + 4096);
        glds16(bgp + k0, dstB + bf * 8192);
        glds16(bgp + rK + k0, dstB + bf * 8192 + 4096);
    };

    int NT = K >> 5;
    stage(0, 0);
    stage(1, 1);
    stage(2, 2);
    for (int t = 0; t < NT; ++t) {
        int cb = t & 3;
        VMCNT(8);       // tile t's 4 loads (oldest) retired; t+1,t+2 in flight
        barrier_raw();  // collective: all waves' t-loads landed; buf (t+3)&3 free
        const f16* Ab = Afr + cb * 8192;
        const f16* Bb = Bfr + cb * 8192;
        f16x8 af[4], bf4[4];
#pragma unroll
        for (int m = 0; m < 4; m++) af[m] = *(const f16x8*)(Ab + m * 512);
#pragma unroll
        for (int n = 0; n < 4; n++) bf4[n] = *(const f16x8*)(Bb + n * 512);
        if (t + 3 < NT) stage(t + 3, (t + 3) & 3); // issue under phase-0 compute
        __builtin_amdgcn_s_setprio(1);
#pragma unroll
        for (int m = 0; m < 4; m++)
#pragma unroll
            for (int n = 0; n < 4; n++)
                acc[m][n] = __builtin_amdgcn_mfma_f32_16x16x32_f16(af[m], bf4[n], acc[m][n], 0, 0, 0);
        __builtin_amdgcn_s_setprio(0);
        barrier_raw();  // phase split (lockstep role diversity; no hazard)
#pragma unroll
        for (int m = 0; m < 4; m++) af[m] = *(const f16x8*)(Ab + (m + 4) * 512);
        __builtin_amdgcn_s_setprio(1);
#pragma unroll
        for (int m = 0; m < 4; m++)
#pragma unroll
            for (int n = 0; n < 4; n++)
                acc[m + 4][n] = __builtin_amdgcn_mfma_f32_16x16x32_f16(af[m], bf4[n], acc[m + 4][n], 0, 0, 0);
        __builtin_amdgcn_s_setprio(0);
    }
    VMCNT(0); // drain before exit (stray loads into LDS)

    int row0 = bm * 256 + wr * 128 + (l >> 4) * 4;
    int col0 = bn * 256 + wc * 64 + (l & 15);
#pragma unroll
    for (int m = 0; m < 8; m++) {
#pragma unroll
        for (int n = 0; n < 4; n++) {
#pragma unroll
            for (int r = 0; r < 4; r++) {
                size_t idx = (size_t)(row0 + m * 16 + r) * N + (col0 + n * 16);
                float v = acc[m][n][r];
                if constexpr (EPI == 1) v = fmaxf(v, 0.f);
                Cout[idx] = (f16)v;
            }
        }
    }
}

// L2-aware decode for 128^2 grids: XCD x owns bm-chunk [4x, 4x+4).
__device__ __forceinline__ void l2_map(int& bm, int& bn) {
    int wg = blockIdx.y * 32 + blockIdx.x;
    int x = wg & 7, idx = wg >> 3;
    bm = x * 4 + (idx & 3);
    bn = idx >> 2;
}

// ---------------------------------------------------------------------------
// GEMM with in-block split-K: 512 threads = 2 groups x 4 waves; group g does
// K-range [g*K/2, (g+1)*K/2) with its own 2-buffer pipeline; group 1 reduced
// into group 0 via LDS.  64KB LDS -> 2 blocks/CU.  (proj, FF2)
// ---------------------------------------------------------------------------
template <int EPI>
__global__ __launch_bounds__(512) void gemm_ks(const f16* __restrict__ A, const f16* __restrict__ Bt,
                                               void* __restrict__ Cout, const float* __restrict__ resid,
                                               int M, int N, int K) {
    __shared__ __align__(16) char smem[65536];
    f16* As = (f16*)smem;            // [grp][2][4096] = 32KB
    f16* Bs = (f16*)(smem + 32768);  // [grp][2][4096] = 32KB
    int bm, bn;
    l2_map(bm, bn);
    int tid = threadIdx.x, l = tid & 63, w = tid >> 6;
    int grp = w >> 2, wl = w & 3;
    int wr = wl >> 1, wc = wl & 1;
    int Kh = K >> 1;
    int KT = Kh >> 5;

    f32x4 acc[4][4];
#pragma unroll
    for (int m = 0; m < 4; m++)
#pragma unroll
        for (int n = 0; n < 4; n++) acc[m][n] = f32x4{0.f, 0.f, 0.f, 0.f};

    const f16* agp = A + (size_t)(bm * 128 + wl * 16 + (l >> 2)) * K + grp * Kh + (l & 3) * 8;
    const f16* bgp = Bt + (size_t)(bn * 128 + wl * 16 + (l >> 2)) * K + grp * Kh + (l & 3) * 8;
    const size_t half = (size_t)64 * K;
    f16* Ab = As + grp * 8192;
    f16* Bb = Bs + grp * 8192;

    auto stage = [&](int kt, int bf) {
        size_t k0 = (size_t)kt * 32;
        glds16(agp + k0, Ab + bf * 4096 + wl * 512);
        glds16(agp + half + k0, Ab + bf * 4096 + 2048 + wl * 512);
        glds16(bgp + k0, Bb + bf * 4096 + wl * 512);
        glds16(bgp + half + k0, Bb + bf * 4096 + 2048 + wl * 512);
    };

    int rbase = (wr * 64 + (l & 15)) * 32 + (l >> 4) * 8;
    int cbase = (wc * 64 + (l & 15)) * 32 + (l >> 4) * 8;

    stage(0, 0);
    __syncthreads();
    for (int kt = 0; kt < KT; ++kt) {
        int cb = kt & 1;
        if (kt + 1 < KT) stage(kt + 1, cb ^ 1);
        f16x8 af[4], bfr[4];
#pragma unroll
        for (int m = 0; m < 4; m++) af[m] = *(const f16x8*)(Ab + cb * 4096 + rbase + m * 512);
#pragma unroll
        for (int n = 0; n < 4; n++) bfr[n] = *(const f16x8*)(Bb + cb * 4096 + cbase + n * 512);
#pragma unroll
        for (int m = 0; m < 4; m++)
#pragma unroll
            for (int n = 0; n < 4; n++)
                acc[m][n] = __builtin_amdgcn_mfma_f32_16x16x32_f16(af[m], bfr[n], acc[m][n], 0, 0, 0);
        __syncthreads();
    }

    // cross-group reduction: group1 -> LDS -> group0 (stride-20 spreads banks)
    float* red = (float*)smem;
#pragma unroll
    for (int m = 0; m < 4; m++) {
        if (grp == 1) {
#pragma unroll
            for (int n = 0; n < 4; n++)
                *(f32x4*)(red + wl * 1280 + l * 20 + n * 4) = acc[m][n];
        }
        __syncthreads();
        if (grp == 0) {
#pragma unroll
            for (int n = 0; n < 4; n++)
                acc[m][n] += *(const f32x4*)(red + wl * 1280 + l * 20 + n * 4);
        }
        __syncthreads();
    }

    if (grp == 0) {
        int row0 = bm * 128 + wr * 64 + (l >> 4) * 4;
        int col0 = bn * 128 + wc * 64 + (l & 15);
#pragma unroll
        for (int m = 0; m < 4; m++) {
#pragma unroll
            for (int n = 0; n < 4; n++) {
#pragma unroll
                for (int r = 0; r < 4; r++) {
                    size_t idx = (size_t)(row0 + m * 16 + r) * N + (col0 + n * 16);
                    float v = acc[m][n][r];
                    if constexpr (EPI == 0) ((f16*)Cout)[idx] = (f16)v;
                    else if constexpr (EPI == 1) ((f16*)Cout)[idx] = (f16)fmaxf(v, 0.f);
                    else ((float*)Cout)[idx] = v + resid[idx];
                }
            }
        }
    }
}

// ---------------------------------------------------------------------------
// Flash attention, causal.  Block = (bh, qtile-pair), 4 waves x 16 q-rows.
// Swapped QK^T (lane-local softmax stats), exp2-domain softmax (Q pre-scaled
// by scale*log2e), diagonal-only mask, defer-rescale (THR=8), 2-buffer K/V.
// ---------------------------------------------------------------------------
__global__ __launch_bounds__(256) void attn_kernel(const f16* __restrict__ QKV,
                                                   const f16* __restrict__ vT,
                                                   const float* __restrict__ p,
                                                   f16* __restrict__ att) {
    int wg = blockIdx.x;
    int x = wg & 7, idx = wg >> 3;
    int bh = x * 4 + (idx & 3);
    int pq = idx >> 2; // 0..15
    int b = bh >> 4, h = bh & 15;
    int tid = threadIdx.x, w = tid >> 6, l = tid & 63;
    float sc2 = rsqrtf(p[h]) * 1.44269504f; // scale * log2(e)

    __shared__ __align__(16) f16 Ks[2][4096];
    __shared__ __align__(16) f16 Vs[2][4096];
    __shared__ __align__(16) f16 Ps[4][16 * 80];
    f16* Pw = &Ps[w][0];

    int srow0 = tid >> 3;
    int c0 = (tid & 7) ^ (srow0 & 7);
    int srow1 = 32 + srow0;
    int c1 = (tid & 7) ^ (srow1 & 7);
    const f16* Kg = QKV + (size_t)b * Tn * 3072 + 1024 + h * HSn;
    const f16* Vg = vT + (size_t)bh * HSn * Tn;

    auto stageKV = [&](int kv0, int bf) {
        glds16(Kg + (size_t)(kv0 + srow0) * 3072 + c0 * 8, &Ks[bf][w * 512]);
        glds16(Kg + (size_t)(kv0 + srow1) * 3072 + c1 * 8, &Ks[bf][2048 + w * 512]);
        glds16(Vg + (size_t)srow0 * Tn + kv0 + c0 * 8, &Vs[bf][w * 512]);
        glds16(Vg + (size_t)srow1 * Tn + kv0 + c1 * 8, &Vs[bf][2048 + w * 512]);
    };

    for (int pass = 0; pass < 2; ++pass) {
        int qt = pass ? (31 - pq) : pq;
        int qg = qt * 64 + w * 16 + (l & 15);
        int qo = qt * 64 + w * 16 + (l >> 4) * 4;
        const f16* qptr = QKV + (size_t)(b * Tn + qg) * 3072 + h * HSn + (l >> 4) * 8;
        f16x8 qf0 = *(const f16x8*)(qptr);
        f16x8 qf1 = *(const f16x8*)(qptr + 32);
        f16 sch = (f16)sc2;
#pragma unroll
        for (int j = 0; j < 8; j++) { qf0[j] *= sch; qf1[j] *= sch; }

        f32x4 o[4];
#pragma unroll
        for (int nf = 0; nf < 4; nf++) o[nf] = f32x4{0.f, 0.f, 0.f, 0.f};
        float m_r = -1e30f, l_r = 0.f;

        int nt = qt + 1;
        stageKV(0, 0);
        __syncthreads();
        for (int t = 0; t < nt; ++t) {
            int cb = t & 1, kv0 = t * 64;
            if (t + 1 < nt) stageKV(kv0 + 64, cb ^ 1);
            const char* Kb = (const char*)&Ks[cb][0];
            const char* Vb = (const char*)&Vs[cb][0];
            f32x4 s[4];
#pragma unroll
            for (int n = 0; n < 4; n++) s[n] = f32x4{0.f, 0.f, 0.f, 0.f};
            __builtin_amdgcn_s_setprio(1);
#pragma unroll
            for (int n = 0; n < 4; n++) {
#pragma unroll
                for (int ks = 0; ks < 2; ks++) {
                    int boff = (n * 16 + (l & 15)) * 128 + (((ks * 32 + (l >> 4) * 8) * 2) ^ ((l & 7) << 4));
                    f16x8 kf = *(const f16x8*)(Kb + boff);
                    s[n] = __builtin_amdgcn_mfma_f32_16x16x32_f16(kf, ks == 0 ? qf0 : qf1, s[n], 0, 0, 0);
                }
            }
            __builtin_amdgcn_s_setprio(0);
            if (t == qt) { // mask only on the diagonal tile
                int rel = qg - kv0;
#pragma unroll
                for (int n = 0; n < 4; n++)
#pragma unroll
                    for (int r = 0; r < 4; r++) {
                        int kvr = n * 16 + (l >> 4) * 4 + r;
                        if (kvr > rel) s[n][r] = -1e30f;
                    }
            }
            float tmax = -1e30f;
#pragma unroll
            for (int n = 0; n < 4; n++)
#pragma unroll
                for (int r = 0; r < 4; r++) tmax = fmaxf(tmax, s[n][r]);
            tmax = fmaxf(tmax, __shfl_xor(tmax, 16));
            tmax = fmaxf(tmax, __shfl_xor(tmax, 32));
            float lmul = 1.f;
            if (__any(tmax > m_r + 8.f)) { // T13 defer-rescale (exp2 domain)
                float mnew = fmaxf(m_r, tmax);
                lmul = exp2f(m_r - mnew);
                m_r = mnew;
                float ar[4];
#pragma unroll
                for (int r = 0; r < 4; r++) ar[r] = __shfl(lmul, (l >> 4) * 4 + r);
#pragma unroll
                for (int nf = 0; nf < 4; nf++)
#pragma unroll
                    for (int r = 0; r < 4; r++) o[nf][r] *= ar[r];
            }
            float rsum = 0.f;
#pragma unroll
            for (int n = 0; n < 4; n++) {
                f16x4v pk;
#pragma unroll
                for (int r = 0; r < 4; r++) {
                    float e = exp2f(s[n][r] - m_r);
                    rsum += e;
                    pk[r] = (f16)e;
                }
                *(f16x4v*)(&Pw[(l & 15) * 80 + n * 16 + (l >> 4) * 4]) = pk;
            }
            rsum += __shfl_xor(rsum, 16);
            rsum += __shfl_xor(rsum, 32);
            l_r = l_r * lmul + rsum;
            f16x8 pa0 = *(const f16x8*)(&Pw[(l & 15) * 80 + (l >> 4) * 8]);
            f16x8 pa1 = *(const f16x8*)(&Pw[(l & 15) * 80 + 32 + (l >> 4) * 8]);
            __builtin_amdgcn_s_setprio(1);
#pragma unroll
            for (int nf = 0; nf < 4; nf++) {
#pragma unroll
                for (int ks = 0; ks < 2; ks++) {
                    int boff = (nf * 16 + (l & 15)) * 128 + (((ks * 32 + (l >> 4) * 8) * 2) ^ ((l & 7) << 4));
                    f16x8 vf = *(const f16x8*)(Vb + boff);
                    o[nf] = __builtin_amdgcn_mfma_f32_16x16x32_f16(ks == 0 ? pa0 : pa1, vf, o[nf], 0, 0, 0);
                }
            }
            __builtin_amdgcn_s_setprio(0);
            __syncthreads();
        }
        float lro[4];
#pragma unroll
        for (int r = 0; r < 4; r++) lro[r] = __shfl(l_r, (l >> 4) * 4 + r);
#pragma unroll
        for (int nf = 0; nf < 4; nf++) {
#pragma unroll
            for (int r = 0; r < 4; r++) {
                float v = o[nf][r] / lro[r];
                att[(size_t)(b * Tn + qo + r) * Cn + h * HSn + nf * 16 + (l & 15)] = (f16)v;
            }
        }
    }
}

// ---------------------------------------------------------------------------
extern "C" void kernel_launch(void* const* d_in, const int* in_sizes, int n_in,
                              void* d_out, int out_size, void* d_ws, size_t ws_size,
                              hipStream_t stream) {
    const float* x = (const float*)d_in[0];
    const float* Wq = (const float*)d_in[1];
    const float* Wk = (const float*)d_in[2];
    const float* Wv = (const float*)d_in[3];
    const float* p = (const float*)d_in[4];
    const float* Wproj = (const float*)d_in[5];
    const float* W1 = (const float*)d_in[6];
    const float* W2 = (const float*)d_in[7];
    const float* ln1w = (const float*)d_in[8];
    const float* ln1b = (const float*)d_in[9];
    const float* ln2w = (const float*)d_in[10];
    const float* ln2b = (const float*)d_in[11];

    char* ws = (char*)d_ws;
    const size_t MB = 1ull << 20;
    f16* Wqkv_t = (f16*)(ws + 0 * MB);   // [3072][1024]
    f16* Wproj_t = (f16*)(ws + 6 * MB);  // [1024][1024]
    f16* W1_t = (f16*)(ws + 8 * MB);     // [4096][1024]
    f16* W2_t = (f16*)(ws + 16 * MB);    // [1024][4096]
    float* x1 = (float*)(ws + 24 * MB);  // [4096][1024] f32
    f16* QKV = (f16*)(ws + 40 * MB);     // [4096][3072]
    f16* h1 = (f16*)(ws + 64 * MB);      // [4096][1024]
    f16* vTb = (f16*)(ws + 64 * MB);     // [32][64][2048] (reuses h1 slot)
    f16* attb = (f16*)(ws + 72 * MB);    // [4096][1024]
    f16* h2 = attb;                      // reuse (att dead after proj gemm)
    f16* ffh = QKV;                      // [4096][4096] spans 40M..72M
    float* out = (float*)d_out;

    // weight repack (transposed f16)
    tr_cast_qkv<<<dim3(32, 2, 48), 256, 0, stream>>>(Wq, Wk, Wv, Wqkv_t);
    tr_cast_f32<<<dim3(32, 32), 256, 0, stream>>>(Wproj, 1024, Wproj_t, 1024);
    tr_cast_f32<<<dim3(32, 128), 256, 0, stream>>>(W1, 4096, W1_t, 1024);
    tr_cast_f32<<<dim3(128, 32), 256, 0, stream>>>(W2, 1024, W2_t, 4096);

    // block forward
    ln_kernel<<<4096, 256, 0, stream>>>(x, ln1w, ln1b, h1);
    gemm8<0><<<192, 512, 0, stream>>>(h1, Wqkv_t, QKV, 4096, 3072, 1024);
    tr_vT<<<dim3(32, 1, 32), 256, 0, stream>>>(QKV, vTb);
    attn_kernel<<<512, 256, 0, stream>>>(QKV, vTb, p, attb);
    gemm_ks<2><<<dim3(32, 8), 512, 0, stream>>>(attb, Wproj_t, x1, x, 4096, 1024, 1024);
    ln_kernel<<<4096, 256, 0, stream>>>(x1, ln2w, ln2b, h2);
    gemm8<1><<<256, 512, 0, stream>>>(h2, W1_t, ffh, 4096, 4096, 1024);
    gemm_ks<2><<<dim3(32, 8), 512, 0, stream>>>(ffh, W2_t, out, x1, 4096, 1024, 4096);
}

// Round 7
// 228.289 us; speedup vs baseline: 1.3984x; 1.0648x over previous
//
#include <hip/hip_runtime.h>

// ---------------------------------------------------------------------------
// Transformer block forward on gfx950.  B=2 T=2048 C=1024 H=16 HS=64 FF=4096.
// All matmuls: f16 inputs, fp32 MFMA accumulation (16x16x32).
// R7: gemm_ks (proj, FF2) upgraded to the R6-proven deep pipeline: per group
//     3 LDS buffers, stage depth 2, vmcnt(4) + raw s_barrier per K-step
//     (vmcnt(0) only on the last), XOR chunk swizzle on both sides, setprio.
//     gemm8 (QKV, FF1) and attention unchanged from R6.
// Workspace layout (80 MB): unchanged.
// ---------------------------------------------------------------------------

typedef _Float16 f16;
typedef _Float16 f16x8 __attribute__((ext_vector_type(8)));
typedef _Float16 f16x4v __attribute__((ext_vector_type(4)));
typedef float f32x4 __attribute__((ext_vector_type(4)));

static constexpr int Tn = 2048;
static constexpr int Cn = 1024;
static constexpr int HSn = 64;

// async global->LDS, 16B per lane; dest = wave-uniform base + lane*16
__device__ __forceinline__ void glds16(const f16* g, f16* l) {
    __builtin_amdgcn_global_load_lds((const __attribute__((address_space(1))) void*)g,
                                     (__attribute__((address_space(3))) void*)l,
                                     16, 0, 0);
}

#define VMCNT(N) asm volatile("s_waitcnt vmcnt(" #N ")" ::: "memory")
// raw barrier with code-motion fences (no implicit vmcnt/lgkm drain)
__device__ __forceinline__ void barrier_raw() {
    asm volatile("" ::: "memory");
    __builtin_amdgcn_s_barrier();
    asm volatile("" ::: "memory");
}

// ---------------------------------------------------------------------------
// LayerNorm (fp32 in) -> f16 out.  One block per row, 256 threads.
// ---------------------------------------------------------------------------
__global__ __launch_bounds__(256) void ln_kernel(const float* __restrict__ x,
                                                 const float* __restrict__ w,
                                                 const float* __restrict__ b,
                                                 f16* __restrict__ out) {
    int row = blockIdx.x;
    const float* xr = x + (size_t)row * Cn;
    int tid = threadIdx.x, l = tid & 63, wv = tid >> 6;
    float4 v = *(const float4*)(xr + tid * 4);
    float s = v.x + v.y + v.z + v.w;
    float sq = v.x * v.x + v.y * v.y + v.z * v.z + v.w * v.w;
#pragma unroll
    for (int off = 32; off > 0; off >>= 1) {
        s += __shfl_down(s, off);
        sq += __shfl_down(sq, off);
    }
    __shared__ float red[8];
    if (l == 0) { red[wv] = s; red[wv + 4] = sq; }
    __syncthreads();
    float ts = red[0] + red[1] + red[2] + red[3];
    float tq = red[4] + red[5] + red[6] + red[7];
    float mean = ts * (1.0f / Cn);
    float var = tq * (1.0f / Cn) - mean * mean;
    float rstd = rsqrtf(var + 1e-5f);
    float4 wv4 = *(const float4*)(w + tid * 4);
    float4 bv4 = *(const float4*)(b + tid * 4);
    f16x4v o;
    o[0] = (f16)((v.x - mean) * rstd * wv4.x + bv4.x);
    o[1] = (f16)((v.y - mean) * rstd * wv4.y + bv4.y);
    o[2] = (f16)((v.z - mean) * rstd * wv4.z + bv4.z);
    o[3] = (f16)((v.w - mean) * rstd * wv4.w + bv4.w);
    *(f16x4v*)(out + (size_t)row * Cn + tid * 4) = o;
}

// ---------------------------------------------------------------------------
// Transpose + cast fp32 -> f16:  out[c][r] = in[r][c].  32x32 tiles.
// ---------------------------------------------------------------------------
__global__ __launch_bounds__(256) void tr_cast_f32(const float* __restrict__ in, int irs,
                                                   f16* __restrict__ out, int ors) {
    __shared__ float tile[32][33];
    int r0 = blockIdx.x * 32, c0 = blockIdx.y * 32;
    int t = threadIdx.x;
    int rr = t >> 3, c4 = (t & 7) * 4;
    float4 v = *(const float4*)(in + (size_t)(r0 + rr) * irs + c0 + c4);
    tile[rr][c4] = v.x; tile[rr][c4 + 1] = v.y; tile[rr][c4 + 2] = v.z; tile[rr][c4 + 3] = v.w;
    __syncthreads();
    int cc = t >> 3, r4 = (t & 7) * 4;
    f16x4v o;
    o[0] = (f16)tile[r4][cc];
    o[1] = (f16)tile[r4 + 1][cc];
    o[2] = (f16)tile[r4 + 2][cc];
    o[3] = (f16)tile[r4 + 3][cc];
    *(f16x4v*)(out + (size_t)(c0 + cc) * ors + r0 + r4) = o;
}

// Same, but gathers Wq/Wk/Wv [H][C][HS] into Wqkv^T rows n = qkv*1024 + h*64 + s.
__global__ __launch_bounds__(256) void tr_cast_qkv(const float* __restrict__ Wq,
                                                   const float* __restrict__ Wk,
                                                   const float* __restrict__ Wv,
                                                   f16* __restrict__ out) {
    int z = blockIdx.z;
    int qkv = z >> 4, h = z & 15;
    const float* in = (qkv == 0 ? Wq : qkv == 1 ? Wk : Wv) + (size_t)h * Cn * HSn; // [1024][64]
    f16* o = out + (size_t)(qkv * Cn + h * HSn) * Cn;
    __shared__ float tile[32][33];
    int r0 = blockIdx.x * 32, c0 = blockIdx.y * 32;
    int t = threadIdx.x;
    int rr = t >> 3, c4 = (t & 7) * 4;
    float4 v = *(const float4*)(in + (size_t)(r0 + rr) * HSn + c0 + c4);
    tile[rr][c4] = v.x; tile[rr][c4 + 1] = v.y; tile[rr][c4 + 2] = v.z; tile[rr][c4 + 3] = v.w;
    __syncthreads();
    int cc = t >> 3, r4 = (t & 7) * 4;
    f16x4v ov;
    ov[0] = (f16)tile[r4][cc];
    ov[1] = (f16)tile[r4 + 1][cc];
    ov[2] = (f16)tile[r4 + 2][cc];
    ov[3] = (f16)tile[r4 + 3][cc];
    *(f16x4v*)(o + (size_t)(c0 + cc) * Cn + r0 + r4) = ov;
}

// ---------------------------------------------------------------------------
// f16 transpose: vT[bh][s][t] = QKV[(b*T+t)][2048 + h*64 + s].  64x64 tiles.
// ---------------------------------------------------------------------------
__global__ __launch_bounds__(256) void tr_vT(const f16* __restrict__ QKV, f16* __restrict__ vT) {
    int bh = blockIdx.z;
    int b = bh >> 4, h = bh & 15;
    const f16* in = QKV + (size_t)b * Tn * 3072 + 2048 + h * HSn; // [T][64] stride 3072
    f16* out = vT + (size_t)bh * HSn * Tn;                        // [64][T]
    int r0 = blockIdx.x * 64;
    __shared__ __align__(16) f16 tile[64][72];
    int t = threadIdx.x;
#pragma unroll
    for (int i = 0; i < 2; i++) {
        int f = i * 256 + t;
        int rr = f >> 3, c8 = (f & 7) * 8;
        *(uint4*)(&tile[rr][c8]) = *(const uint4*)(in + (size_t)(r0 + rr) * 3072 + c8);
    }
    __syncthreads();
#pragma unroll
    for (int i = 0; i < 2; i++) {
        int f = i * 256 + t;
        int cc = f >> 3, r8 = (f & 7) * 8;
        union { f16 h[8]; uint4 v; } u;
#pragma unroll
        for (int j = 0; j < 8; j++) u.h[j] = tile[r8 + j][cc];
        *(uint4*)(out + (size_t)cc * Tn + r0 + r8) = u.v;
    }
}

// ---------------------------------------------------------------------------
// gemm8: C[M][N] = A[M][K] @ Bt[N][K]^T, 256x256 tile, 8 waves (2M x 4N),
// BK=32, 4 LDS buffers, stage depth 3, vmcnt(8)+s_barrier per K-tile,
// 2 phases x 16 MFMA, XOR chunk swizzle both sides, setprio.  (QKV, FF1)
// ---------------------------------------------------------------------------
template <int EPI>
__global__ __launch_bounds__(512, 2) void gemm8(const f16* __restrict__ A, const f16* __restrict__ Bt,
                                                f16* __restrict__ Cout, int M, int N, int K) {
    __shared__ __align__(16) f16 Abuf[4][8192];
    __shared__ __align__(16) f16 Bbuf[4][8192];
    int wg = blockIdx.x;
    int xcd = wg & 7, idx = wg >> 3;
    int bm = xcd * 2 + (idx & 1), bn = idx >> 1;
    int tid = threadIdx.x, l = tid & 63, w = tid >> 6;
    int wr = w >> 2, wc = w & 3;

    f32x4 acc[8][4];
#pragma unroll
    for (int m = 0; m < 8; m++)
#pragma unroll
        for (int n = 0; n < 4; n++) acc[m][n] = f32x4{0.f, 0.f, 0.f, 0.f};

    int l15 = l & 15;
    int lane_off = l15 * 32 + (((l >> 4) ^ ((l15 >> 1) & 3)) << 3);
    const f16* Afr = &Abuf[0][wr * 4096 + lane_off];
    const f16* Bfr = &Bbuf[0][(wc >> 1) * 4096 + (wc & 1) * 2048 + lane_off];

    int srow = w * 16 + (l >> 2);
    int schunk = (l & 3) ^ ((l >> 3) & 3);
    const f16* agp = A + (size_t)(bm * 256 + srow) * K + schunk * 8;
    const f16* bgp = Bt + (size_t)(bn * 256 + srow) * K + schunk * 8;
    const size_t rK = (size_t)128 * K;
    f16* dstA = &Abuf[0][w * 512];
    f16* dstB = &Bbuf[0][w * 512];

    auto stage = [&](int kt, int bf) {
        int k0 = kt * 32;
        glds16(agp + k0, dstA + bf * 8192);
        glds16(agp + rK + k0, dstA + bf * 8192 + 4096);
        glds16(bgp + k0, dstB + bf * 8192);
        glds16(bgp + rK + k0, dstB + bf * 8192 + 4096);
    };

    int NT = K >> 5;
    stage(0, 0);
    stage(1, 1);
    stage(2, 2);
    for (int t = 0; t < NT; ++t) {
        int cb = t & 3;
        VMCNT(8);
        barrier_raw();
        const f16* Ab = Afr + cb * 8192;
        const f16* Bb = Bfr + cb * 8192;
        f16x8 af[4], bf4[4];
#pragma unroll
        for (int m = 0; m < 4; m++) af[m] = *(const f16x8*)(Ab + m * 512);
#pragma unroll
        for (int n = 0; n < 4; n++) bf4[n] = *(const f16x8*)(Bb + n * 512);
        if (t + 3 < NT) stage(t + 3, (t + 3) & 3);
        __builtin_amdgcn_s_setprio(1);
#pragma unroll
        for (int m = 0; m < 4; m++)
#pragma unroll
            for (int n = 0; n < 4; n++)
                acc[m][n] = __builtin_amdgcn_mfma_f32_16x16x32_f16(af[m], bf4[n], acc[m][n], 0, 0, 0);
        __builtin_amdgcn_s_setprio(0);
        barrier_raw();
#pragma unroll
        for (int m = 0; m < 4; m++) af[m] = *(const f16x8*)(Ab + (m + 4) * 512);
        __builtin_amdgcn_s_setprio(1);
#pragma unroll
        for (int m = 0; m < 4; m++)
#pragma unroll
            for (int n = 0; n < 4; n++)
                acc[m + 4][n] = __builtin_amdgcn_mfma_f32_16x16x32_f16(af[m], bf4[n], acc[m + 4][n], 0, 0, 0);
        __builtin_amdgcn_s_setprio(0);
    }
    VMCNT(0);

    int row0 = bm * 256 + wr * 128 + (l >> 4) * 4;
    int col0 = bn * 256 + wc * 64 + (l & 15);
#pragma unroll
    for (int m = 0; m < 8; m++) {
#pragma unroll
        for (int n = 0; n < 4; n++) {
#pragma unroll
            for (int r = 0; r < 4; r++) {
                size_t idx = (size_t)(row0 + m * 16 + r) * N + (col0 + n * 16);
                float v = acc[m][n][r];
                if constexpr (EPI == 1) v = fmaxf(v, 0.f);
                Cout[idx] = (f16)v;
            }
        }
    }
}

// L2-aware decode for 128^2 grids: XCD x owns bm-chunk [4x, 4x+4).
__device__ __forceinline__ void l2_map(int& bm, int& bn) {
    int wg = blockIdx.y * 32 + blockIdx.x;
    int x = wg & 7, idx = wg >> 3;
    bm = x * 4 + (idx & 3);
    bn = idx >> 2;
}

// ---------------------------------------------------------------------------
// GEMM with in-block split-K + deep pipeline: 512 threads = 2 groups x 4
// waves; group g covers K-range [g*K/2, (g+1)*K/2) with its own 3-buffer
// counted-vmcnt pipeline (per wave 4 loads/stage; at top of iter t the
// outstanding loads are tiles t and t+1 -> vmcnt(4) retires exactly tile t;
// stage(t+2) issued after the barrier; buffer (t+2)%3 is WAR-safe because
// its iter-(t-1) ds_reads completed before their consuming MFMAs, which
// precede the barrier).  Groups have identical KT -> barriers collective.
// XOR chunk swizzle both sides (same algebra as gemm8, group-local row ==
// tid>>2 pattern).  Group 1 reduced into group 0 via LDS.  96KB LDS (grid
// is 256 blocks = 1 block/CU regardless).  (proj, FF2)
// ---------------------------------------------------------------------------
template <int EPI>
__global__ __launch_bounds__(512) void gemm_ks(const f16* __restrict__ A, const f16* __restrict__ Bt,
                                               void* __restrict__ Cout, const float* __restrict__ resid,
                                               int M, int N, int K) {
    __shared__ __align__(16) char smem[98304];
    f16* As = (f16*)smem;            // [grp][3][4096] = 48KB
    f16* Bs = (f16*)(smem + 49152);  // [grp][3][4096] = 48KB
    int bm, bn;
    l2_map(bm, bn);
    int tid = threadIdx.x, l = tid & 63, w = tid >> 6;
    int grp = w >> 2, wl = w & 3;
    int wr = wl >> 1, wc = wl & 1;
    int Kh = K >> 1;
    int KT = Kh >> 5;

    f32x4 acc[4][4];
#pragma unroll
    for (int m = 0; m < 4; m++)
#pragma unroll
        for (int n = 0; n < 4; n++) acc[m][n] = f32x4{0.f, 0.f, 0.f, 0.f};

    // staging: group-local row = wl*16 + (l>>2) (+64), swizzled chunk
    int schunk = (l & 3) ^ ((l >> 3) & 3);
    const f16* agp = A + (size_t)(bm * 128 + wl * 16 + (l >> 2)) * K + grp * Kh + schunk * 8;
    const f16* bgp = Bt + (size_t)(bn * 128 + wl * 16 + (l >> 2)) * K + grp * Kh + schunk * 8;
    const size_t half = (size_t)64 * K;
    f16* Ab = As + grp * 12288;
    f16* Bb = Bs + grp * 12288;

    auto stage = [&](int kt, int bf) {
        size_t k0 = (size_t)kt * 32;
        glds16(agp + k0, Ab + bf * 4096 + wl * 512);
        glds16(agp + half + k0, Ab + bf * 4096 + 2048 + wl * 512);
        glds16(bgp + k0, Bb + bf * 4096 + wl * 512);
        glds16(bgp + half + k0, Bb + bf * 4096 + 2048 + wl * 512);
    };

    // fragment reads: row' = wr*64 + (l&15) + m*16; chunk = (l>>4) ^ ((row'>>1)&3)
    int l15 = l & 15;
    int rbase = (wr * 64 + l15) * 32 + (((l >> 4) ^ ((l15 >> 1) & 3)) << 3);
    int cbase = (wc * 64 + l15) * 32 + (((l >> 4) ^ ((l15 >> 1) & 3)) << 3);

    stage(0, 0);
    if (KT > 1) stage(1, 1);
    int nb = 2;
    for (int kt = 0; kt < KT; ++kt) {
        int cb = kt % 3;
        if (kt + 1 < KT) VMCNT(4);
        else VMCNT(0);
        barrier_raw();
        if (kt + 2 < KT) { stage(kt + 2, nb); nb = (nb == 2) ? 0 : nb + 1; }
        f16x8 af[4], bfr[4];
#pragma unroll
        for (int m = 0; m < 4; m++) af[m] = *(const f16x8*)(Ab + cb * 4096 + rbase + m * 512);
#pragma unroll
        for (int n = 0; n < 4; n++) bfr[n] = *(const f16x8*)(Bb + cb * 4096 + cbase + n * 512);
        __builtin_amdgcn_s_setprio(1);
#pragma unroll
        for (int m = 0; m < 4; m++)
#pragma unroll
            for (int n = 0; n < 4; n++)
                acc[m][n] = __builtin_amdgcn_mfma_f32_16x16x32_f16(af[m], bfr[n], acc[m][n], 0, 0, 0);
        __builtin_amdgcn_s_setprio(0);
    }
    __syncthreads(); // all compute done (drains lgkm/vm) before red aliases As

    // cross-group reduction: group1 -> LDS -> group0 (stride-20 spreads banks)
    float* red = (float*)smem;
#pragma unroll
    for (int m = 0; m < 4; m++) {
        if (grp == 1) {
#pragma unroll
            for (int n = 0; n < 4; n++)
                *(f32x4*)(red + wl * 1280 + l * 20 + n * 4) = acc[m][n];
        }
        __syncthreads();
        if (grp == 0) {
#pragma unroll
            for (int n = 0; n < 4; n++)
                acc[m][n] += *(const f32x4*)(red + wl * 1280 + l * 20 + n * 4);
        }
        __syncthreads();
    }

    if (grp == 0) {
        int row0 = bm * 128 + wr * 64 + (l >> 4) * 4;
        int col0 = bn * 128 + wc * 64 + (l & 15);
#pragma unroll
        for (int m = 0; m < 4; m++) {
#pragma unroll
            for (int n = 0; n < 4; n++) {
#pragma unroll
                for (int r = 0; r < 4; r++) {
                    size_t idx = (size_t)(row0 + m * 16 + r) * N + (col0 + n * 16);
                    float v = acc[m][n][r];
                    if constexpr (EPI == 0) ((f16*)Cout)[idx] = (f16)v;
                    else if constexpr (EPI == 1) ((f16*)Cout)[idx] = (f16)fmaxf(v, 0.f);
                    else ((float*)Cout)[idx] = v + resid[idx];
                }
            }
        }
    }
}

// ---------------------------------------------------------------------------
// Flash attention, causal.  Block = (bh, qtile-pair), 4 waves x 16 q-rows.
// Swapped QK^T (lane-local softmax stats), exp2-domain softmax (Q pre-scaled
// by scale*log2e), diagonal-only mask, defer-rescale (THR=8), 2-buffer K/V.
// ---------------------------------------------------------------------------
__global__ __launch_bounds__(256) void attn_kernel(const f16* __restrict__ QKV,
                                                   const f16* __restrict__ vT,
                                                   const float* __restrict__ p,
                                                   f16* __restrict__ att) {
    int wg = blockIdx.x;
    int x = wg & 7, idx = wg >> 3;
    int bh = x * 4 + (idx & 3);
    int pq = idx >> 2; // 0..15
    int b = bh >> 4, h = bh & 15;
    int tid = threadIdx.x, w = tid >> 6, l = tid & 63;
    float sc2 = rsqrtf(p[h]) * 1.44269504f; // scale * log2(e)

    __shared__ __align__(16) f16 Ks[2][4096];
    __shared__ __align__(16) f16 Vs[2][4096];
    __shared__ __align__(16) f16 Ps[4][16 * 80];
    f16* Pw = &Ps[w][0];

    int srow0 = tid >> 3;
    int c0 = (tid & 7) ^ (srow0 & 7);
    int srow1 = 32 + srow0;
    int c1 = (tid & 7) ^ (srow1 & 7);
    const f16* Kg = QKV + (size_t)b * Tn * 3072 + 1024 + h * HSn;
    const f16* Vg = vT + (size_t)bh * HSn * Tn;

    auto stageKV = [&](int kv0, int bf) {
        glds16(Kg + (size_t)(kv0 + srow0) * 3072 + c0 * 8, &Ks[bf][w * 512]);
        glds16(Kg + (size_t)(kv0 + srow1) * 3072 + c1 * 8, &Ks[bf][2048 + w * 512]);
        glds16(Vg + (size_t)srow0 * Tn + kv0 + c0 * 8, &Vs[bf][w * 512]);
        glds16(Vg + (size_t)srow1 * Tn + kv0 + c1 * 8, &Vs[bf][2048 + w * 512]);
    };

    for (int pass = 0; pass < 2; ++pass) {
        int qt = pass ? (31 - pq) : pq;
        int qg = qt * 64 + w * 16 + (l & 15);
        int qo = qt * 64 + w * 16 + (l >> 4) * 4;
        const f16* qptr = QKV + (size_t)(b * Tn + qg) * 3072 + h * HSn + (l >> 4) * 8;
        f16x8 qf0 = *(const f16x8*)(qptr);
        f16x8 qf1 = *(const f16x8*)(qptr + 32);
        f16 sch = (f16)sc2;
#pragma unroll
        for (int j = 0; j < 8; j++) { qf0[j] *= sch; qf1[j] *= sch; }

        f32x4 o[4];
#pragma unroll
        for (int nf = 0; nf < 4; nf++) o[nf] = f32x4{0.f, 0.f, 0.f, 0.f};
        float m_r = -1e30f, l_r = 0.f;

        int nt = qt + 1;
        stageKV(0, 0);
        __syncthreads();
        for (int t = 0; t < nt; ++t) {
            int cb = t & 1, kv0 = t * 64;
            if (t + 1 < nt) stageKV(kv0 + 64, cb ^ 1);
            const char* Kb = (const char*)&Ks[cb][0];
            const char* Vb = (const char*)&Vs[cb][0];
            f32x4 s[4];
#pragma unroll
            for (int n = 0; n < 4; n++) s[n] = f32x4{0.f, 0.f, 0.f, 0.f};
            __builtin_amdgcn_s_setprio(1);
#pragma unroll
            for (int n = 0; n < 4; n++) {
#pragma unroll
                for (int ks = 0; ks < 2; ks++) {
                    int boff = (n * 16 + (l & 15)) * 128 + (((ks * 32 + (l >> 4) * 8) * 2) ^ ((l & 7) << 4));
                    f16x8 kf = *(const f16x8*)(Kb + boff);
                    s[n] = __builtin_amdgcn_mfma_f32_16x16x32_f16(kf, ks == 0 ? qf0 : qf1, s[n], 0, 0, 0);
                }
            }
            __builtin_amdgcn_s_setprio(0);
            if (t == qt) { // mask only on the diagonal tile
                int rel = qg - kv0;
#pragma unroll
                for (int n = 0; n < 4; n++)
#pragma unroll
                    for (int r = 0; r < 4; r++) {
                        int kvr = n * 16 + (l >> 4) * 4 + r;
                        if (kvr > rel) s[n][r] = -1e30f;
                    }
            }
            float tmax = -1e30f;
#pragma unroll
            for (int n = 0; n < 4; n++)
#pragma unroll
                for (int r = 0; r < 4; r++) tmax = fmaxf(tmax, s[n][r]);
            tmax = fmaxf(tmax, __shfl_xor(tmax, 16));
            tmax = fmaxf(tmax, __shfl_xor(tmax, 32));
            float lmul = 1.f;
            if (__any(tmax > m_r + 8.f)) { // T13 defer-rescale (exp2 domain)
                float mnew = fmaxf(m_r, tmax);
                lmul = exp2f(m_r - mnew);
                m_r = mnew;
                float ar[4];
#pragma unroll
                for (int r = 0; r < 4; r++) ar[r] = __shfl(lmul, (l >> 4) * 4 + r);
#pragma unroll
                for (int nf = 0; nf < 4; nf++)
#pragma unroll
                    for (int r = 0; r < 4; r++) o[nf][r] *= ar[r];
            }
            float rsum = 0.f;
#pragma unroll
            for (int n = 0; n < 4; n++) {
                f16x4v pk;
#pragma unroll
                for (int r = 0; r < 4; r++) {
                    float e = exp2f(s[n][r] - m_r);
                    rsum += e;
                    pk[r] = (f16)e;
                }
                *(f16x4v*)(&Pw[(l & 15) * 80 + n * 16 + (l >> 4) * 4]) = pk;
            }
            rsum += __shfl_xor(rsum, 16);
            rsum += __shfl_xor(rsum, 32);
            l_r = l_r * lmul + rsum;
            f16x8 pa0 = *(const f16x8*)(&Pw[(l & 15) * 80 + (l >> 4) * 8]);
            f16x8 pa1 = *(const f16x8*)(&Pw[(l & 15) * 80 + 32 + (l >> 4) * 8]);
            __builtin_amdgcn_s_setprio(1);
#pragma unroll
            for (int nf = 0; nf < 4; nf++) {
#pragma unroll
                for (int ks = 0; ks < 2; ks++) {
                    int boff = (nf * 16 + (l & 15)) * 128 + (((ks * 32 + (l >> 4) * 8) * 2) ^ ((l & 7) << 4));
                    f16x8 vf = *(const f16x8*)(Vb + boff);
                    o[nf] = __builtin_amdgcn_mfma_f32_16x16x32_f16(ks == 0 ? pa0 : pa1, vf, o[nf], 0, 0, 0);
                }
            }
            __builtin_amdgcn_s_setprio(0);
            __syncthreads();
        }
        float lro[4];
#pragma unroll
        for (int r = 0; r < 4; r++) lro[r] = __shfl(l_r, (l >> 4) * 4 + r);
#pragma unroll
        for (int nf = 0; nf < 4; nf++) {
#pragma unroll
            for (int r = 0; r < 4; r++) {
                float v = o[nf][r] / lro[r];
                att[(size_t)(b * Tn + qo + r) * Cn + h * HSn + nf * 16 + (l & 15)] = (f16)v;
            }
        }
    }
}

// ---------------------------------------------------------------------------
extern "C" void kernel_launch(void* const* d_in, const int* in_sizes, int n_in,
                              void* d_out, int out_size, void* d_ws, size_t ws_size,
                              hipStream_t stream) {
    const float* x = (const float*)d_in[0];
    const float* Wq = (const float*)d_in[1];
    const float* Wk = (const float*)d_in[2];
    const float* Wv = (const float*)d_in[3];
    const float* p = (const float*)d_in[4];
    const float* Wproj = (const float*)d_in[5];
    const float* W1 = (const float*)d_in[6];
    const float* W2 = (const float*)d_in[7];
    const float* ln1w = (const float*)d_in[8];
    const float* ln1b = (const float*)d_in[9];
    const float* ln2w = (const float*)d_in[10];
    const float* ln2b = (const float*)d_in[11];

    char* ws = (char*)d_ws;
    const size_t MB = 1ull << 20;
    f16* Wqkv_t = (f16*)(ws + 0 * MB);   // [3072][1024]
    f16* Wproj_t = (f16*)(ws + 6 * MB);  // [1024][1024]
    f16* W1_t = (f16*)(ws + 8 * MB);     // [4096][1024]
    f16* W2_t = (f16*)(ws + 16 * MB);    // [1024][4096]
    float* x1 = (float*)(ws + 24 * MB);  // [4096][1024] f32
    f16* QKV = (f16*)(ws + 40 * MB);     // [4096][3072]
    f16* h1 = (f16*)(ws + 64 * MB);      // [4096][1024]
    f16* vTb = (f16*)(ws + 64 * MB);     // [32][64][2048] (reuses h1 slot)
    f16* attb = (f16*)(ws + 72 * MB);    // [4096][1024]
    f16* h2 = attb;                      // reuse (att dead after proj gemm)
    f16* ffh = QKV;                      // [4096][4096] spans 40M..72M
    float* out = (float*)d_out;

    // weight repack (transposed f16)
    tr_cast_qkv<<<dim3(32, 2, 48), 256, 0, stream>>>(Wq, Wk, Wv, Wqkv_t);
    tr_cast_f32<<<dim3(32, 32), 256, 0, stream>>>(Wproj, 1024, Wproj_t, 1024);
    tr_cast_f32<<<dim3(32, 128), 256, 0, stream>>>(W1, 4096, W1_t, 1024);
    tr_cast_f32<<<dim3(128, 32), 256, 0, stream>>>(W2, 1024, W2_t, 4096);

    // block forward
    ln_kernel<<<4096, 256, 0, stream>>>(x, ln1w, ln1b, h1);
    gemm8<0><<<192, 512, 0, stream>>>(h1, Wqkv_t, QKV, 4096, 3072, 1024);
    tr_vT<<<dim3(32, 1, 32), 256, 0, stream>>>(QKV, vTb);
    attn_kernel<<<512, 256, 0, stream>>>(QKV, vTb, p, attb);
    gemm_ks<2><<<dim3(32, 8), 512, 0, stream>>>(attb, Wproj_t, x1, x, 4096, 1024, 1024);
    ln_kernel<<<4096, 256, 0, stream>>>(x1, ln2w, ln2b, h2);
    gemm8<1><<<256, 512, 0, stream>>>(h2, W1_t, ffh, 4096, 4096, 1024);
    gemm_ks<2><<<dim3(32, 8), 512, 0, stream>>>(ffh, W2_t, out, x1, 4096, 1024, 4096);
}

// Round 9
// 221.748 us; speedup vs baseline: 1.4396x; 1.0295x over previous
//
#include <hip/hip_runtime.h>

// ---------------------------------------------------------------------------
// Transformer block forward on gfx950.  B=2 T=2048 C=1024 H=16 HS=64 FF=4096.
// All matmuls: f16 inputs, fp32 MFMA accumulation (16x16x32).
// R9 (= R8 + compile fix): attention rework for TLP + VALU: unpaired q-tiles
//     (grid 1024, 3 blocks/CU, long-blocks-first dispatch), hoisted K/V
//     swizzle offsets, packed cvt_pkrtz (bit-cast via u32) for P, lane-local
//     deferred l-reduce.  GEMMs frozen (gemm8 QKV/FF1, deep gemm_ks proj/FF2).
// Workspace layout (80 MB): unchanged.
// ---------------------------------------------------------------------------

typedef _Float16 f16;
typedef _Float16 f16x8 __attribute__((ext_vector_type(8)));
typedef _Float16 f16x4v __attribute__((ext_vector_type(4)));
typedef float f32x4 __attribute__((ext_vector_type(4)));

static constexpr int Tn = 2048;
static constexpr int Cn = 1024;
static constexpr int HSn = 64;

// async global->LDS, 16B per lane; dest = wave-uniform base + lane*16
__device__ __forceinline__ void glds16(const f16* g, f16* l) {
    __builtin_amdgcn_global_load_lds((const __attribute__((address_space(1))) void*)g,
                                     (__attribute__((address_space(3))) void*)l,
                                     16, 0, 0);
}

#define VMCNT(N) asm volatile("s_waitcnt vmcnt(" #N ")" ::: "memory")
// raw barrier with code-motion fences (no implicit vmcnt/lgkm drain)
__device__ __forceinline__ void barrier_raw() {
    asm volatile("" ::: "memory");
    __builtin_amdgcn_s_barrier();
    asm volatile("" ::: "memory");
}

// pack two f32 -> two f16 (RTZ) as a u32 (v_cvt_pkrtz_f16_f32)
__device__ __forceinline__ unsigned cvt_pk_u32(float a, float b) {
    auto v = __builtin_amdgcn_cvt_pkrtz(a, b);
    union { __fp16 h2 __attribute__((ext_vector_type(2))); unsigned u; } c;
    c.h2 = v;
    return c.u;
}

// ---------------------------------------------------------------------------
// LayerNorm (fp32 in) -> f16 out.  One block per row, 256 threads.
// ---------------------------------------------------------------------------
__global__ __launch_bounds__(256) void ln_kernel(const float* __restrict__ x,
                                                 const float* __restrict__ w,
                                                 const float* __restrict__ b,
                                                 f16* __restrict__ out) {
    int row = blockIdx.x;
    const float* xr = x + (size_t)row * Cn;
    int tid = threadIdx.x, l = tid & 63, wv = tid >> 6;
    float4 v = *(const float4*)(xr + tid * 4);
    float s = v.x + v.y + v.z + v.w;
    float sq = v.x * v.x + v.y * v.y + v.z * v.z + v.w * v.w;
#pragma unroll
    for (int off = 32; off > 0; off >>= 1) {
        s += __shfl_down(s, off);
        sq += __shfl_down(sq, off);
    }
    __shared__ float red[8];
    if (l == 0) { red[wv] = s; red[wv + 4] = sq; }
    __syncthreads();
    float ts = red[0] + red[1] + red[2] + red[3];
    float tq = red[4] + red[5] + red[6] + red[7];
    float mean = ts * (1.0f / Cn);
    float var = tq * (1.0f / Cn) - mean * mean;
    float rstd = rsqrtf(var + 1e-5f);
    float4 wv4 = *(const float4*)(w + tid * 4);
    float4 bv4 = *(const float4*)(b + tid * 4);
    f16x4v o;
    o[0] = (f16)((v.x - mean) * rstd * wv4.x + bv4.x);
    o[1] = (f16)((v.y - mean) * rstd * wv4.y + bv4.y);
    o[2] = (f16)((v.z - mean) * rstd * wv4.z + bv4.z);
    o[3] = (f16)((v.w - mean) * rstd * wv4.w + bv4.w);
    *(f16x4v*)(out + (size_t)row * Cn + tid * 4) = o;
}

// ---------------------------------------------------------------------------
// Transpose + cast fp32 -> f16:  out[c][r] = in[r][c].  32x32 tiles.
// ---------------------------------------------------------------------------
__global__ __launch_bounds__(256) void tr_cast_f32(const float* __restrict__ in, int irs,
                                                   f16* __restrict__ out, int ors) {
    __shared__ float tile[32][33];
    int r0 = blockIdx.x * 32, c0 = blockIdx.y * 32;
    int t = threadIdx.x;
    int rr = t >> 3, c4 = (t & 7) * 4;
    float4 v = *(const float4*)(in + (size_t)(r0 + rr) * irs + c0 + c4);
    tile[rr][c4] = v.x; tile[rr][c4 + 1] = v.y; tile[rr][c4 + 2] = v.z; tile[rr][c4 + 3] = v.w;
    __syncthreads();
    int cc = t >> 3, r4 = (t & 7) * 4;
    f16x4v o;
    o[0] = (f16)tile[r4][cc];
    o[1] = (f16)tile[r4 + 1][cc];
    o[2] = (f16)tile[r4 + 2][cc];
    o[3] = (f16)tile[r4 + 3][cc];
    *(f16x4v*)(out + (size_t)(c0 + cc) * ors + r0 + r4) = o;
}

// Same, but gathers Wq/Wk/Wv [H][C][HS] into Wqkv^T rows n = qkv*1024 + h*64 + s.
__global__ __launch_bounds__(256) void tr_cast_qkv(const float* __restrict__ Wq,
                                                   const float* __restrict__ Wk,
                                                   const float* __restrict__ Wv,
                                                   f16* __restrict__ out) {
    int z = blockIdx.z;
    int qkv = z >> 4, h = z & 15;
    const float* in = (qkv == 0 ? Wq : qkv == 1 ? Wk : Wv) + (size_t)h * Cn * HSn; // [1024][64]
    f16* o = out + (size_t)(qkv * Cn + h * HSn) * Cn;
    __shared__ float tile[32][33];
    int r0 = blockIdx.x * 32, c0 = blockIdx.y * 32;
    int t = threadIdx.x;
    int rr = t >> 3, c4 = (t & 7) * 4;
    float4 v = *(const float4*)(in + (size_t)(r0 + rr) * HSn + c0 + c4);
    tile[rr][c4] = v.x; tile[rr][c4 + 1] = v.y; tile[rr][c4 + 2] = v.z; tile[rr][c4 + 3] = v.w;
    __syncthreads();
    int cc = t >> 3, r4 = (t & 7) * 4;
    f16x4v ov;
    ov[0] = (f16)tile[r4][cc];
    ov[1] = (f16)tile[r4 + 1][cc];
    ov[2] = (f16)tile[r4 + 2][cc];
    ov[3] = (f16)tile[r4 + 3][cc];
    *(f16x4v*)(o + (size_t)(c0 + cc) * Cn + r0 + r4) = ov;
}

// ---------------------------------------------------------------------------
// f16 transpose: vT[bh][s][t] = QKV[(b*T+t)][2048 + h*64 + s].  64x64 tiles.
// ---------------------------------------------------------------------------
__global__ __launch_bounds__(256) void tr_vT(const f16* __restrict__ QKV, f16* __restrict__ vT) {
    int bh = blockIdx.z;
    int b = bh >> 4, h = bh & 15;
    const f16* in = QKV + (size_t)b * Tn * 3072 + 2048 + h * HSn; // [T][64] stride 3072
    f16* out = vT + (size_t)bh * HSn * Tn;                        // [64][T]
    int r0 = blockIdx.x * 64;
    __shared__ __align__(16) f16 tile[64][72];
    int t = threadIdx.x;
#pragma unroll
    for (int i = 0; i < 2; i++) {
        int f = i * 256 + t;
        int rr = f >> 3, c8 = (f & 7) * 8;
        *(uint4*)(&tile[rr][c8]) = *(const uint4*)(in + (size_t)(r0 + rr) * 3072 + c8);
    }
    __syncthreads();
#pragma unroll
    for (int i = 0; i < 2; i++) {
        int f = i * 256 + t;
        int cc = f >> 3, r8 = (f & 7) * 8;
        union { f16 h[8]; uint4 v; } u;
#pragma unroll
        for (int j = 0; j < 8; j++) u.h[j] = tile[r8 + j][cc];
        *(uint4*)(out + (size_t)cc * Tn + r0 + r8) = u.v;
    }
}

// ---------------------------------------------------------------------------
// gemm8: C[M][N] = A[M][K] @ Bt[N][K]^T, 256x256 tile, 8 waves (2M x 4N),
// BK=32, 4 LDS buffers, stage depth 3, vmcnt(8)+s_barrier per K-tile,
// 2 phases x 16 MFMA, XOR chunk swizzle both sides, setprio.  (QKV, FF1)
// ---------------------------------------------------------------------------
template <int EPI>
__global__ __launch_bounds__(512, 2) void gemm8(const f16* __restrict__ A, const f16* __restrict__ Bt,
                                                f16* __restrict__ Cout, int M, int N, int K) {
    __shared__ __align__(16) f16 Abuf[4][8192];
    __shared__ __align__(16) f16 Bbuf[4][8192];
    int wg = blockIdx.x;
    int xcd = wg & 7, idx = wg >> 3;
    int bm = xcd * 2 + (idx & 1), bn = idx >> 1;
    int tid = threadIdx.x, l = tid & 63, w = tid >> 6;
    int wr = w >> 2, wc = w & 3;

    f32x4 acc[8][4];
#pragma unroll
    for (int m = 0; m < 8; m++)
#pragma unroll
        for (int n = 0; n < 4; n++) acc[m][n] = f32x4{0.f, 0.f, 0.f, 0.f};

    int l15 = l & 15;
    int lane_off = l15 * 32 + (((l >> 4) ^ ((l15 >> 1) & 3)) << 3);
    const f16* Afr = &Abuf[0][wr * 4096 + lane_off];
    const f16* Bfr = &Bbuf[0][(wc >> 1) * 4096 + (wc & 1) * 2048 + lane_off];

    int srow = w * 16 + (l >> 2);
    int schunk = (l & 3) ^ ((l >> 3) & 3);
    const f16* agp = A + (size_t)(bm * 256 + srow) * K + schunk * 8;
    const f16* bgp = Bt + (size_t)(bn * 256 + srow) * K + schunk * 8;
    const size_t rK = (size_t)128 * K;
    f16* dstA = &Abuf[0][w * 512];
    f16* dstB = &Bbuf[0][w * 512];

    auto stage = [&](int kt, int bf) {
        int k0 = kt * 32;
        glds16(agp + k0, dstA + bf * 8192);
        glds16(agp + rK + k0, dstA + bf * 8192 + 4096);
        glds16(bgp + k0, dstB + bf * 8192);
        glds16(bgp + rK + k0, dstB + bf * 8192 + 4096);
    };

    int NT = K >> 5;
    stage(0, 0);
    stage(1, 1);
    stage(2, 2);
    for (int t = 0; t < NT; ++t) {
        int cb = t & 3;
        VMCNT(8);
        barrier_raw();
        const f16* Ab = Afr + cb * 8192;
        const f16* Bb = Bfr + cb * 8192;
        f16x8 af[4], bf4[4];
#pragma unroll
        for (int m = 0; m < 4; m++) af[m] = *(const f16x8*)(Ab + m * 512);
#pragma unroll
        for (int n = 0; n < 4; n++) bf4[n] = *(const f16x8*)(Bb + n * 512);
        if (t + 3 < NT) stage(t + 3, (t + 3) & 3);
        __builtin_amdgcn_s_setprio(1);
#pragma unroll
        for (int m = 0; m < 4; m++)
#pragma unroll
            for (int n = 0; n < 4; n++)
                acc[m][n] = __builtin_amdgcn_mfma_f32_16x16x32_f16(af[m], bf4[n], acc[m][n], 0, 0, 0);
        __builtin_amdgcn_s_setprio(0);
        barrier_raw();
#pragma unroll
        for (int m = 0; m < 4; m++) af[m] = *(const f16x8*)(Ab + (m + 4) * 512);
        __builtin_amdgcn_s_setprio(1);
#pragma unroll
        for (int m = 0; m < 4; m++)
#pragma unroll
            for (int n = 0; n < 4; n++)
                acc[m + 4][n] = __builtin_amdgcn_mfma_f32_16x16x32_f16(af[m], bf4[n], acc[m + 4][n], 0, 0, 0);
        __builtin_amdgcn_s_setprio(0);
    }
    VMCNT(0);

    int row0 = bm * 256 + wr * 128 + (l >> 4) * 4;
    int col0 = bn * 256 + wc * 64 + (l & 15);
#pragma unroll
    for (int m = 0; m < 8; m++) {
#pragma unroll
        for (int n = 0; n < 4; n++) {
#pragma unroll
            for (int r = 0; r < 4; r++) {
                size_t idx = (size_t)(row0 + m * 16 + r) * N + (col0 + n * 16);
                float v = acc[m][n][r];
                if constexpr (EPI == 1) v = fmaxf(v, 0.f);
                Cout[idx] = (f16)v;
            }
        }
    }
}

// L2-aware decode for 128^2 grids: XCD x owns bm-chunk [4x, 4x+4).
__device__ __forceinline__ void l2_map(int& bm, int& bn) {
    int wg = blockIdx.y * 32 + blockIdx.x;
    int x = wg & 7, idx = wg >> 3;
    bm = x * 4 + (idx & 3);
    bn = idx >> 2;
}

// ---------------------------------------------------------------------------
// GEMM with in-block split-K + deep pipeline (3 buffers, vmcnt(4), raw
// barriers, XOR swizzle both sides).  Group 1 reduced into group 0 via LDS.
// (proj, FF2)
// ---------------------------------------------------------------------------
template <int EPI>
__global__ __launch_bounds__(512) void gemm_ks(const f16* __restrict__ A, const f16* __restrict__ Bt,
                                               void* __restrict__ Cout, const float* __restrict__ resid,
                                               int M, int N, int K) {
    __shared__ __align__(16) char smem[98304];
    f16* As = (f16*)smem;            // [grp][3][4096] = 48KB
    f16* Bs = (f16*)(smem + 49152);  // [grp][3][4096] = 48KB
    int bm, bn;
    l2_map(bm, bn);
    int tid = threadIdx.x, l = tid & 63, w = tid >> 6;
    int grp = w >> 2, wl = w & 3;
    int wr = wl >> 1, wc = wl & 1;
    int Kh = K >> 1;
    int KT = Kh >> 5;

    f32x4 acc[4][4];
#pragma unroll
    for (int m = 0; m < 4; m++)
#pragma unroll
        for (int n = 0; n < 4; n++) acc[m][n] = f32x4{0.f, 0.f, 0.f, 0.f};

    int schunk = (l & 3) ^ ((l >> 3) & 3);
    const f16* agp = A + (size_t)(bm * 128 + wl * 16 + (l >> 2)) * K + grp * Kh + schunk * 8;
    const f16* bgp = Bt + (size_t)(bn * 128 + wl * 16 + (l >> 2)) * K + grp * Kh + schunk * 8;
    const size_t half = (size_t)64 * K;
    f16* Ab = As + grp * 12288;
    f16* Bb = Bs + grp * 12288;

    auto stage = [&](int kt, int bf) {
        size_t k0 = (size_t)kt * 32;
        glds16(agp + k0, Ab + bf * 4096 + wl * 512);
        glds16(agp + half + k0, Ab + bf * 4096 + 2048 + wl * 512);
        glds16(bgp + k0, Bb + bf * 4096 + wl * 512);
        glds16(bgp + half + k0, Bb + bf * 4096 + 2048 + wl * 512);
    };

    int l15 = l & 15;
    int rbase = (wr * 64 + l15) * 32 + (((l >> 4) ^ ((l15 >> 1) & 3)) << 3);
    int cbase = (wc * 64 + l15) * 32 + (((l >> 4) ^ ((l15 >> 1) & 3)) << 3);

    stage(0, 0);
    if (KT > 1) stage(1, 1);
    int nb = 2;
    for (int kt = 0; kt < KT; ++kt) {
        int cb = kt % 3;
        if (kt + 1 < KT) VMCNT(4);
        else VMCNT(0);
        barrier_raw();
        if (kt + 2 < KT) { stage(kt + 2, nb); nb = (nb == 2) ? 0 : nb + 1; }
        f16x8 af[4], bfr[4];
#pragma unroll
        for (int m = 0; m < 4; m++) af[m] = *(const f16x8*)(Ab + cb * 4096 + rbase + m * 512);
#pragma unroll
        for (int n = 0; n < 4; n++) bfr[n] = *(const f16x8*)(Bb + cb * 4096 + cbase + n * 512);
        __builtin_amdgcn_s_setprio(1);
#pragma unroll
        for (int m = 0; m < 4; m++)
#pragma unroll
            for (int n = 0; n < 4; n++)
                acc[m][n] = __builtin_amdgcn_mfma_f32_16x16x32_f16(af[m], bfr[n], acc[m][n], 0, 0, 0);
        __builtin_amdgcn_s_setprio(0);
    }
    __syncthreads(); // all compute done (drains lgkm/vm) before red aliases As

    float* red = (float*)smem;
#pragma unroll
    for (int m = 0; m < 4; m++) {
        if (grp == 1) {
#pragma unroll
            for (int n = 0; n < 4; n++)
                *(f32x4*)(red + wl * 1280 + l * 20 + n * 4) = acc[m][n];
        }
        __syncthreads();
        if (grp == 0) {
#pragma unroll
            for (int n = 0; n < 4; n++)
                acc[m][n] += *(const f32x4*)(red + wl * 1280 + l * 20 + n * 4);
        }
        __syncthreads();
    }

    if (grp == 0) {
        int row0 = bm * 128 + wr * 64 + (l >> 4) * 4;
        int col0 = bn * 128 + wc * 64 + (l & 15);
#pragma unroll
        for (int m = 0; m < 4; m++) {
#pragma unroll
            for (int n = 0; n < 4; n++) {
#pragma unroll
                for (int r = 0; r < 4; r++) {
                    size_t idx = (size_t)(row0 + m * 16 + r) * N + (col0 + n * 16);
                    float v = acc[m][n][r];
                    if constexpr (EPI == 0) ((f16*)Cout)[idx] = (f16)v;
                    else if constexpr (EPI == 1) ((f16*)Cout)[idx] = (f16)fmaxf(v, 0.f);
                    else ((float*)Cout)[idx] = v + resid[idx];
                }
            }
        }
    }
}

// ---------------------------------------------------------------------------
// Flash attention, causal.  One q-tile per block, grid 1024 (3 blocks/CU,
// 42KB LDS), long-blocks-first dispatch (low blockIdx -> large qt), bh
// grouped per XCD.  Swapped QK^T, exp2-domain softmax, diagonal-only mask,
// defer-rescale (THR=8), hoisted swizzle offsets, packed cvt_pkrtz,
// lane-local deferred l-reduce, 2-buffer K/V.
// ---------------------------------------------------------------------------
__global__ __launch_bounds__(256) void attn_kernel(const f16* __restrict__ QKV,
                                                   const f16* __restrict__ vT,
                                                   const float* __restrict__ p,
                                                   f16* __restrict__ att) {
    int i = blockIdx.x;                      // 1024 = 8 xcd x 4 bh x 32 qt
    int bh = (i & 7) * 4 + ((i >> 3) & 3);   // XCD owns 4 heads (K/V L2-fit)
    int qt = 31 - (i >> 5);                  // low idx -> large qt (long first)
    int b = bh >> 4, h = bh & 15;
    int tid = threadIdx.x, w = tid >> 6, l = tid & 63;
    float sc2 = rsqrtf(p[h]) * 1.44269504f;  // scale * log2(e)

    __shared__ __align__(16) f16 Ks[2][4096];
    __shared__ __align__(16) f16 Vs[2][4096];
    __shared__ __align__(16) f16 Ps[4][16 * 80];
    f16* Pw = &Ps[w][0];

    int srow0 = tid >> 3;
    int c0 = (tid & 7) ^ (srow0 & 7);
    int srow1 = 32 + srow0;
    int c1 = (tid & 7) ^ (srow1 & 7);
    const f16* Kg = QKV + (size_t)b * Tn * 3072 + 1024 + h * HSn;
    const f16* Vg = vT + (size_t)bh * HSn * Tn;

    auto stageKV = [&](int kv0, int bf) {
        glds16(Kg + (size_t)(kv0 + srow0) * 3072 + c0 * 8, &Ks[bf][w * 512]);
        glds16(Kg + (size_t)(kv0 + srow1) * 3072 + c1 * 8, &Ks[bf][2048 + w * 512]);
        glds16(Vg + (size_t)srow0 * Tn + kv0 + c0 * 8, &Vs[bf][w * 512]);
        glds16(Vg + (size_t)srow1 * Tn + kv0 + c1 * 8, &Vs[bf][2048 + w * 512]);
    };

    // hoisted swizzled fragment offsets (bytes), static-unrolled -> regs
    int foff[8];
#pragma unroll
    for (int n = 0; n < 4; n++)
#pragma unroll
        for (int ks = 0; ks < 2; ks++)
            foff[n * 2 + ks] = (n * 16 + (l & 15)) * 128 +
                               (((ks * 32 + (l >> 4) * 8) * 2) ^ ((l & 7) << 4));

    int qg = qt * 64 + w * 16 + (l & 15);
    int qo = qt * 64 + w * 16 + (l >> 4) * 4;
    const f16* qptr = QKV + (size_t)(b * Tn + qg) * 3072 + h * HSn + (l >> 4) * 8;
    f16x8 qf0 = *(const f16x8*)(qptr);
    f16x8 qf1 = *(const f16x8*)(qptr + 32);
    f16 sch = (f16)sc2;
#pragma unroll
    for (int j = 0; j < 8; j++) { qf0[j] *= sch; qf1[j] *= sch; }

    f32x4 o[4];
#pragma unroll
    for (int nf = 0; nf < 4; nf++) o[nf] = f32x4{0.f, 0.f, 0.f, 0.f};
    float m_r = -1e30f, l_r = 0.f; // l_r is LANE-LOCAL partial (reduced at end)

    int nt = qt + 1;
    stageKV(0, 0);
    __syncthreads();
    for (int t = 0; t < nt; ++t) {
        int cb = t & 1, kv0 = t * 64;
        if (t + 1 < nt) stageKV(kv0 + 64, cb ^ 1);
        const char* Kb = (const char*)&Ks[cb][0];
        const char* Vb = (const char*)&Vs[cb][0];
        f32x4 s[4];
#pragma unroll
        for (int n = 0; n < 4; n++) s[n] = f32x4{0.f, 0.f, 0.f, 0.f};
        __builtin_amdgcn_s_setprio(1);
#pragma unroll
        for (int n = 0; n < 4; n++)
#pragma unroll
            for (int ks = 0; ks < 2; ks++) {
                f16x8 kf = *(const f16x8*)(Kb + foff[n * 2 + ks]);
                s[n] = __builtin_amdgcn_mfma_f32_16x16x32_f16(kf, ks == 0 ? qf0 : qf1, s[n], 0, 0, 0);
            }
        __builtin_amdgcn_s_setprio(0);
        if (t == qt) { // mask only on the diagonal tile
            int rel = qg - kv0;
#pragma unroll
            for (int n = 0; n < 4; n++)
#pragma unroll
                for (int r = 0; r < 4; r++) {
                    int kvr = n * 16 + (l >> 4) * 4 + r;
                    if (kvr > rel) s[n][r] = -1e30f;
                }
        }
        float tmax = -1e30f;
#pragma unroll
        for (int n = 0; n < 4; n++)
#pragma unroll
            for (int r = 0; r < 4; r++) tmax = fmaxf(tmax, s[n][r]);
        tmax = fmaxf(tmax, __shfl_xor(tmax, 16));
        tmax = fmaxf(tmax, __shfl_xor(tmax, 32));
        float lmul = 1.f;
        if (__any(tmax > m_r + 8.f)) { // T13 defer-rescale (exp2 domain)
            float mnew = fmaxf(m_r, tmax);
            lmul = exp2f(m_r - mnew);
            m_r = mnew;
            float ar[4];
#pragma unroll
            for (int r = 0; r < 4; r++) ar[r] = __shfl(lmul, (l >> 4) * 4 + r);
#pragma unroll
            for (int nf = 0; nf < 4; nf++)
#pragma unroll
                for (int r = 0; r < 4; r++) o[nf][r] *= ar[r];
        }
        float rsum = 0.f;
#pragma unroll
        for (int n = 0; n < 4; n++) {
            float e0 = exp2f(s[n][0] - m_r), e1 = exp2f(s[n][1] - m_r);
            float e2 = exp2f(s[n][2] - m_r), e3 = exp2f(s[n][3] - m_r);
            rsum += (e0 + e1) + (e2 + e3);
            union { unsigned u[2]; f16x4v h4; } u;
            u.u[0] = cvt_pk_u32(e0, e1);
            u.u[1] = cvt_pk_u32(e2, e3);
            *(f16x4v*)(&Pw[(l & 15) * 80 + n * 16 + (l >> 4) * 4]) = u.h4;
        }
        l_r = l_r * lmul + rsum; // lane-local; lmul is row-uniform -> exact
        f16x8 pa0 = *(const f16x8*)(&Pw[(l & 15) * 80 + (l >> 4) * 8]);
        f16x8 pa1 = *(const f16x8*)(&Pw[(l & 15) * 80 + 32 + (l >> 4) * 8]);
        __builtin_amdgcn_s_setprio(1);
#pragma unroll
        for (int nf = 0; nf < 4; nf++)
#pragma unroll
            for (int ks = 0; ks < 2; ks++) {
                f16x8 vf = *(const f16x8*)(Vb + foff[nf * 2 + ks]);
                o[nf] = __builtin_amdgcn_mfma_f32_16x16x32_f16(ks == 0 ? pa0 : pa1, vf, o[nf], 0, 0, 0);
            }
        __builtin_amdgcn_s_setprio(0);
        __syncthreads(); // drains next-tile glds + guards buffer reuse
    }
    // deferred l reduce (row sum across the 4 lane-groups), then broadcast
    float lsum = l_r;
    lsum += __shfl_xor(lsum, 16);
    lsum += __shfl_xor(lsum, 32);
    float lro[4];
#pragma unroll
    for (int r = 0; r < 4; r++) lro[r] = __shfl(lsum, (l >> 4) * 4 + r);
#pragma unroll
    for (int nf = 0; nf < 4; nf++) {
#pragma unroll
        for (int r = 0; r < 4; r++) {
            float v = o[nf][r] / lro[r];
            att[(size_t)(b * Tn + qo + r) * Cn + h * HSn + nf * 16 + (l & 15)] = (f16)v;
        }
    }
}

// ---------------------------------------------------------------------------
extern "C" void kernel_launch(void* const* d_in, const int* in_sizes, int n_in,
                              void* d_out, int out_size, void* d_ws, size_t ws_size,
                              hipStream_t stream) {
    const float* x = (const float*)d_in[0];
    const float* Wq = (const float*)d_in[1];
    const float* Wk = (const float*)d_in[2];
    const float* Wv = (const float*)d_in[3];
    const float* p = (const float*)d_in[4];
    const float* Wproj = (const float*)d_in[5];
    const float* W1 = (const float*)d_in[6];
    const float* W2 = (const float*)d_in[7];
    const float* ln1w = (const float*)d_in[8];
    const float* ln1b = (const float*)d_in[9];
    const float* ln2w = (const float*)d_in[10];
    const float* ln2b = (const float*)d_in[11];

    char* ws = (char*)d_ws;
    const size_t MB = 1ull << 20;
    f16* Wqkv_t = (f16*)(ws + 0 * MB);   // [3072][1024]
    f16* Wproj_t = (f16*)(ws + 6 * MB);  // [1024][1024]
    f16* W1_t = (f16*)(ws + 8 * MB);     // [4096][1024]
    f16* W2_t = (f16*)(ws + 16 * MB);    // [1024][4096]
    float* x1 = (float*)(ws + 24 * MB);  // [4096][1024] f32
    f16* QKV = (f16*)(ws + 40 * MB);     // [4096][3072]
    f16* h1 = (f16*)(ws + 64 * MB);      // [4096][1024]
    f16* vTb = (f16*)(ws + 64 * MB);     // [32][64][2048] (reuses h1 slot)
    f16* attb = (f16*)(ws + 72 * MB);    // [4096][1024]
    f16* h2 = attb;                      // reuse (att dead after proj gemm)
    f16* ffh = QKV;                      // [4096][4096] spans 40M..72M
    float* out = (float*)d_out;

    // weight repack (transposed f16)
    tr_cast_qkv<<<dim3(32, 2, 48), 256, 0, stream>>>(Wq, Wk, Wv, Wqkv_t);
    tr_cast_f32<<<dim3(32, 32), 256, 0, stream>>>(Wproj, 1024, Wproj_t, 1024);
    tr_cast_f32<<<dim3(32, 128), 256, 0, stream>>>(W1, 4096, W1_t, 1024);
    tr_cast_f32<<<dim3(128, 32), 256, 0, stream>>>(W2, 1024, W2_t, 4096);

    // block forward
    ln_kernel<<<4096, 256, 0, stream>>>(x, ln1w, ln1b, h1);
    gemm8<0><<<192, 512, 0, stream>>>(h1, Wqkv_t, QKV, 4096, 3072, 1024);
    tr_vT<<<dim3(32, 1, 32), 256, 0, stream>>>(QKV, vTb);
    attn_kernel<<<1024, 256, 0, stream>>>(QKV, vTb, p, attb);
    gemm_ks<2><<<dim3(32, 8), 512, 0, stream>>>(attb, Wproj_t, x1, x, 4096, 1024, 1024);
    ln_kernel<<<4096, 256, 0, stream>>>(x1, ln2w, ln2b, h2);
    gemm8<1><<<256, 512, 0, stream>>>(h2, W1_t, ffh, 4096, 4096, 1024);
    gemm_ks<2><<<dim3(32, 8), 512, 0, stream>>>(ffh, W2_t, out, x1, 4096, 1024, 4096);
}

// Round 10
// 216.776 us; speedup vs baseline: 1.4726x; 1.0229x over previous
//
#include <hip/hip_runtime.h>

// ---------------------------------------------------------------------------
// Transformer block forward on gfx950.  B=2 T=2048 C=1024 H=16 HS=64 FF=4096.
// All matmuls: f16 inputs, fp32 MFMA accumulation (16x16x32).
// R10: attn latency work: (1) T14 reg-staged K/V (global->reg at tile top,
//      ds_write at tile end -- load latency hides under the tile body, barrier
//      no longer drains in-flight prefetch); (2) per-lane defer-max check
//      (2-shfl row reduce moved inside the rare rescale branch).
//      GEMMs frozen (gemm8 QKV/FF1, deep gemm_ks proj/FF2).
// Workspace layout (80 MB): unchanged.
// ---------------------------------------------------------------------------

typedef _Float16 f16;
typedef _Float16 f16x8 __attribute__((ext_vector_type(8)));
typedef _Float16 f16x4v __attribute__((ext_vector_type(4)));
typedef float f32x4 __attribute__((ext_vector_type(4)));

static constexpr int Tn = 2048;
static constexpr int Cn = 1024;
static constexpr int HSn = 64;

// async global->LDS, 16B per lane; dest = wave-uniform base + lane*16
__device__ __forceinline__ void glds16(const f16* g, f16* l) {
    __builtin_amdgcn_global_load_lds((const __attribute__((address_space(1))) void*)g,
                                     (__attribute__((address_space(3))) void*)l,
                                     16, 0, 0);
}

#define VMCNT(N) asm volatile("s_waitcnt vmcnt(" #N ")" ::: "memory")
// raw barrier with code-motion fences (no implicit vmcnt/lgkm drain)
__device__ __forceinline__ void barrier_raw() {
    asm volatile("" ::: "memory");
    __builtin_amdgcn_s_barrier();
    asm volatile("" ::: "memory");
}

// pack two f32 -> two f16 (RTZ) as a u32 (v_cvt_pkrtz_f16_f32)
__device__ __forceinline__ unsigned cvt_pk_u32(float a, float b) {
    auto v = __builtin_amdgcn_cvt_pkrtz(a, b);
    union { __fp16 h2 __attribute__((ext_vector_type(2))); unsigned u; } c;
    c.h2 = v;
    return c.u;
}

// ---------------------------------------------------------------------------
// LayerNorm (fp32 in) -> f16 out.  One block per row, 256 threads.
// ---------------------------------------------------------------------------
__global__ __launch_bounds__(256) void ln_kernel(const float* __restrict__ x,
                                                 const float* __restrict__ w,
                                                 const float* __restrict__ b,
                                                 f16* __restrict__ out) {
    int row = blockIdx.x;
    const float* xr = x + (size_t)row * Cn;
    int tid = threadIdx.x, l = tid & 63, wv = tid >> 6;
    float4 v = *(const float4*)(xr + tid * 4);
    float s = v.x + v.y + v.z + v.w;
    float sq = v.x * v.x + v.y * v.y + v.z * v.z + v.w * v.w;
#pragma unroll
    for (int off = 32; off > 0; off >>= 1) {
        s += __shfl_down(s, off);
        sq += __shfl_down(sq, off);
    }
    __shared__ float red[8];
    if (l == 0) { red[wv] = s; red[wv + 4] = sq; }
    __syncthreads();
    float ts = red[0] + red[1] + red[2] + red[3];
    float tq = red[4] + red[5] + red[6] + red[7];
    float mean = ts * (1.0f / Cn);
    float var = tq * (1.0f / Cn) - mean * mean;
    float rstd = rsqrtf(var + 1e-5f);
    float4 wv4 = *(const float4*)(w + tid * 4);
    float4 bv4 = *(const float4*)(b + tid * 4);
    f16x4v o;
    o[0] = (f16)((v.x - mean) * rstd * wv4.x + bv4.x);
    o[1] = (f16)((v.y - mean) * rstd * wv4.y + bv4.y);
    o[2] = (f16)((v.z - mean) * rstd * wv4.z + bv4.z);
    o[3] = (f16)((v.w - mean) * rstd * wv4.w + bv4.w);
    *(f16x4v*)(out + (size_t)row * Cn + tid * 4) = o;
}

// ---------------------------------------------------------------------------
// Transpose + cast fp32 -> f16:  out[c][r] = in[r][c].  32x32 tiles.
// ---------------------------------------------------------------------------
__global__ __launch_bounds__(256) void tr_cast_f32(const float* __restrict__ in, int irs,
                                                   f16* __restrict__ out, int ors) {
    __shared__ float tile[32][33];
    int r0 = blockIdx.x * 32, c0 = blockIdx.y * 32;
    int t = threadIdx.x;
    int rr = t >> 3, c4 = (t & 7) * 4;
    float4 v = *(const float4*)(in + (size_t)(r0 + rr) * irs + c0 + c4);
    tile[rr][c4] = v.x; tile[rr][c4 + 1] = v.y; tile[rr][c4 + 2] = v.z; tile[rr][c4 + 3] = v.w;
    __syncthreads();
    int cc = t >> 3, r4 = (t & 7) * 4;
    f16x4v o;
    o[0] = (f16)tile[r4][cc];
    o[1] = (f16)tile[r4 + 1][cc];
    o[2] = (f16)tile[r4 + 2][cc];
    o[3] = (f16)tile[r4 + 3][cc];
    *(f16x4v*)(out + (size_t)(c0 + cc) * ors + r0 + r4) = o;
}

// Same, but gathers Wq/Wk/Wv [H][C][HS] into Wqkv^T rows n = qkv*1024 + h*64 + s.
__global__ __launch_bounds__(256) void tr_cast_qkv(const float* __restrict__ Wq,
                                                   const float* __restrict__ Wk,
                                                   const float* __restrict__ Wv,
                                                   f16* __restrict__ out) {
    int z = blockIdx.z;
    int qkv = z >> 4, h = z & 15;
    const float* in = (qkv == 0 ? Wq : qkv == 1 ? Wk : Wv) + (size_t)h * Cn * HSn; // [1024][64]
    f16* o = out + (size_t)(qkv * Cn + h * HSn) * Cn;
    __shared__ float tile[32][33];
    int r0 = blockIdx.x * 32, c0 = blockIdx.y * 32;
    int t = threadIdx.x;
    int rr = t >> 3, c4 = (t & 7) * 4;
    float4 v = *(const float4*)(in + (size_t)(r0 + rr) * HSn + c0 + c4);
    tile[rr][c4] = v.x; tile[rr][c4 + 1] = v.y; tile[rr][c4 + 2] = v.z; tile[rr][c4 + 3] = v.w;
    __syncthreads();
    int cc = t >> 3, r4 = (t & 7) * 4;
    f16x4v ov;
    ov[0] = (f16)tile[r4][cc];
    ov[1] = (f16)tile[r4 + 1][cc];
    ov[2] = (f16)tile[r4 + 2][cc];
    ov[3] = (f16)tile[r4 + 3][cc];
    *(f16x4v*)(o + (size_t)(c0 + cc) * Cn + r0 + r4) = ov;
}

// ---------------------------------------------------------------------------
// f16 transpose: vT[bh][s][t] = QKV[(b*T+t)][2048 + h*64 + s].  64x64 tiles.
// ---------------------------------------------------------------------------
__global__ __launch_bounds__(256) void tr_vT(const f16* __restrict__ QKV, f16* __restrict__ vT) {
    int bh = blockIdx.z;
    int b = bh >> 4, h = bh & 15;
    const f16* in = QKV + (size_t)b * Tn * 3072 + 2048 + h * HSn; // [T][64] stride 3072
    f16* out = vT + (size_t)bh * HSn * Tn;                        // [64][T]
    int r0 = blockIdx.x * 64;
    __shared__ __align__(16) f16 tile[64][72];
    int t = threadIdx.x;
#pragma unroll
    for (int i = 0; i < 2; i++) {
        int f = i * 256 + t;
        int rr = f >> 3, c8 = (f & 7) * 8;
        *(uint4*)(&tile[rr][c8]) = *(const uint4*)(in + (size_t)(r0 + rr) * 3072 + c8);
    }
    __syncthreads();
#pragma unroll
    for (int i = 0; i < 2; i++) {
        int f = i * 256 + t;
        int cc = f >> 3, r8 = (f & 7) * 8;
        union { f16 h[8]; uint4 v; } u;
#pragma unroll
        for (int j = 0; j < 8; j++) u.h[j] = tile[r8 + j][cc];
        *(uint4*)(out + (size_t)cc * Tn + r0 + r8) = u.v;
    }
}

// ---------------------------------------------------------------------------
// gemm8: C[M][N] = A[M][K] @ Bt[N][K]^T, 256x256 tile, 8 waves (2M x 4N),
// BK=32, 4 LDS buffers, stage depth 3, vmcnt(8)+s_barrier per K-tile,
// 2 phases x 16 MFMA, XOR chunk swizzle both sides, setprio.  (QKV, FF1)
// ---------------------------------------------------------------------------
template <int EPI>
__global__ __launch_bounds__(512, 2) void gemm8(const f16* __restrict__ A, const f16* __restrict__ Bt,
                                                f16* __restrict__ Cout, int M, int N, int K) {
    __shared__ __align__(16) f16 Abuf[4][8192];
    __shared__ __align__(16) f16 Bbuf[4][8192];
    int wg = blockIdx.x;
    int xcd = wg & 7, idx = wg >> 3;
    int bm = xcd * 2 + (idx & 1), bn = idx >> 1;
    int tid = threadIdx.x, l = tid & 63, w = tid >> 6;
    int wr = w >> 2, wc = w & 3;

    f32x4 acc[8][4];
#pragma unroll
    for (int m = 0; m < 8; m++)
#pragma unroll
        for (int n = 0; n < 4; n++) acc[m][n] = f32x4{0.f, 0.f, 0.f, 0.f};

    int l15 = l & 15;
    int lane_off = l15 * 32 + (((l >> 4) ^ ((l15 >> 1) & 3)) << 3);
    const f16* Afr = &Abuf[0][wr * 4096 + lane_off];
    const f16* Bfr = &Bbuf[0][(wc >> 1) * 4096 + (wc & 1) * 2048 + lane_off];

    int srow = w * 16 + (l >> 2);
    int schunk = (l & 3) ^ ((l >> 3) & 3);
    const f16* agp = A + (size_t)(bm * 256 + srow) * K + schunk * 8;
    const f16* bgp = Bt + (size_t)(bn * 256 + srow) * K + schunk * 8;
    const size_t rK = (size_t)128 * K;
    f16* dstA = &Abuf[0][w * 512];
    f16* dstB = &Bbuf[0][w * 512];

    auto stage = [&](int kt, int bf) {
        int k0 = kt * 32;
        glds16(agp + k0, dstA + bf * 8192);
        glds16(agp + rK + k0, dstA + bf * 8192 + 4096);
        glds16(bgp + k0, dstB + bf * 8192);
        glds16(bgp + rK + k0, dstB + bf * 8192 + 4096);
    };

    int NT = K >> 5;
    stage(0, 0);
    stage(1, 1);
    stage(2, 2);
    for (int t = 0; t < NT; ++t) {
        int cb = t & 3;
        VMCNT(8);
        barrier_raw();
        const f16* Ab = Afr + cb * 8192;
        const f16* Bb = Bfr + cb * 8192;
        f16x8 af[4], bf4[4];
#pragma unroll
        for (int m = 0; m < 4; m++) af[m] = *(const f16x8*)(Ab + m * 512);
#pragma unroll
        for (int n = 0; n < 4; n++) bf4[n] = *(const f16x8*)(Bb + n * 512);
        if (t + 3 < NT) stage(t + 3, (t + 3) & 3);
        __builtin_amdgcn_s_setprio(1);
#pragma unroll
        for (int m = 0; m < 4; m++)
#pragma unroll
            for (int n = 0; n < 4; n++)
                acc[m][n] = __builtin_amdgcn_mfma_f32_16x16x32_f16(af[m], bf4[n], acc[m][n], 0, 0, 0);
        __builtin_amdgcn_s_setprio(0);
        barrier_raw();
#pragma unroll
        for (int m = 0; m < 4; m++) af[m] = *(const f16x8*)(Ab + (m + 4) * 512);
        __builtin_amdgcn_s_setprio(1);
#pragma unroll
        for (int m = 0; m < 4; m++)
#pragma unroll
            for (int n = 0; n < 4; n++)
                acc[m + 4][n] = __builtin_amdgcn_mfma_f32_16x16x32_f16(af[m], bf4[n], acc[m + 4][n], 0, 0, 0);
        __builtin_amdgcn_s_setprio(0);
    }
    VMCNT(0);

    int row0 = bm * 256 + wr * 128 + (l >> 4) * 4;
    int col0 = bn * 256 + wc * 64 + (l & 15);
#pragma unroll
    for (int m = 0; m < 8; m++) {
#pragma unroll
        for (int n = 0; n < 4; n++) {
#pragma unroll
            for (int r = 0; r < 4; r++) {
                size_t idx = (size_t)(row0 + m * 16 + r) * N + (col0 + n * 16);
                float v = acc[m][n][r];
                if constexpr (EPI == 1) v = fmaxf(v, 0.f);
                Cout[idx] = (f16)v;
            }
        }
    }
}

// L2-aware decode for 128^2 grids: XCD x owns bm-chunk [4x, 4x+4).
__device__ __forceinline__ void l2_map(int& bm, int& bn) {
    int wg = blockIdx.y * 32 + blockIdx.x;
    int x = wg & 7, idx = wg >> 3;
    bm = x * 4 + (idx & 3);
    bn = idx >> 2;
}

// ---------------------------------------------------------------------------
// GEMM with in-block split-K + deep pipeline (3 buffers, vmcnt(4), raw
// barriers, XOR swizzle both sides).  Group 1 reduced into group 0 via LDS.
// (proj, FF2)
// ---------------------------------------------------------------------------
template <int EPI>
__global__ __launch_bounds__(512) void gemm_ks(const f16* __restrict__ A, const f16* __restrict__ Bt,
                                               void* __restrict__ Cout, const float* __restrict__ resid,
                                               int M, int N, int K) {
    __shared__ __align__(16) char smem[98304];
    f16* As = (f16*)smem;            // [grp][3][4096] = 48KB
    f16* Bs = (f16*)(smem + 49152);  // [grp][3][4096] = 48KB
    int bm, bn;
    l2_map(bm, bn);
    int tid = threadIdx.x, l = tid & 63, w = tid >> 6;
    int grp = w >> 2, wl = w & 3;
    int wr = wl >> 1, wc = wl & 1;
    int Kh = K >> 1;
    int KT = Kh >> 5;

    f32x4 acc[4][4];
#pragma unroll
    for (int m = 0; m < 4; m++)
#pragma unroll
        for (int n = 0; n < 4; n++) acc[m][n] = f32x4{0.f, 0.f, 0.f, 0.f};

    int schunk = (l & 3) ^ ((l >> 3) & 3);
    const f16* agp = A + (size_t)(bm * 128 + wl * 16 + (l >> 2)) * K + grp * Kh + schunk * 8;
    const f16* bgp = Bt + (size_t)(bn * 128 + wl * 16 + (l >> 2)) * K + grp * Kh + schunk * 8;
    const size_t half = (size_t)64 * K;
    f16* Ab = As + grp * 12288;
    f16* Bb = Bs + grp * 12288;

    auto stage = [&](int kt, int bf) {
        size_t k0 = (size_t)kt * 32;
        glds16(agp + k0, Ab + bf * 4096 + wl * 512);
        glds16(agp + half + k0, Ab + bf * 4096 + 2048 + wl * 512);
        glds16(bgp + k0, Bb + bf * 4096 + wl * 512);
        glds16(bgp + half + k0, Bb + bf * 4096 + 2048 + wl * 512);
    };

    int l15 = l & 15;
    int rbase = (wr * 64 + l15) * 32 + (((l >> 4) ^ ((l15 >> 1) & 3)) << 3);
    int cbase = (wc * 64 + l15) * 32 + (((l >> 4) ^ ((l15 >> 1) & 3)) << 3);

    stage(0, 0);
    if (KT > 1) stage(1, 1);
    int nb = 2;
    for (int kt = 0; kt < KT; ++kt) {
        int cb = kt % 3;
        if (kt + 1 < KT) VMCNT(4);
        else VMCNT(0);
        barrier_raw();
        if (kt + 2 < KT) { stage(kt + 2, nb); nb = (nb == 2) ? 0 : nb + 1; }
        f16x8 af[4], bfr[4];
#pragma unroll
        for (int m = 0; m < 4; m++) af[m] = *(const f16x8*)(Ab + cb * 4096 + rbase + m * 512);
#pragma unroll
        for (int n = 0; n < 4; n++) bfr[n] = *(const f16x8*)(Bb + cb * 4096 + cbase + n * 512);
        __builtin_amdgcn_s_setprio(1);
#pragma unroll
        for (int m = 0; m < 4; m++)
#pragma unroll
            for (int n = 0; n < 4; n++)
                acc[m][n] = __builtin_amdgcn_mfma_f32_16x16x32_f16(af[m], bfr[n], acc[m][n], 0, 0, 0);
        __builtin_amdgcn_s_setprio(0);
    }
    __syncthreads(); // all compute done (drains lgkm/vm) before red aliases As

    float* red = (float*)smem;
#pragma unroll
    for (int m = 0; m < 4; m++) {
        if (grp == 1) {
#pragma unroll
            for (int n = 0; n < 4; n++)
                *(f32x4*)(red + wl * 1280 + l * 20 + n * 4) = acc[m][n];
        }
        __syncthreads();
        if (grp == 0) {
#pragma unroll
            for (int n = 0; n < 4; n++)
                acc[m][n] += *(const f32x4*)(red + wl * 1280 + l * 20 + n * 4);
        }
        __syncthreads();
    }

    if (grp == 0) {
        int row0 = bm * 128 + wr * 64 + (l >> 4) * 4;
        int col0 = bn * 128 + wc * 64 + (l & 15);
#pragma unroll
        for (int m = 0; m < 4; m++) {
#pragma unroll
            for (int n = 0; n < 4; n++) {
#pragma unroll
                for (int r = 0; r < 4; r++) {
                    size_t idx = (size_t)(row0 + m * 16 + r) * N + (col0 + n * 16);
                    float v = acc[m][n][r];
                    if constexpr (EPI == 0) ((f16*)Cout)[idx] = (f16)v;
                    else if constexpr (EPI == 1) ((f16*)Cout)[idx] = (f16)fmaxf(v, 0.f);
                    else ((float*)Cout)[idx] = v + resid[idx];
                }
            }
        }
    }
}

// ---------------------------------------------------------------------------
// Flash attention, causal.  One q-tile per block, grid 1024 (3 blocks/CU,
// 42KB LDS), long-blocks-first dispatch, bh grouped per XCD.  Swapped QK^T,
// exp2-domain softmax, diagonal-only mask.  R10: T14 reg-staged K/V (loads
// issued at tile top, ds_write at tile end); per-lane defer-max check with
// the cross-lane reduce inside the rare rescale branch.
// ---------------------------------------------------------------------------
__global__ __launch_bounds__(256) void attn_kernel(const f16* __restrict__ QKV,
                                                   const f16* __restrict__ vT,
                                                   const float* __restrict__ p,
                                                   f16* __restrict__ att) {
    int i = blockIdx.x;                      // 1024 = 8 xcd x 4 bh x 32 qt
    int bh = (i & 7) * 4 + ((i >> 3) & 3);   // XCD owns 4 heads (K/V L2-fit)
    int qt = 31 - (i >> 5);                  // low idx -> large qt (long first)
    int b = bh >> 4, h = bh & 15;
    int tid = threadIdx.x, w = tid >> 6, l = tid & 63;
    float sc2 = rsqrtf(p[h]) * 1.44269504f;  // scale * log2(e)

    __shared__ __align__(16) f16 Ks[2][4096];
    __shared__ __align__(16) f16 Vs[2][4096];
    __shared__ __align__(16) f16 Ps[4][16 * 80];
    f16* Pw = &Ps[w][0];

    // staging geometry: thread covers rows srow0 / srow0+32, 16B chunk c0
    // (inverse swizzle on the GLOBAL side; LDS content identical to glds path;
    //  note (srow0+32)&7 == srow0&7 so both rows share c0)
    int srow0 = tid >> 3;
    int c0 = (tid & 7) ^ (srow0 & 7);
    const f16* Kg = QKV + (size_t)b * Tn * 3072 + 1024 + h * HSn;
    const f16* Vg = vT + (size_t)bh * HSn * Tn;
    const f16* Kg0 = Kg + (size_t)srow0 * 3072 + c0 * 8;
    const f16* Kg1 = Kg + (size_t)(srow0 + 32) * 3072 + c0 * 8;
    const f16* Vg0 = Vg + (size_t)srow0 * Tn + c0 * 8;
    const f16* Vg1 = Vg + (size_t)(srow0 + 32) * Tn + c0 * 8;
    int dl = w * 512 + l * 8; // this thread's 16B LDS slot (f16 index)

    // hoisted swizzled fragment offsets (bytes), static-unrolled -> regs
    int foff[8];
#pragma unroll
    for (int n = 0; n < 4; n++)
#pragma unroll
        for (int ks = 0; ks < 2; ks++)
            foff[n * 2 + ks] = (n * 16 + (l & 15)) * 128 +
                               (((ks * 32 + (l >> 4) * 8) * 2) ^ ((l & 7) << 4));

    int qg = qt * 64 + w * 16 + (l & 15);
    int qo = qt * 64 + w * 16 + (l >> 4) * 4;
    const f16* qptr = QKV + (size_t)(b * Tn + qg) * 3072 + h * HSn + (l >> 4) * 8;
    f16x8 qf0 = *(const f16x8*)(qptr);
    f16x8 qf1 = *(const f16x8*)(qptr + 32);
    f16 sch = (f16)sc2;
#pragma unroll
    for (int j = 0; j < 8; j++) { qf0[j] *= sch; qf1[j] *= sch; }

    f32x4 o[4];
#pragma unroll
    for (int nf = 0; nf < 4; nf++) o[nf] = f32x4{0.f, 0.f, 0.f, 0.f};
    float m_r = -1e30f, l_r = 0.f; // lane-local l partial (reduced at end)

    int nt = qt + 1;
    // prologue: tile 0 -> regs -> LDS buf 0
    uint4 kr0 = *(const uint4*)(Kg0);
    uint4 kr1 = *(const uint4*)(Kg1);
    uint4 vr0 = *(const uint4*)(Vg0);
    uint4 vr1 = *(const uint4*)(Vg1);
    *(uint4*)(&Ks[0][dl]) = kr0;
    *(uint4*)(&Ks[0][2048 + dl]) = kr1;
    *(uint4*)(&Vs[0][dl]) = vr0;
    *(uint4*)(&Vs[0][2048 + dl]) = vr1;
    __syncthreads();
    for (int t = 0; t < nt; ++t) {
        int kv0 = t * 64;
        if (t + 1 < nt) { // issue next tile's loads; consumed at tile end (T14)
            size_t ko = (size_t)(kv0 + 64) * 3072;
            kr0 = *(const uint4*)(Kg0 + ko);
            kr1 = *(const uint4*)(Kg1 + ko);
            vr0 = *(const uint4*)(Vg0 + kv0 + 64);
            vr1 = *(const uint4*)(Vg1 + kv0 + 64);
        }
        const char* Kb = (const char*)&Ks[t & 1][0];
        const char* Vb = (const char*)&Vs[t & 1][0];
        f32x4 s[4];
#pragma unroll
        for (int n = 0; n < 4; n++) s[n] = f32x4{0.f, 0.f, 0.f, 0.f};
        __builtin_amdgcn_s_setprio(1);
#pragma unroll
        for (int n = 0; n < 4; n++)
#pragma unroll
            for (int ks = 0; ks < 2; ks++) {
                f16x8 kf = *(const f16x8*)(Kb + foff[n * 2 + ks]);
                s[n] = __builtin_amdgcn_mfma_f32_16x16x32_f16(kf, ks == 0 ? qf0 : qf1, s[n], 0, 0, 0);
            }
        __builtin_amdgcn_s_setprio(0);
        if (t == qt) { // mask only on the diagonal tile
            int rel = qg - kv0;
#pragma unroll
            for (int n = 0; n < 4; n++)
#pragma unroll
                for (int r = 0; r < 4; r++) {
                    int kvr = n * 16 + (l >> 4) * 4 + r;
                    if (kvr > rel) s[n][r] = -1e30f;
                }
        }
        // per-lane partial max; full row reduce only inside the rare branch
        float tmax = -1e30f;
#pragma unroll
        for (int n = 0; n < 4; n++)
#pragma unroll
            for (int r = 0; r < 4; r++) tmax = fmaxf(tmax, s[n][r]);
        float lmul = 1.f;
        if (__any(tmax > m_r + 8.f)) { // T13 defer-rescale (exp2 domain)
            float rmax = fmaxf(tmax, __shfl_xor(tmax, 16));
            rmax = fmaxf(rmax, __shfl_xor(rmax, 32));
            float mnew = fmaxf(m_r, rmax);
            lmul = exp2f(m_r - mnew);
            m_r = mnew;
            float ar[4];
#pragma unroll
            for (int r = 0; r < 4; r++) ar[r] = __shfl(lmul, (l >> 4) * 4 + r);
#pragma unroll
            for (int nf = 0; nf < 4; nf++)
#pragma unroll
                for (int r = 0; r < 4; r++) o[nf][r] *= ar[r];
        }
        float rsum = 0.f;
#pragma unroll
        for (int n = 0; n < 4; n++) {
            float e0 = exp2f(s[n][0] - m_r), e1 = exp2f(s[n][1] - m_r);
            float e2 = exp2f(s[n][2] - m_r), e3 = exp2f(s[n][3] - m_r);
            rsum += (e0 + e1) + (e2 + e3);
            union { unsigned u[2]; f16x4v h4; } u;
            u.u[0] = cvt_pk_u32(e0, e1);
            u.u[1] = cvt_pk_u32(e2, e3);
            *(f16x4v*)(&Pw[(l & 15) * 80 + n * 16 + (l >> 4) * 4]) = u.h4;
        }
        l_r = l_r * lmul + rsum; // lane-local; lmul is row-uniform -> exact
        f16x8 pa0 = *(const f16x8*)(&Pw[(l & 15) * 80 + (l >> 4) * 8]);
        f16x8 pa1 = *(const f16x8*)(&Pw[(l & 15) * 80 + 32 + (l >> 4) * 8]);
        __builtin_amdgcn_s_setprio(1);
#pragma unroll
        for (int nf = 0; nf < 4; nf++)
#pragma unroll
            for (int ks = 0; ks < 2; ks++) {
                f16x8 vf = *(const f16x8*)(Vb + foff[nf * 2 + ks]);
                o[nf] = __builtin_amdgcn_mfma_f32_16x16x32_f16(ks == 0 ? pa0 : pa1, vf, o[nf], 0, 0, 0);
            }
        __builtin_amdgcn_s_setprio(0);
        if (t + 1 < nt) { // write next tile to the other buffer (T14 late half)
            int nbf = (t + 1) & 1;
            *(uint4*)(&Ks[nbf][dl]) = kr0;
            *(uint4*)(&Ks[nbf][2048 + dl]) = kr1;
            *(uint4*)(&Vs[nbf][dl]) = vr0;
            *(uint4*)(&Vs[nbf][2048 + dl]) = vr1;
            __syncthreads(); // writes visible; also fences buf[t&1] reuse
        }
    }
    // deferred l reduce (row sum across the 4 lane-groups), then broadcast
    float lsum = l_r;
    lsum += __shfl_xor(lsum, 16);
    lsum += __shfl_xor(lsum, 32);
    float lro[4];
#pragma unroll
    for (int r = 0; r < 4; r++) lro[r] = __shfl(lsum, (l >> 4) * 4 + r);
#pragma unroll
    for (int nf = 0; nf < 4; nf++) {
#pragma unroll
        for (int r = 0; r < 4; r++) {
            float v = o[nf][r] / lro[r];
            att[(size_t)(b * Tn + qo + r) * Cn + h * HSn + nf * 16 + (l & 15)] = (f16)v;
        }
    }
}

// ---------------------------------------------------------------------------
extern "C" void kernel_launch(void* const* d_in, const int* in_sizes, int n_in,
                              void* d_out, int out_size, void* d_ws, size_t ws_size,
                              hipStream_t stream) {
    const float* x = (const float*)d_in[0];
    const float* Wq = (const float*)d_in[1];
    const float* Wk = (const float*)d_in[2];
    const float* Wv = (const float*)d_in[3];
    const float* p = (const float*)d_in[4];
    const float* Wproj = (const float*)d_in[5];
    const float* W1 = (const float*)d_in[6];
    const float* W2 = (const float*)d_in[7];
    const float* ln1w = (const float*)d_in[8];
    const float* ln1b = (const float*)d_in[9];
    const float* ln2w = (const float*)d_in[10];
    const float* ln2b = (const float*)d_in[11];

    char* ws = (char*)d_ws;
    const size_t MB = 1ull << 20;
    f16* Wqkv_t = (f16*)(ws + 0 * MB);   // [3072][1024]
    f16* Wproj_t = (f16*)(ws + 6 * MB);  // [1024][1024]
    f16* W1_t = (f16*)(ws + 8 * MB);     // [4096][1024]
    f16* W2_t = (f16*)(ws + 16 * MB);    // [1024][4096]
    float* x1 = (float*)(ws + 24 * MB);  // [4096][1024] f32
    f16* QKV = (f16*)(ws + 40 * MB);     // [4096][3072]
    f16* h1 = (f16*)(ws + 64 * MB);      // [4096][1024]
    f16* vTb = (f16*)(ws + 64 * MB);     // [32][64][2048] (reuses h1 slot)
    f16* attb = (f16*)(ws + 72 * MB);    // [4096][1024]
    f16* h2 = attb;                      // reuse (att dead after proj gemm)
    f16* ffh = QKV;                      // [4096][4096] spans 40M..72M
    float* out = (float*)d_out;

    // weight repack (transposed f16)
    tr_cast_qkv<<<dim3(32, 2, 48), 256, 0, stream>>>(Wq, Wk, Wv, Wqkv_t);
    tr_cast_f32<<<dim3(32, 32), 256, 0, stream>>>(Wproj, 1024, Wproj_t, 1024);
    tr_cast_f32<<<dim3(32, 128), 256, 0, stream>>>(W1, 4096, W1_t, 1024);
    tr_cast_f32<<<dim3(128, 32), 256, 0, stream>>>(W2, 1024, W2_t, 4096);

    // block forward
    ln_kernel<<<4096, 256, 0, stream>>>(x, ln1w, ln1b, h1);
    gemm8<0><<<192, 512, 0, stream>>>(h1, Wqkv_t, QKV, 4096, 3072, 1024);
    tr_vT<<<dim3(32, 1, 32), 256, 0, stream>>>(QKV, vTb);
    attn_kernel<<<1024, 256, 0, stream>>>(QKV, vTb, p, attb);
    gemm_ks<2><<<dim3(32, 8), 512, 0, stream>>>(attb, Wproj_t, x1, x, 4096, 1024, 1024);
    ln_kernel<<<4096, 256, 0, stream>>>(x1, ln2w, ln2b, h2);
    gemm8<1><<<256, 512, 0, stream>>>(h2, W1_t, ffh, 4096, 4096, 1024);
    gemm_ks<2><<<dim3(32, 8), 512, 0, stream>>>(ffh, W2_t, out, x1, 4096, 1024, 4096);
}